// Round 1
// baseline (4832.748 us; speedup 1.0000x reference)
//
#include <hip/hip_runtime.h>
#include <math.h>

#define NNODES 4096
#define NEDGES 65536

enum { AT_F32 = 0, AT_MASK = 1, AT_U8 = 2 };

// Generic tiled f32 GEMM: C[M,Nn] = act( (A * a_rs[row]) @ (B * b_rs[k]) + bias ) (+C if accum)
// A: row-major [M,K], optionally decoded from packed view-bitmask (popcount) or uint8.
// B: row-major [K,Nn], or [Nn,K] when BTR (i.e. B^T logical).
// Thread layout fixed 16x16=256; per-thread microtile TM x TN = BM/16 x BN/16.
template<int BM, int BN, int BK, int ATY, bool BTR, int ACT>
__global__ __launch_bounds__(256)
void gemm_k(const void* __restrict__ Ap, const float* __restrict__ a_rs,
            const float* __restrict__ B, const float* __restrict__ b_rs,
            const float* __restrict__ bias, float* __restrict__ C,
            int M, int Nn, int K, int accum)
{
    constexpr int TM = BM / 16;
    constexpr int TN = BN / 16;
    __shared__ float As[BK][BM + 4];
    __shared__ float Bs[BK][BN + 4];
    const int tid = threadIdx.x;
    const int tx = tid & 15, ty = tid >> 4;
    const int bm0 = blockIdx.y * BM, bn0 = blockIdx.x * BN;

    float acc[TM][TN];
#pragma unroll
    for (int i = 0; i < TM; ++i)
#pragma unroll
        for (int j = 0; j < TN; ++j) acc[i][j] = 0.f;

    for (int k0 = 0; k0 < K; k0 += BK) {
        // ---- stage A tile (transposed into LDS) ----
        for (int idx = tid; idx < BM * BK; idx += 256) {
            int m = idx / BK, kk = idx % BK;
            int row = bm0 + m, kg = k0 + kk;
            float a;
            if constexpr (ATY == AT_MASK) {
                unsigned c = (unsigned)row * (unsigned)K + (unsigned)kg;
                a = (float)__popc((((const unsigned*)Ap)[c >> 2] >> ((c & 3u) * 8u)) & 7u);
            } else if constexpr (ATY == AT_U8) {
                a = (float)((const unsigned char*)Ap)[(size_t)row * K + kg];
            } else {
                a = ((const float*)Ap)[(size_t)row * K + kg];
            }
            if (a_rs) a *= a_rs[row];
            As[kk][m] = a;
        }
        // ---- stage B tile ----
        for (int idx = tid; idx < BK * BN; idx += 256) {
            int kk = idx / BN, n = idx % BN;
            int col = bn0 + n, kg = k0 + kk;
            float b = 0.f;
            if (col < Nn) {
                b = BTR ? B[(size_t)col * K + kg] : B[(size_t)kg * Nn + col];
                if (b_rs) b *= b_rs[kg];
            }
            Bs[kk][n] = b;
        }
        __syncthreads();
#pragma unroll
        for (int kk = 0; kk < BK; ++kk) {
            float av[TM], bv[TN];
#pragma unroll
            for (int i = 0; i < TM; ++i) av[i] = As[kk][ty * TM + i];
#pragma unroll
            for (int j = 0; j < TN; ++j) bv[j] = Bs[kk][tx * TN + j];
#pragma unroll
            for (int i = 0; i < TM; ++i)
#pragma unroll
                for (int j = 0; j < TN; ++j) acc[i][j] += av[i] * bv[j];
        }
        __syncthreads();
    }

#pragma unroll
    for (int i = 0; i < TM; ++i) {
        int row = bm0 + ty * TM + i;
#pragma unroll
        for (int j = 0; j < TN; ++j) {
            int col = bn0 + tx * TN + j;
            if (col < Nn) {
                float v = acc[i][j];
                if (bias) v += bias[col];
                if (accum) v += C[(size_t)row * Nn + col];
                if constexpr (ACT == 1) v = fmaxf(v, 0.f);
                if constexpr (ACT == 2) v = rintf(fminf(fmaxf(v, 0.f), 1.f) + 0.1f);
                C[(size_t)row * Nn + col] = v;
            }
        }
    }
}

// scatter per-view adjacency bit into packed mask: bit ((cell&3)*8 + view) of word cell>>2
__global__ void mask_scatter_k(const int* __restrict__ src, const int* __restrict__ dst,
                               unsigned* __restrict__ mask, int E, int view)
{
    int t = blockIdx.x * 256 + threadIdx.x;
    if (t < E) {
        unsigned c = (unsigned)src[t] * (unsigned)NNODES + (unsigned)dst[t];
        atomicOr(&mask[c >> 2], 1u << ((c & 3u) * 8u + (unsigned)view));
    }
}

__global__ void deg_count_k(const int* __restrict__ src, const int* __restrict__ dst,
                            int* __restrict__ dout, int* __restrict__ din, int E)
{
    int t = blockIdx.x * 256 + threadIdx.x;
    if (t < E) {
        atomicAdd(&dout[src[t]], 1);
        atomicAdd(&din[dst[t]], 1);
    }
}

__global__ void deg_norm_k(const int* __restrict__ degs, float* __restrict__ isq, int n)
{
    int t = blockIdx.x * 256 + threadIdx.x;
    if (t < n) isq[t] = 1.0f / sqrtf(fmaxf((float)degs[t], 1.0f));
}

// agg[dst[e], :] += H[src[e], :]
template<int F>
__global__ void scatter_add_k(const float* __restrict__ H, const int* __restrict__ src,
                              const int* __restrict__ dst, float* __restrict__ agg, int E)
{
    int t = blockIdx.x * 256 + threadIdx.x;
    int e = t / F, f = t % F;
    if (e < E) {
        atomicAdd(&agg[(size_t)dst[e] * F + f], H[(size_t)src[e] * F + f]);
    }
}

// out = act(agg * rs[row] + bias[col])
template<int F, int ACT>
__global__ void sba_k(const float* __restrict__ agg, const float* __restrict__ rs,
                      const float* __restrict__ bias, float* __restrict__ out, int total)
{
    int t = blockIdx.x * 256 + threadIdx.x;
    if (t < total) {
        int i = t / F, f = t % F;
        float v = agg[t] * rs[i] + bias[f];
        if (ACT) v = fmaxf(v, 0.f);
        out[t] = v;
    }
}

// row softmax over 64 features; one wave per row (relu(softmax)=softmax, strictly >0)
__global__ void softmax64_k(float* __restrict__ z)
{
    int row = blockIdx.x * 4 + (threadIdx.x >> 6);
    int f = threadIdx.x & 63;
    float v = z[(size_t)row * 64 + f];
    float m = v;
#pragma unroll
    for (int off = 32; off >= 1; off >>= 1) m = fmaxf(m, __shfl_xor(m, off));
    float e = expf(v - m);
    float s = e;
#pragma unroll
    for (int off = 32; off >= 1; off >>= 1) s += __shfl_xor(s, off);
    z[(size_t)row * 64 + f] = e / s;
}

// A[i,j] = (adjr[i,j]>0 | adjr[j,i]>0 | i==j); deg[i] += rowsum
__global__ void build_A_k(const float* __restrict__ adjr, unsigned char* __restrict__ A,
                          int* __restrict__ deg)
{
    __shared__ float Tji[64][65];
    const int bi = blockIdx.y * 64, bj = blockIdx.x * 64;
    for (int idx = threadIdx.x; idx < 4096; idx += 256) {
        int r = idx >> 6, c = idx & 63;
        Tji[r][c] = adjr[(size_t)(bj + r) * NNODES + bi + c];
    }
    __syncthreads();
    int i = threadIdx.x >> 2;
    int j0 = (threadIdx.x & 3) * 16;
    int psum = 0;
    for (int jj = 0; jj < 16; ++jj) {
        int j = j0 + jj;
        float a = adjr[(size_t)(bi + i) * NNODES + bj + j];
        float b = Tji[j][i];
        int on = (a > 0.5f) | (b > 0.5f) | ((bi + i) == (bj + j));
        A[(size_t)(bi + i) * NNODES + bj + j] = (unsigned char)on;
        psum += on;
    }
    atomicAdd(&deg[bi + i], psum);
}

__global__ void dn_k(const int* __restrict__ deg, float* __restrict__ dn, int n)
{
    int t = blockIdx.x * 256 + threadIdx.x;
    if (t < n) dn[t] = 1.0f / sqrtf((float)deg[t]);
}

extern "C" void kernel_launch(void* const* d_in, const int* in_sizes, int n_in,
                              void* d_out, int out_size, void* d_ws, size_t ws_size,
                              hipStream_t stream)
{
    const int N = NNODES, E = NEDGES;

    const float* x[3]; const int* src[3]; const int* dst[3];
    const float *Wv0[3], *bv0[3], *Wv1[3], *bv1[3], *Wf[3];
    for (int v = 0; v < 3; ++v) {
        const int b = v * 8;
        x[v]   = (const float*)d_in[b + 0];
        src[v] = (const int*)  d_in[b + 1];
        dst[v] = (const int*)  d_in[b + 2];
        Wv0[v] = (const float*)d_in[b + 3];
        bv0[v] = (const float*)d_in[b + 4];
        Wv1[v] = (const float*)d_in[b + 5];
        bv1[v] = (const float*)d_in[b + 6];
        Wf[v]  = (const float*)d_in[b + 7];
    }
    const float* Wg1 = (const float*)d_in[24];
    const float* bg1 = (const float*)d_in[25];
    const float* Wg2 = (const float*)d_in[26];
    const float* bg2 = (const float*)d_in[27];
    const float* Wm0 = (const float*)d_in[28];
    const float* bm0 = (const float*)d_in[29];
    const float* Wm1 = (const float*)d_in[30];
    const float* bm1 = (const float*)d_in[31];

    float* out_adjr = (float*)d_out;                    // [N,N]
    float* out_rec  = out_adjr + (size_t)N * N;         // [N,N]  (free until the end -> holds H1)
    float* out_h    = out_rec + (size_t)N * N;          // [N,64]
    float* H1 = out_rec;                                // [N,2048] fits in 16M-float slot

    // ---- workspace carve (~26.5 MB) ----
    char* p = (char*)d_ws;
    unsigned* mask = (unsigned*)p;                      // 16 MB; reused as A8 after GEMM1
    unsigned char* A8 = (unsigned char*)p;
    p += (size_t)N * N;                                 // N*N/4 words
    int* degs = (int*)p;       p += (size_t)6 * N * 4;  // [dout0,din0,dout1,din1,dout2,din2]
    float* isq = (float*)p;    p += (size_t)6 * N * 4;
    float* hv1 = (float*)p;    p += (size_t)N * 128 * 4;
    float* agg1 = (float*)p;   p += (size_t)N * 128 * 4;
    float* hv2 = (float*)p;    p += (size_t)N * 64 * 4;
    float* agg2 = (float*)p;   p += (size_t)N * 64 * 4;
    float* feat = (float*)p;   p += (size_t)N * 64 * 4;
    float* z = (float*)p;      p += (size_t)N * 64 * 4;
    float* t1 = (float*)p;     p += (size_t)N * 64 * 4;
    float* h1m = (float*)p;    p += (size_t)N * 64 * 4;
    int* degA = (int*)p;       p += (size_t)N * 4;
    float* dnv = (float*)p;    p += (size_t)N * 4;

    hipMemsetAsync(mask, 0, (size_t)N * N, stream);
    hipMemsetAsync(degs, 0, (size_t)6 * N * 4, stream);

    for (int v = 0; v < 3; ++v) {
        mask_scatter_k<<<(E + 255) / 256, 256, 0, stream>>>(src[v], dst[v], mask, E, v);
        deg_count_k<<<(E + 255) / 256, 256, 0, stream>>>(src[v], dst[v],
                                                          degs + 2 * v * N, degs + (2 * v + 1) * N, E);
    }
    deg_norm_k<<<(6 * N + 255) / 256, 256, 0, stream>>>(degs, isq, 6 * N);

    // per-view GCN stacks
    for (int v = 0; v < 3; ++v) {
        const float* doi = isq + 2 * v * N;
        const float* dii = isq + (2 * v + 1) * N;
        // layer1: hv1 = (x * doi) @ Wv0   [N,128], K=512
        gemm_k<64, 64, 16, AT_F32, false, 0><<<dim3(2, N / 64), 256, 0, stream>>>(
            x[v], doi, Wv0[v], nullptr, nullptr, hv1, N, 128, 512, 0);
        hipMemsetAsync(agg1, 0, (size_t)N * 128 * 4, stream);
        scatter_add_k<128><<<E * 128 / 256, 256, 0, stream>>>(hv1, src[v], dst[v], agg1, E);
        sba_k<128, 1><<<N * 128 / 256, 256, 0, stream>>>(agg1, dii, bv0[v], hv1, N * 128);
        // layer2: hv2 = (f1 * doi) @ Wv1  [N,64], K=128
        gemm_k<64, 64, 16, AT_F32, false, 0><<<dim3(1, N / 64), 256, 0, stream>>>(
            hv1, doi, Wv1[v], nullptr, nullptr, hv2, N, 64, 128, 0);
        hipMemsetAsync(agg2, 0, (size_t)N * 64 * 4, stream);
        scatter_add_k<64><<<E * 64 / 256, 256, 0, stream>>>(hv2, src[v], dst[v], agg2, E);
        sba_k<64, 0><<<N * 64 / 256, 256, 0, stream>>>(agg2, dii, bv1[v], feat, N * 64);
        // z += feat @ Wf[v]
        gemm_k<64, 64, 16, AT_F32, false, 0><<<dim3(1, N / 64), 256, 0, stream>>>(
            feat, nullptr, Wf[v], nullptr, nullptr, z, N, 64, 64, v > 0 ? 1 : 0);
    }
    softmax64_k<<<N / 4, 256, 0, stream>>>(z);

    // GFN: H1 = relu(adj @ Wg1 + bg1)   [N,2048], K=N, A decoded from mask (popcount)
    gemm_k<128, 128, 16, AT_MASK, false, 1><<<dim3(2048 / 128, N / 128), 256, 0, stream>>>(
        mask, nullptr, Wg1, nullptr, bg1, H1, N, 2048, N, 0);
    // adj_r = round(clip(H1 @ Wg2 + bg2, 0, 1) + 0.1)   [N,N], K=2048
    gemm_k<128, 128, 16, AT_F32, false, 2><<<dim3(N / 128, N / 128), 256, 0, stream>>>(
        H1, nullptr, Wg2, nullptr, bg2, out_adjr, N, N, 2048, 0);

    // A = sym(adj_r)>0 | I ; deg; dn = deg^-1/2   (A8 overwrites mask region)
    hipMemsetAsync(degA, 0, (size_t)N * 4, stream);
    build_A_k<<<dim3(N / 64, N / 64), 256, 0, stream>>>(out_adjr, A8, degA);
    dn_k<<<(N + 255) / 256, 256, 0, stream>>>(degA, dnv, N);

    // fused-graph GCN: t1 = A @ (z*dn); h1m = relu((t1*dn)@Wm0+bm0); t2 = A @ (h1m*dn); h = (t2*dn)@Wm1+bm1
    gemm_k<64, 64, 16, AT_U8, false, 0><<<dim3(1, N / 64), 256, 0, stream>>>(
        A8, nullptr, z, dnv, nullptr, t1, N, 64, N, 0);
    gemm_k<64, 64, 16, AT_F32, false, 1><<<dim3(1, N / 64), 256, 0, stream>>>(
        t1, dnv, Wm0, nullptr, bm0, h1m, N, 64, 64, 0);
    gemm_k<64, 64, 16, AT_U8, false, 0><<<dim3(1, N / 64), 256, 0, stream>>>(
        A8, nullptr, h1m, dnv, nullptr, t1, N, 64, N, 0);
    gemm_k<64, 64, 16, AT_F32, false, 0><<<dim3(1, N / 64), 256, 0, stream>>>(
        t1, dnv, Wm1, nullptr, bm1, out_h, N, 64, 64, 0);

    // adj_rec = h @ h.T  [N,N], K=64 (overwrites H1 region)
    gemm_k<128, 128, 16, AT_F32, true, 0><<<dim3(N / 128, N / 128), 256, 0, stream>>>(
        out_h, nullptr, out_h, nullptr, nullptr, out_rec, N, N, 64, 0);
}

// Round 2
// 1244.946 us; speedup vs baseline: 3.8819x; 3.8819x over previous
//
#include <hip/hip_runtime.h>
#include <math.h>

#define NNODES 4096
#define NEDGES 65536

enum { AT_F32 = 0, AT_U8 = 2 };

typedef short bf16x8 __attribute__((ext_vector_type(8)));
typedef short short4v __attribute__((ext_vector_type(4)));
typedef float f32x4 __attribute__((ext_vector_type(4)));

__device__ __forceinline__ short f2bf(float f) {
    unsigned u = __builtin_bit_cast(unsigned, f);
    unsigned r = (u + 0x7FFFu + ((u >> 16) & 1u)) >> 16;
    return (short)r;
}

__device__ __forceinline__ void gload_lds16(const void* g, void* l) {
    __builtin_amdgcn_global_load_lds(
        (const __attribute__((address_space(1))) unsigned*)g,
        (__attribute__((address_space(3))) unsigned*)l, 16, 0, 0);
}

// ---------------- bf16 MFMA GEMM: C = act(A @ B^T + bias) ----------------
// A bf16 [M][K] row-major, Bt bf16 [Nn][K] row-major. 128x128 tile, BK=64.
// 4 waves (2x2), each 64x64 out = 4x4 frags of 16x16x32 MFMA.
// LDS: [row][slot'] with slot' = slot ^ (row&7) (16B slots) -> conflict-free
// ds_read_b128; staging via global_load_lds with pre-swizzled global source.
// ACT==1: relu -> bf16 out ; ACT==2: round(clip(v,0,1)+0.1) -> f32 out
template<int ACT>
__global__ __launch_bounds__(256)
void mfma_gemm_k(const short* __restrict__ A, const short* __restrict__ Bt,
                 const float* __restrict__ bias, void* __restrict__ Cout,
                 int M, int Nn, int K)
{
    __shared__ short As[128 * 64];
    __shared__ short Bs[128 * 64];
    const int tid = threadIdx.x;
    const int lane = tid & 63, wave = tid >> 6;
    const int bm0 = blockIdx.y * 128, bn0 = blockIdx.x * 128;
    const int wr = (wave >> 1) * 64, wc = (wave & 1) * 64;

    f32x4 acc[4][4] = {};

    for (int k0 = 0; k0 < K; k0 += 64) {
        // stage A tile (128x64 bf16 = 16KB = 16 chunks of 1KB) + B tile
        for (int c = wave; c < 16; c += 4) {
            int o = c * 1024 + lane * 16;       // linear LDS byte offset
            int row = o >> 7;                   // 128B per row
            int sl = (o >> 4) & 7;              // 16B slot
            int ss = sl ^ (row & 7);            // inverse-swizzled source slot
            gload_lds16(A + ((size_t)(bm0 + row) * K + k0 + ss * 8), As + c * 512);
            gload_lds16(Bt + ((size_t)(bn0 + row) * K + k0 + ss * 8), Bs + c * 512);
        }
        __syncthreads();   // drains vmcnt before barrier (compiler-emitted)
#pragma unroll
        for (int kk = 0; kk < 2; ++kk) {
            bf16x8 a[4], b[4];
            const int khalf = kk * 4 + (lane >> 4);
#pragma unroll
            for (int i = 0; i < 4; ++i) {
                int r = wr + i * 16 + (lane & 15);
                a[i] = *(const bf16x8*)(As + r * 64 + ((khalf ^ (r & 7)) << 3));
            }
#pragma unroll
            for (int j = 0; j < 4; ++j) {
                int r = wc + j * 16 + (lane & 15);
                b[j] = *(const bf16x8*)(Bs + r * 64 + ((khalf ^ (r & 7)) << 3));
            }
#pragma unroll
            for (int i = 0; i < 4; ++i)
#pragma unroll
                for (int j = 0; j < 4; ++j)
                    acc[i][j] = __builtin_amdgcn_mfma_f32_16x16x32_bf16(a[i], b[j], acc[i][j], 0, 0, 0);
        }
        __syncthreads();
    }

    const int cr = (lane >> 4) * 4;   // C/D: col=lane&15, row=(lane>>4)*4+reg
    const int cc = lane & 15;
#pragma unroll
    for (int i = 0; i < 4; ++i) {
#pragma unroll
        for (int j = 0; j < 4; ++j) {
            int col = bn0 + wc + j * 16 + cc;
            float bv = bias ? bias[col] : 0.f;
#pragma unroll
            for (int q = 0; q < 4; ++q) {
                int row = bm0 + wr + i * 16 + cr + q;
                float v = acc[i][j][q] + bv;
                if constexpr (ACT == 1) {
                    v = fmaxf(v, 0.f);
                    ((short*)Cout)[(size_t)row * Nn + col] = f2bf(v);
                } else {
                    v = rintf(fminf(fmaxf(v, 0.f), 1.f) + 0.1f);
                    ((float*)Cout)[(size_t)row * Nn + col] = v;
                }
            }
        }
    }
}

// f32 [R][C] -> bf16 transposed [C][R]
__global__ void f32_to_bf16T_k(const float* __restrict__ src, short* __restrict__ dstT,
                               int R, int C)
{
    __shared__ float t[64][65];
    const int br = blockIdx.y * 64, bc = blockIdx.x * 64;
    for (int idx = threadIdx.x; idx < 64 * 64; idx += 256) {
        int r = idx >> 6, c = idx & 63;
        t[r][c] = src[(size_t)(br + r) * C + bc + c];
    }
    __syncthreads();
    for (int idx = threadIdx.x; idx < 64 * 64; idx += 256) {
        int c = idx >> 6, r = idx & 63;
        dstT[(size_t)(bc + c) * R + br + r] = f2bf(t[r][c]);
    }
}

// packed view-bitmask -> bf16 popcount matrix (values 0..3, exact in bf16)
__global__ void mask_to_bf16_k(const unsigned* __restrict__ mask, short* __restrict__ adj,
                               int words)
{
    int t = blockIdx.x * 256 + threadIdx.x;
    if (t < words) {
        unsigned w = mask[t];
        short4v o;
        o.x = f2bf((float)__popc(w & 0x7u));
        o.y = f2bf((float)__popc(w & 0x700u));
        o.z = f2bf((float)__popc(w & 0x70000u));
        o.w = f2bf((float)__popc(w & 0x7000000u));
        *(short4v*)(adj + (size_t)t * 4) = o;
    }
}

// ---------------- generic f32 GEMM (small ops) ----------------
template<int BM, int BN, int BK, int ATY, bool BTR, int ACT>
__global__ __launch_bounds__(256)
void gemm_k(const void* __restrict__ Ap, const float* __restrict__ a_rs,
            const float* __restrict__ B, const float* __restrict__ b_rs,
            const float* __restrict__ bias, float* __restrict__ C,
            int M, int Nn, int K, int accum)
{
    constexpr int TM = BM / 16;
    constexpr int TN = BN / 16;
    __shared__ float As[BK][BM + 4];
    __shared__ float Bs[BK][BN + 4];
    const int tid = threadIdx.x;
    const int tx = tid & 15, ty = tid >> 4;
    const int bm0 = blockIdx.y * BM, bn0 = blockIdx.x * BN;

    float acc[TM][TN];
#pragma unroll
    for (int i = 0; i < TM; ++i)
#pragma unroll
        for (int j = 0; j < TN; ++j) acc[i][j] = 0.f;

    for (int k0 = 0; k0 < K; k0 += BK) {
        for (int idx = tid; idx < BM * BK; idx += 256) {
            int m = idx / BK, kk = idx % BK;
            int row = bm0 + m, kg = k0 + kk;
            float a;
            if constexpr (ATY == AT_U8) {
                a = (float)((const unsigned char*)Ap)[(size_t)row * K + kg];
            } else {
                a = ((const float*)Ap)[(size_t)row * K + kg];
            }
            if (a_rs) a *= a_rs[row];
            As[kk][m] = a;
        }
        for (int idx = tid; idx < BK * BN; idx += 256) {
            int kk = idx / BN, n = idx % BN;
            int col = bn0 + n, kg = k0 + kk;
            float b = 0.f;
            if (col < Nn) {
                b = BTR ? B[(size_t)col * K + kg] : B[(size_t)kg * Nn + col];
                if (b_rs) b *= b_rs[kg];
            }
            Bs[kk][n] = b;
        }
        __syncthreads();
#pragma unroll
        for (int kk = 0; kk < BK; ++kk) {
            float av[TM], bv[TN];
#pragma unroll
            for (int i = 0; i < TM; ++i) av[i] = As[kk][ty * TM + i];
#pragma unroll
            for (int j = 0; j < TN; ++j) bv[j] = Bs[kk][tx * TN + j];
#pragma unroll
            for (int i = 0; i < TM; ++i)
#pragma unroll
                for (int j = 0; j < TN; ++j) acc[i][j] += av[i] * bv[j];
        }
        __syncthreads();
    }

#pragma unroll
    for (int i = 0; i < TM; ++i) {
        int row = bm0 + ty * TM + i;
#pragma unroll
        for (int j = 0; j < TN; ++j) {
            int col = bn0 + tx * TN + j;
            if (col < Nn) {
                float v = acc[i][j];
                if (bias) v += bias[col];
                if (accum) v += C[(size_t)row * Nn + col];
                if constexpr (ACT == 1) v = fmaxf(v, 0.f);
                C[(size_t)row * Nn + col] = v;
            }
        }
    }
}

// ---------------- K-split u8 SpMM: part[kc] = A8[:,kc] @ (X*xs)[kc,:] ----------------
// N fixed at 64 cols. grid = (KSPLITS, M/64); each block K-chunk = K/KSPLITS.
template<int KCHUNK>
__global__ __launch_bounds__(256)
void spmm_u8_k(const unsigned char* __restrict__ A8, const float* __restrict__ X,
               const float* __restrict__ xs, float* __restrict__ part, int K, int Mtot)
{
    __shared__ float As[16][68];
    __shared__ float Bs[16][68];
    const int tid = threadIdx.x, tx = tid & 15, ty = tid >> 4;
    const int bm0 = blockIdx.y * 64;
    const int kbase = blockIdx.x * KCHUNK;
    float acc[4][4] = {};

    for (int k0 = kbase; k0 < kbase + KCHUNK; k0 += 16) {
        for (int idx = tid; idx < 64 * 16; idx += 256) {
            int m = idx >> 4, kk = idx & 15;
            As[kk][m] = (float)A8[(size_t)(bm0 + m) * K + k0 + kk];
        }
        for (int idx = tid; idx < 16 * 64; idx += 256) {
            int kk = idx >> 6, n = idx & 63;
            Bs[kk][n] = X[(size_t)(k0 + kk) * 64 + n] * xs[k0 + kk];
        }
        __syncthreads();
#pragma unroll
        for (int kk = 0; kk < 16; ++kk) {
            float av[4], bv[4];
#pragma unroll
            for (int i = 0; i < 4; ++i) av[i] = As[kk][ty * 4 + i];
#pragma unroll
            for (int j = 0; j < 4; ++j) bv[j] = Bs[kk][tx * 4 + j];
#pragma unroll
            for (int i = 0; i < 4; ++i)
#pragma unroll
                for (int j = 0; j < 4; ++j) acc[i][j] += av[i] * bv[j];
        }
        __syncthreads();
    }
    float* dst = part + (size_t)blockIdx.x * Mtot * 64;
#pragma unroll
    for (int i = 0; i < 4; ++i)
#pragma unroll
        for (int j = 0; j < 4; ++j)
            dst[(size_t)(bm0 + ty * 4 + i) * 64 + tx * 4 + j] = acc[i][j];
}

__global__ void reduce8_k(const float* __restrict__ part, float* __restrict__ out, int total)
{
    int t = blockIdx.x * 256 + threadIdx.x;
    if (t < total) {
        float s = 0.f;
        for (int p = 0; p < 8; ++p) s += part[(size_t)p * total + t];
        out[t] = s;
    }
}

// ---------------- graph-construction / per-view helpers ----------------
__global__ void mask_scatter_k(const int* __restrict__ src, const int* __restrict__ dst,
                               unsigned* __restrict__ mask, int E, int view)
{
    int t = blockIdx.x * 256 + threadIdx.x;
    if (t < E) {
        unsigned c = (unsigned)src[t] * (unsigned)NNODES + (unsigned)dst[t];
        atomicOr(&mask[c >> 2], 1u << ((c & 3u) * 8u + (unsigned)view));
    }
}

__global__ void deg_count_k(const int* __restrict__ src, const int* __restrict__ dst,
                            int* __restrict__ dout, int* __restrict__ din, int E)
{
    int t = blockIdx.x * 256 + threadIdx.x;
    if (t < E) {
        atomicAdd(&dout[src[t]], 1);
        atomicAdd(&din[dst[t]], 1);
    }
}

__global__ void deg_norm_k(const int* __restrict__ degs, float* __restrict__ isq, int n)
{
    int t = blockIdx.x * 256 + threadIdx.x;
    if (t < n) isq[t] = 1.0f / sqrtf(fmaxf((float)degs[t], 1.0f));
}

template<int F>
__global__ void scatter_add_k(const float* __restrict__ H, const int* __restrict__ src,
                              const int* __restrict__ dst, float* __restrict__ agg, int E)
{
    int t = blockIdx.x * 256 + threadIdx.x;
    int e = t / F, f = t % F;
    if (e < E) {
        atomicAdd(&agg[(size_t)dst[e] * F + f], H[(size_t)src[e] * F + f]);
    }
}

template<int F, int ACT>
__global__ void sba_k(const float* __restrict__ agg, const float* __restrict__ rs,
                      const float* __restrict__ bias, float* __restrict__ out, int total)
{
    int t = blockIdx.x * 256 + threadIdx.x;
    if (t < total) {
        int i = t / F, f = t % F;
        float v = agg[t] * rs[i] + bias[f];
        if (ACT) v = fmaxf(v, 0.f);
        out[t] = v;
    }
}

__global__ void softmax64_k(float* __restrict__ z)
{
    int row = blockIdx.x * 4 + (threadIdx.x >> 6);
    int f = threadIdx.x & 63;
    float v = z[(size_t)row * 64 + f];
    float m = v;
#pragma unroll
    for (int off = 32; off >= 1; off >>= 1) m = fmaxf(m, __shfl_xor(m, off));
    float e = expf(v - m);
    float s = e;
#pragma unroll
    for (int off = 32; off >= 1; off >>= 1) s += __shfl_xor(s, off);
    z[(size_t)row * 64 + f] = e / s;
}

__global__ void build_A_k(const float* __restrict__ adjr, unsigned char* __restrict__ A,
                          int* __restrict__ deg)
{
    __shared__ float Tji[64][65];
    const int bi = blockIdx.y * 64, bj = blockIdx.x * 64;
    for (int idx = threadIdx.x; idx < 4096; idx += 256) {
        int r = idx >> 6, c = idx & 63;
        Tji[r][c] = adjr[(size_t)(bj + r) * NNODES + bi + c];
    }
    __syncthreads();
    int i = threadIdx.x >> 2;
    int j0 = (threadIdx.x & 3) * 16;
    int psum = 0;
    for (int jj = 0; jj < 16; ++jj) {
        int j = j0 + jj;
        float a = adjr[(size_t)(bi + i) * NNODES + bj + j];
        float b = Tji[j][i];
        int on = (a > 0.5f) | (b > 0.5f) | ((bi + i) == (bj + j));
        A[(size_t)(bi + i) * NNODES + bj + j] = (unsigned char)on;
        psum += on;
    }
    atomicAdd(&deg[bi + i], psum);
}

__global__ void dn_k(const int* __restrict__ deg, float* __restrict__ dn, int n)
{
    int t = blockIdx.x * 256 + threadIdx.x;
    if (t < n) dn[t] = 1.0f / sqrtf((float)deg[t]);
}

extern "C" void kernel_launch(void* const* d_in, const int* in_sizes, int n_in,
                              void* d_out, int out_size, void* d_ws, size_t ws_size,
                              hipStream_t stream)
{
    const int N = NNODES, E = NEDGES;

    const float* x[3]; const int* src[3]; const int* dst[3];
    const float *Wv0[3], *bv0[3], *Wv1[3], *bv1[3], *Wf[3];
    for (int v = 0; v < 3; ++v) {
        const int b = v * 8;
        x[v]   = (const float*)d_in[b + 0];
        src[v] = (const int*)  d_in[b + 1];
        dst[v] = (const int*)  d_in[b + 2];
        Wv0[v] = (const float*)d_in[b + 3];
        bv0[v] = (const float*)d_in[b + 4];
        Wv1[v] = (const float*)d_in[b + 5];
        bv1[v] = (const float*)d_in[b + 6];
        Wf[v]  = (const float*)d_in[b + 7];
    }
    const float* Wg1 = (const float*)d_in[24];
    const float* bg1 = (const float*)d_in[25];
    const float* Wg2 = (const float*)d_in[26];
    const float* bg2 = (const float*)d_in[27];
    const float* Wm0 = (const float*)d_in[28];
    const float* bm0 = (const float*)d_in[29];
    const float* Wm1 = (const float*)d_in[30];
    const float* bm1 = (const float*)d_in[31];

    float* out_adjr = (float*)d_out;                    // [N,N] f32 (final)
    float* out_rec  = out_adjr + (size_t)N * N;         // [N,N] f32 (final; scratch until then)
    float* out_h    = out_rec + (size_t)N * N;          // [N,64]

    // scratch carved from dead output regions:
    short* AdjB  = (short*)out_adjr;                    // bf16 [N][N] (32MB) - dead before GEMM2 writes
    short* H1b   = (short*)out_rec;                     // bf16 [N][2048] (16MB)
    short* Wg1T  = (short*)out_rec + (size_t)8 * 1024 * 1024;   // bf16 [2048][4096] (16MB)
    short* Wg2T  = (short*)out_rec + (size_t)16 * 1024 * 1024;  // bf16 [4096][2048] (16MB)
    float* part  = (float*)((char*)out_rec + (size_t)48 * 1024 * 1024); // 8MB partials

    // ---- workspace carve ----
    char* p = (char*)d_ws;
    unsigned* mask = (unsigned*)p;                      // 16 MB; reused as A8 later
    unsigned char* A8 = (unsigned char*)p;
    p += (size_t)N * N;
    int* degs = (int*)p;       p += (size_t)6 * N * 4;
    float* isq = (float*)p;    p += (size_t)6 * N * 4;
    float* hv1 = (float*)p;    p += (size_t)N * 128 * 4;
    float* agg1 = (float*)p;   p += (size_t)N * 128 * 4;
    float* hv2 = (float*)p;    p += (size_t)N * 64 * 4;
    float* agg2 = (float*)p;   p += (size_t)N * 64 * 4;
    float* feat = (float*)p;   p += (size_t)N * 64 * 4;
    float* z = (float*)p;      p += (size_t)N * 64 * 4;
    float* t1 = (float*)p;     p += (size_t)N * 64 * 4;
    float* h1m = (float*)p;    p += (size_t)N * 64 * 4;
    int* degA = (int*)p;       p += (size_t)N * 4;
    float* dnv = (float*)p;    p += (size_t)N * 4;

    hipMemsetAsync(mask, 0, (size_t)N * N, stream);
    hipMemsetAsync(degs, 0, (size_t)6 * N * 4, stream);

    for (int v = 0; v < 3; ++v) {
        mask_scatter_k<<<(E + 255) / 256, 256, 0, stream>>>(src[v], dst[v], mask, E, v);
        deg_count_k<<<(E + 255) / 256, 256, 0, stream>>>(src[v], dst[v],
                                                          degs + 2 * v * N, degs + (2 * v + 1) * N, E);
    }
    deg_norm_k<<<(6 * N + 255) / 256, 256, 0, stream>>>(degs, isq, 6 * N);

    // bf16 conversions for the GFN path
    f32_to_bf16T_k<<<dim3(2048 / 64, 4096 / 64), 256, 0, stream>>>(Wg1, Wg1T, 4096, 2048);
    f32_to_bf16T_k<<<dim3(4096 / 64, 2048 / 64), 256, 0, stream>>>(Wg2, Wg2T, 2048, 4096);
    mask_to_bf16_k<<<(N * N / 4 + 255) / 256, 256, 0, stream>>>(mask, AdjB, N * N / 4);

    // per-view GCN stacks (f32)
    for (int v = 0; v < 3; ++v) {
        const float* doi = isq + 2 * v * N;
        const float* dii = isq + (2 * v + 1) * N;
        gemm_k<64, 64, 16, AT_F32, false, 0><<<dim3(2, N / 64), 256, 0, stream>>>(
            x[v], doi, Wv0[v], nullptr, nullptr, hv1, N, 128, 512, 0);
        hipMemsetAsync(agg1, 0, (size_t)N * 128 * 4, stream);
        scatter_add_k<128><<<E * 128 / 256, 256, 0, stream>>>(hv1, src[v], dst[v], agg1, E);
        sba_k<128, 1><<<N * 128 / 256, 256, 0, stream>>>(agg1, dii, bv0[v], hv1, N * 128);
        gemm_k<64, 64, 16, AT_F32, false, 0><<<dim3(1, N / 64), 256, 0, stream>>>(
            hv1, doi, Wv1[v], nullptr, nullptr, hv2, N, 64, 128, 0);
        hipMemsetAsync(agg2, 0, (size_t)N * 64 * 4, stream);
        scatter_add_k<64><<<E * 64 / 256, 256, 0, stream>>>(hv2, src[v], dst[v], agg2, E);
        sba_k<64, 0><<<N * 64 / 256, 256, 0, stream>>>(agg2, dii, bv1[v], feat, N * 64);
        gemm_k<64, 64, 16, AT_F32, false, 0><<<dim3(1, N / 64), 256, 0, stream>>>(
            feat, nullptr, Wf[v], nullptr, nullptr, z, N, 64, 64, v > 0 ? 1 : 0);
    }
    softmax64_k<<<N / 4, 256, 0, stream>>>(z);

    // GFN on MFMA: H1b = relu(Adj @ Wg1 + bg1) -> bf16 [4096][2048]
    mfma_gemm_k<1><<<dim3(2048 / 128, 4096 / 128), 256, 0, stream>>>(
        AdjB, Wg1T, bg1, H1b, 4096, 2048, 4096);
    // adj_r = round(clip(H1 @ Wg2 + bg2, 0, 1) + 0.1) -> f32 [4096][4096]
    mfma_gemm_k<2><<<dim3(4096 / 128, 4096 / 128), 256, 0, stream>>>(
        H1b, Wg2T, bg2, out_adjr, 4096, 4096, 2048);

    // A = sym(adj_r)>0 | I ; deg ; dn
    hipMemsetAsync(degA, 0, (size_t)N * 4, stream);
    build_A_k<<<dim3(N / 64, N / 64), 256, 0, stream>>>(out_adjr, A8, degA);
    dn_k<<<(N + 255) / 256, 256, 0, stream>>>(degA, dnv, N);

    // fused-graph GCN with K-split SpMM (8 chunks of 512)
    spmm_u8_k<512><<<dim3(8, N / 64), 256, 0, stream>>>(A8, z, dnv, part, N, N);
    reduce8_k<<<(N * 64 + 255) / 256, 256, 0, stream>>>(part, t1, N * 64);
    gemm_k<64, 64, 16, AT_F32, false, 1><<<dim3(1, N / 64), 256, 0, stream>>>(
        t1, dnv, Wm0, nullptr, bm0, h1m, N, 64, 64, 0);
    spmm_u8_k<512><<<dim3(8, N / 64), 256, 0, stream>>>(A8, h1m, dnv, part, N, N);
    reduce8_k<<<(N * 64 + 255) / 256, 256, 0, stream>>>(part, t1, N * 64);
    gemm_k<64, 64, 16, AT_F32, false, 0><<<dim3(1, N / 64), 256, 0, stream>>>(
        t1, dnv, Wm1, nullptr, bm1, out_h, N, 64, 64, 0);

    // adj_rec = h @ h.T (f32, K=64) - overwrites all scratch in out_rec
    gemm_k<128, 128, 16, AT_F32, true, 0><<<dim3(N / 128, N / 128), 256, 0, stream>>>(
        out_h, nullptr, out_h, nullptr, nullptr, out_rec, N, N, 64, 0);
}

// Round 3
// 655.187 us; speedup vs baseline: 7.3761x; 1.9001x over previous
//
#include <hip/hip_runtime.h>
#include <math.h>

#define NNODES 4096
#define NEDGES 65536

enum { AT_F32 = 0, AT_U8 = 2 };

typedef short bf16x8 __attribute__((ext_vector_type(8)));
typedef short short4v __attribute__((ext_vector_type(4)));
typedef float f32x4 __attribute__((ext_vector_type(4)));

struct Ptr3  { const float* p[3]; };
struct Ptr3i { const int*   p[3]; };
struct Out3  { float*       p[3]; };

__device__ __forceinline__ short f2bf(float f) {
    unsigned u = __builtin_bit_cast(unsigned, f);
    unsigned r = (u + 0x7FFFu + ((u >> 16) & 1u)) >> 16;
    return (short)r;
}

__device__ __forceinline__ void gload_lds16(const void* g, void* l) {
    __builtin_amdgcn_global_load_lds(
        (const __attribute__((address_space(1))) unsigned*)g,
        (__attribute__((address_space(3))) unsigned*)l, 16, 0, 0);
}

// ---------------- bf16 MFMA GEMM: C = act(A @ B^T + bias) ----------------
// A bf16 [M][K] row-major, Bt bf16 [Nn][K] row-major. 128x128 tile, BK=64.
// ACT==0: f32 out ; ACT==1: relu -> bf16 out ; ACT==2: round(clip+0.1) -> f32 out (+u8 P)
template<int ACT>
__global__ __launch_bounds__(256)
void mfma_gemm_k(const short* __restrict__ A, const short* __restrict__ Bt,
                 const float* __restrict__ bias, void* __restrict__ Cout,
                 unsigned char* __restrict__ Pout,
                 int M, int Nn, int K)
{
    __shared__ short As[128 * 64];
    __shared__ short Bs[128 * 64];
    const int tid = threadIdx.x;
    const int lane = tid & 63, wave = tid >> 6;
    // XCD-bijective swizzle (grid size always %8==0 here)
    const int gx = gridDim.x, nwg = gx * gridDim.y;
    int w = blockIdx.y * gx + blockIdx.x;
    const int q = nwg >> 3;
    w = (w & 7) * q + (w >> 3);
    const int bm0 = (w / gx) * 128, bn0 = (w % gx) * 128;
    const int wr = (wave >> 1) * 64, wc = (wave & 1) * 64;

    f32x4 acc[4][4] = {};

    for (int k0 = 0; k0 < K; k0 += 64) {
        for (int c = wave; c < 16; c += 4) {
            int o = c * 1024 + lane * 16;
            int row = o >> 7;
            int sl = (o >> 4) & 7;
            int ss = sl ^ (row & 7);
            gload_lds16(A + ((size_t)(bm0 + row) * K + k0 + ss * 8), As + c * 512);
            gload_lds16(Bt + ((size_t)(bn0 + row) * K + k0 + ss * 8), Bs + c * 512);
        }
        __syncthreads();
#pragma unroll
        for (int kk = 0; kk < 2; ++kk) {
            bf16x8 a[4], b[4];
            const int khalf = kk * 4 + (lane >> 4);
#pragma unroll
            for (int i = 0; i < 4; ++i) {
                int r = wr + i * 16 + (lane & 15);
                a[i] = *(const bf16x8*)(As + r * 64 + ((khalf ^ (r & 7)) << 3));
            }
#pragma unroll
            for (int j = 0; j < 4; ++j) {
                int r = wc + j * 16 + (lane & 15);
                b[j] = *(const bf16x8*)(Bs + r * 64 + ((khalf ^ (r & 7)) << 3));
            }
#pragma unroll
            for (int i = 0; i < 4; ++i)
#pragma unroll
                for (int j = 0; j < 4; ++j)
                    acc[i][j] = __builtin_amdgcn_mfma_f32_16x16x32_bf16(a[i], b[j], acc[i][j], 0, 0, 0);
        }
        __syncthreads();
    }

    const int cr = (lane >> 4) * 4;
    const int cc = lane & 15;
#pragma unroll
    for (int i = 0; i < 4; ++i) {
#pragma unroll
        for (int j = 0; j < 4; ++j) {
            int col = bn0 + wc + j * 16 + cc;
            float bv = bias ? bias[col] : 0.f;
#pragma unroll
            for (int q2 = 0; q2 < 4; ++q2) {
                int row = bm0 + wr + i * 16 + cr + q2;
                float v = acc[i][j][q2] + bv;
                if constexpr (ACT == 1) {
                    v = fmaxf(v, 0.f);
                    ((short*)Cout)[(size_t)row * Nn + col] = f2bf(v);
                } else if constexpr (ACT == 2) {
                    v = rintf(fminf(fmaxf(v, 0.f), 1.f) + 0.1f);
                    ((float*)Cout)[(size_t)row * Nn + col] = v;
                    Pout[(size_t)row * Nn + col] = (unsigned char)(v > 0.5f);
                } else {
                    ((float*)Cout)[(size_t)row * Nn + col] = v;
                }
            }
        }
    }
}

// f32 [R][C] -> bf16 transposed [C][R]
__global__ void f32_to_bf16T_k(const float* __restrict__ src, short* __restrict__ dstT,
                               int R, int C)
{
    __shared__ float t[64][65];
    const int br = blockIdx.y * 64, bc = blockIdx.x * 64;
    for (int idx = threadIdx.x; idx < 64 * 64; idx += 256) {
        int r = idx >> 6, c = idx & 63;
        t[r][c] = src[(size_t)(br + r) * C + bc + c];
    }
    __syncthreads();
    for (int idx = threadIdx.x; idx < 64 * 64; idx += 256) {
        int c = idx >> 6, r = idx & 63;
        dstT[(size_t)(bc + c) * R + br + r] = f2bf(t[r][c]);
    }
}

__global__ void mask_to_bf16_k(const unsigned* __restrict__ mask, short* __restrict__ adj,
                               int words)
{
    int t = blockIdx.x * 256 + threadIdx.x;
    if (t < words) {
        unsigned w = mask[t];
        short4v o;
        o.x = f2bf((float)__popc(w & 0x7u));
        o.y = f2bf((float)__popc(w & 0x700u));
        o.z = f2bf((float)__popc(w & 0x70000u));
        o.w = f2bf((float)__popc(w & 0x7000000u));
        *(short4v*)(adj + (size_t)t * 4) = o;
    }
}

// ---------------- generic f32 GEMM (small ops: Wm0/Wm1) ----------------
template<int BM, int BN, int BK, int ATY, bool BTR, int ACT>
__global__ __launch_bounds__(256)
void gemm_k(const void* __restrict__ Ap, const float* __restrict__ a_rs,
            const float* __restrict__ B, const float* __restrict__ b_rs,
            const float* __restrict__ bias, float* __restrict__ C,
            int M, int Nn, int K, int accum)
{
    constexpr int TM = BM / 16;
    constexpr int TN = BN / 16;
    __shared__ float As[BK][BM + 4];
    __shared__ float Bs[BK][BN + 4];
    const int tid = threadIdx.x;
    const int tx = tid & 15, ty = tid >> 4;
    const int bm0 = blockIdx.y * BM, bn0 = blockIdx.x * BN;

    float acc[TM][TN];
#pragma unroll
    for (int i = 0; i < TM; ++i)
#pragma unroll
        for (int j = 0; j < TN; ++j) acc[i][j] = 0.f;

    for (int k0 = 0; k0 < K; k0 += BK) {
        for (int idx = tid; idx < BM * BK; idx += 256) {
            int m = idx / BK, kk = idx % BK;
            int row = bm0 + m, kg = k0 + kk;
            float a;
            if constexpr (ATY == AT_U8) {
                a = (float)((const unsigned char*)Ap)[(size_t)row * K + kg];
            } else {
                a = ((const float*)Ap)[(size_t)row * K + kg];
            }
            if (a_rs) a *= a_rs[row];
            As[kk][m] = a;
        }
        for (int idx = tid; idx < BK * BN; idx += 256) {
            int kk = idx / BN, n = idx % BN;
            int col = bn0 + n, kg = k0 + kk;
            float b = 0.f;
            if (col < Nn) {
                b = BTR ? B[(size_t)col * K + kg] : B[(size_t)kg * Nn + col];
                if (b_rs) b *= b_rs[kg];
            }
            Bs[kk][n] = b;
        }
        __syncthreads();
#pragma unroll
        for (int kk = 0; kk < BK; ++kk) {
            float av[TM], bv[TN];
#pragma unroll
            for (int i = 0; i < TM; ++i) av[i] = As[kk][ty * TM + i];
#pragma unroll
            for (int j = 0; j < TN; ++j) bv[j] = Bs[kk][tx * TN + j];
#pragma unroll
            for (int i = 0; i < TM; ++i)
#pragma unroll
                for (int j = 0; j < TN; ++j) acc[i][j] += av[i] * bv[j];
        }
        __syncthreads();
    }

#pragma unroll
    for (int i = 0; i < TM; ++i) {
        int row = bm0 + ty * TM + i;
#pragma unroll
        for (int j = 0; j < TN; ++j) {
            int col = bn0 + tx * TN + j;
            if (col < Nn) {
                float v = acc[i][j];
                if (bias) v += bias[col];
                if (accum) v += C[(size_t)row * Nn + col];
                if constexpr (ACT == 1) v = fmaxf(v, 0.f);
                C[(size_t)row * Nn + col] = v;
            }
        }
    }
}

// ---------------- batched (z=view) f32 GEMM: C[z] = (A[z]*rs[z]) @ B[z] ----------------
template<int BM, int BN, int BK>
__global__ __launch_bounds__(256)
void gemm_b_k(Ptr3 Av, Ptr3 RSv, Ptr3 Bv, Out3 Cv, int Nn, int K)
{
    constexpr int TM = BM / 16;
    constexpr int TN = BN / 16;
    __shared__ float As[BK][BM + 4];
    __shared__ float Bs[BK][BN + 4];
    const int z = blockIdx.z;
    const float* A = Av.p[z];
    const float* rs = RSv.p[z];
    const float* B = Bv.p[z];
    float* C = Cv.p[z];
    const int tid = threadIdx.x;
    const int tx = tid & 15, ty = tid >> 4;
    const int bm0 = blockIdx.y * BM, bn0 = blockIdx.x * BN;

    float acc[TM][TN];
#pragma unroll
    for (int i = 0; i < TM; ++i)
#pragma unroll
        for (int j = 0; j < TN; ++j) acc[i][j] = 0.f;

    for (int k0 = 0; k0 < K; k0 += BK) {
        for (int idx = tid; idx < BM * BK; idx += 256) {
            int m = idx / BK, kk = idx % BK;
            float a = A[(size_t)(bm0 + m) * K + k0 + kk];
            if (rs) a *= rs[bm0 + m];
            As[kk][m] = a;
        }
        for (int idx = tid; idx < BK * BN; idx += 256) {
            int kk = idx / BN, n = idx % BN;
            int col = bn0 + n;
            Bs[kk][n] = (col < Nn) ? B[(size_t)(k0 + kk) * Nn + col] : 0.f;
        }
        __syncthreads();
#pragma unroll
        for (int kk = 0; kk < BK; ++kk) {
            float av[TM], bv[TN];
#pragma unroll
            for (int i = 0; i < TM; ++i) av[i] = As[kk][ty * TM + i];
#pragma unroll
            for (int j = 0; j < TN; ++j) bv[j] = Bs[kk][tx * TN + j];
#pragma unroll
            for (int i = 0; i < TM; ++i)
#pragma unroll
                for (int j = 0; j < TN; ++j) acc[i][j] += av[i] * bv[j];
        }
        __syncthreads();
    }

#pragma unroll
    for (int i = 0; i < TM; ++i) {
        int row = bm0 + ty * TM + i;
#pragma unroll
        for (int j = 0; j < TN; ++j) {
            int col = bn0 + tx * TN + j;
            if (col < Nn) C[(size_t)row * Nn + col] = acc[i][j];
        }
    }
}

// ---------------- K-split u8 SpMM ----------------
template<int KCHUNK>
__global__ __launch_bounds__(256)
void spmm_u8_k(const unsigned char* __restrict__ A8, const float* __restrict__ X,
               const float* __restrict__ xs, float* __restrict__ part, int K, int Mtot)
{
    __shared__ float As[16][68];
    __shared__ float Bs[16][68];
    const int tid = threadIdx.x, tx = tid & 15, ty = tid >> 4;
    const int bm0 = blockIdx.y * 64;
    const int kbase = blockIdx.x * KCHUNK;
    float acc[4][4] = {};

    for (int k0 = kbase; k0 < kbase + KCHUNK; k0 += 16) {
        for (int idx = tid; idx < 64 * 16; idx += 256) {
            int m = idx >> 4, kk = idx & 15;
            As[kk][m] = (float)A8[(size_t)(bm0 + m) * K + k0 + kk];
        }
        for (int idx = tid; idx < 16 * 64; idx += 256) {
            int kk = idx >> 6, n = idx & 63;
            Bs[kk][n] = X[(size_t)(k0 + kk) * 64 + n] * xs[k0 + kk];
        }
        __syncthreads();
#pragma unroll
        for (int kk = 0; kk < 16; ++kk) {
            float av[4], bv[4];
#pragma unroll
            for (int i = 0; i < 4; ++i) av[i] = As[kk][ty * 4 + i];
#pragma unroll
            for (int j = 0; j < 4; ++j) bv[j] = Bs[kk][tx * 4 + j];
#pragma unroll
            for (int i = 0; i < 4; ++i)
#pragma unroll
                for (int j = 0; j < 4; ++j) acc[i][j] += av[i] * bv[j];
        }
        __syncthreads();
    }
    float* dst = part + (size_t)blockIdx.x * Mtot * 64;
#pragma unroll
    for (int i = 0; i < 4; ++i)
#pragma unroll
        for (int j = 0; j < 4; ++j)
            dst[(size_t)(bm0 + ty * 4 + i) * 64 + tx * 4 + j] = acc[i][j];
}

__global__ void reduce8_k(const float* __restrict__ part, float* __restrict__ out, int total)
{
    int t = blockIdx.x * 256 + threadIdx.x;
    if (t < total) {
        float s = 0.f;
        for (int p = 0; p < 8; ++p) s += part[(size_t)p * total + t];
        out[t] = s;
    }
}

// ---------------- graph construction ----------------
// batched: adjacency mask bit + raw in/out degrees
__global__ void edge_k(Ptr3i src, Ptr3i dst, unsigned* __restrict__ mask, int* __restrict__ degs)
{
    int e = blockIdx.x * 256 + threadIdx.x;
    int z = blockIdx.y;
    if (e < NEDGES) {
        int s = src.p[z][e], d = dst.p[z][e];
        unsigned c = (unsigned)s * (unsigned)NNODES + (unsigned)d;
        atomicOr(&mask[c >> 2], 1u << ((c & 3u) * 8u + (unsigned)z));
        atomicAdd(&degs[2 * z * NNODES + s], 1);
        atomicAdd(&degs[(2 * z + 1) * NNODES + d], 1);
    }
}

__global__ void deg_norm_k(const int* __restrict__ degs, float* __restrict__ isq, int n)
{
    int t = blockIdx.x * 256 + threadIdx.x;
    if (t < n) isq[t] = 1.0f / sqrtf(fmaxf((float)degs[t], 1.0f));
}

// per-view exclusive scan of in-degrees -> rowptr (+ cursor copy). 1 block per view.
__global__ __launch_bounds__(1024)
void scan_k(const int* __restrict__ degs, int* __restrict__ rowptr, int* __restrict__ cursor)
{
    const int z = blockIdx.x;
    const int* din = degs + (2 * z + 1) * NNODES;
    __shared__ int sm[1024];
    const int t = threadIdx.x;
    int v0 = din[t * 4], v1 = din[t * 4 + 1], v2 = din[t * 4 + 2], v3 = din[t * 4 + 3];
    int c1 = v0 + v1, c2 = c1 + v2, s = c2 + v3;
    sm[t] = s;
    __syncthreads();
    for (int off = 1; off < 1024; off <<= 1) {
        int add = (t >= off) ? sm[t - off] : 0;
        __syncthreads();
        sm[t] += add;
        __syncthreads();
    }
    int base = sm[t] - s;
    int* rp = rowptr + z * NNODES;
    int* cu = cursor + z * NNODES;
    rp[t * 4] = base;          cu[t * 4] = base;
    rp[t * 4 + 1] = base + v0; cu[t * 4 + 1] = base + v0;
    rp[t * 4 + 2] = base + c1; cu[t * 4 + 2] = base + c1;
    rp[t * 4 + 3] = base + c2; cu[t * 4 + 3] = base + c2;
}

__global__ void fill_k(Ptr3i src, Ptr3i dst, int* __restrict__ cursor, int* __restrict__ eidx)
{
    int e = blockIdx.x * 256 + threadIdx.x;
    int z = blockIdx.y;
    if (e < NEDGES) {
        int d = dst.p[z][e];
        int pos = atomicAdd(&cursor[z * NNODES + d], 1);
        eidx[(size_t)z * NEDGES + pos] = src.p[z][e];
    }
}

// fused CSR-gather + norm + bias + act:  out[n,f] = act(dii[n]*sum_{e in CSR[n]} H[src_e,f] + b[f])
template<int F, int ACT>
__global__ void gather_k(const float* __restrict__ Hpre, const int* __restrict__ eidx,
                         const int* __restrict__ rowptr, const int* __restrict__ degs,
                         const float* __restrict__ isq, Ptr3 bias, float* __restrict__ Hout)
{
    const int z = blockIdx.y;
    const int tid = threadIdx.x;
    const int node = blockIdx.x * (256 / F) + tid / F;
    const int f = tid % F;
    const float* H = Hpre + (size_t)z * NNODES * F;
    const int base = rowptr[z * NNODES + node];
    const int cnt = degs[(2 * z + 1) * NNODES + node];
    const int* ei = eidx + (size_t)z * NEDGES + base;
    float s = 0.f;
    for (int i = 0; i < cnt; ++i) s += H[(size_t)ei[i] * F + f];
    float v = s * isq[(2 * z + 1) * NNODES + node] + bias.p[z][f];
    if (ACT) v = fmaxf(v, 0.f);
    Hout[(size_t)z * NNODES * F + (size_t)node * F + f] = v;
}

// z = softmax_row(zp0+zp1+zp2)
__global__ void softsum_k(const float* __restrict__ zp, float* __restrict__ z)
{
    int row = blockIdx.x * 4 + (threadIdx.x >> 6);
    int f = threadIdx.x & 63;
    size_t i = (size_t)row * 64 + f;
    float v = zp[i] + zp[i + (size_t)NNODES * 64] + zp[i + (size_t)2 * NNODES * 64];
    float m = v;
#pragma unroll
    for (int off = 32; off >= 1; off >>= 1) m = fmaxf(m, __shfl_xor(m, off));
    float e = expf(v - m);
    float s = e;
#pragma unroll
    for (int off = 32; off >= 1; off >>= 1) s += __shfl_xor(s, off);
    z[i] = e / s;
}

// A8[i,j] = P[i,j] | P[j,i] | (i==j), deg row-sums. All uint4 traffic.
__global__ __launch_bounds__(256)
void build_A2_k(const unsigned char* __restrict__ P, unsigned char* __restrict__ A8,
                int* __restrict__ degA)
{
    __shared__ unsigned Ts[64][20];
    const int bi = blockIdx.y * 64, bj = blockIdx.x * 64;
    const int tid = threadIdx.x;
    const int r = tid >> 2, seg = tid & 3;
    uint4 tv = *(const uint4*)(P + (size_t)(bj + r) * NNODES + bi + seg * 16);
    Ts[r][seg * 4 + 0] = tv.x; Ts[r][seg * 4 + 1] = tv.y;
    Ts[r][seg * 4 + 2] = tv.z; Ts[r][seg * 4 + 3] = tv.w;
    __syncthreads();
    uint4 dv = *(const uint4*)(P + (size_t)(bi + r) * NNODES + bj + seg * 16);
    unsigned dw[4] = {dv.x, dv.y, dv.z, dv.w};
    const unsigned char* Tb = (const unsigned char*)Ts;
    unsigned ow[4];
    int psum = 0;
#pragma unroll
    for (int w = 0; w < 4; ++w) {
        unsigned o = 0;
#pragma unroll
        for (int b = 0; b < 4; ++b) {
            int j = seg * 16 + w * 4 + b;
            unsigned a = (dw[w] >> (8 * b)) & 1u;
            unsigned tr = Tb[j * 80 + r] & 1u;
            unsigned on = a | tr | (unsigned)((bi + r) == (bj + j));
            o |= on << (8 * b);
            psum += (int)on;
        }
        ow[w] = o;
    }
    uint4 o4; o4.x = ow[0]; o4.y = ow[1]; o4.z = ow[2]; o4.w = ow[3];
    *(uint4*)(A8 + (size_t)(bi + r) * NNODES + bj + seg * 16) = o4;
    psum += __shfl_xor(psum, 1);
    psum += __shfl_xor(psum, 2);
    if (seg == 0) atomicAdd(&degA[bi + r], psum);
}

__global__ void dn_k(const int* __restrict__ deg, float* __restrict__ dn, int n)
{
    int t = blockIdx.x * 256 + threadIdx.x;
    if (t < n) dn[t] = 1.0f / sqrtf((float)deg[t]);
}

// h (f32 [N][64]) -> split-bf16 extended operands for h@h^T on MFMA:
// Ae row = [hi | hi | lo], Be row = [hi | lo | hi]  (K=192)
__global__ void he_build_k(const float* __restrict__ h, short* __restrict__ Ae,
                           short* __restrict__ Be)
{
    int t = blockIdx.x * 256 + threadIdx.x;
    if (t < NNODES * 64) {
        int r = t >> 6, c = t & 63;
        float v = h[t];
        short hi = f2bf(v);
        float hif = __builtin_bit_cast(float, ((unsigned)(unsigned short)hi) << 16);
        short lo = f2bf(v - hif);
        size_t ro = (size_t)r * 192;
        Ae[ro + c] = hi; Ae[ro + 64 + c] = hi; Ae[ro + 128 + c] = lo;
        Be[ro + c] = hi; Be[ro + 64 + c] = lo; Be[ro + 128 + c] = hi;
    }
}

extern "C" void kernel_launch(void* const* d_in, const int* in_sizes, int n_in,
                              void* d_out, int out_size, void* d_ws, size_t ws_size,
                              hipStream_t stream)
{
    const int N = NNODES, E = NEDGES;

    const float* x[3]; const int* src[3]; const int* dst[3];
    const float *Wv0[3], *bv0[3], *Wv1[3], *bv1[3], *Wf[3];
    for (int v = 0; v < 3; ++v) {
        const int b = v * 8;
        x[v]   = (const float*)d_in[b + 0];
        src[v] = (const int*)  d_in[b + 1];
        dst[v] = (const int*)  d_in[b + 2];
        Wv0[v] = (const float*)d_in[b + 3];
        bv0[v] = (const float*)d_in[b + 4];
        Wv1[v] = (const float*)d_in[b + 5];
        bv1[v] = (const float*)d_in[b + 6];
        Wf[v]  = (const float*)d_in[b + 7];
    }
    const float* Wg1 = (const float*)d_in[24];
    const float* bg1 = (const float*)d_in[25];
    const float* Wg2 = (const float*)d_in[26];
    const float* bg2 = (const float*)d_in[27];
    const float* Wm0 = (const float*)d_in[28];
    const float* bm0 = (const float*)d_in[29];
    const float* Wm1 = (const float*)d_in[30];
    const float* bm1 = (const float*)d_in[31];

    float* out_adjr = (float*)d_out;                    // [N,N] f32 (final)
    float* out_rec  = out_adjr + (size_t)N * N;         // [N,N] f32 (final; scratch until then)
    float* out_h    = out_rec + (size_t)N * N;          // [N,64]

    // scratch carved from dead output regions:
    short* AdjB = (short*)out_adjr;                                  // bf16 [N][N], dead before GEMM2
    short* H1b  = (short*)out_rec;                                   // bf16 [N][2048], +0..16MB
    unsigned char* P = (unsigned char*)((char*)out_rec + (size_t)16 * 1024 * 1024); // u8 [N][N] (over Wg1T after GEMM1)
    short* Wg1T = (short*)((char*)out_rec + (size_t)16 * 1024 * 1024);
    short* Wg2T = (short*)((char*)out_rec + (size_t)32 * 1024 * 1024);
    float* part = (float*)((char*)out_rec + (size_t)48 * 1024 * 1024); // 8MB K-split partials

    // ---- workspace carve (~32 MB) ----
    char* p = (char*)d_ws;
    unsigned* mask = (unsigned*)p;
    unsigned char* A8 = (unsigned char*)p;              // reuses mask region
    p += (size_t)N * N;                                 // 16MB
    int* degs = (int*)p;     p += (size_t)6 * N * 4;
    float* isq = (float*)p;  p += (size_t)6 * N * 4;
    int* rowptr = (int*)p;   p += (size_t)3 * N * 4;
    int* cursor = (int*)p;   p += (size_t)3 * N * 4;
    int* eidx = (int*)p;     p += (size_t)3 * E * 4;
    int* degA = (int*)p;     p += (size_t)N * 4;
    float* dnv = (float*)p;  p += (size_t)N * 4;
    float* zbuf = (float*)p; p += (size_t)N * 64 * 4;
    float* t1 = (float*)p;   p += (size_t)N * 64 * 4;
    float* h1m = (float*)p;  p += (size_t)N * 64 * 4;
    float* slab1 = (float*)p; p += (size_t)3 * N * 128 * 4;  // hv1 -> hv2 -> zp -> Ae/Be
    float* slab2 = (float*)p; p += (size_t)3 * N * 128 * 4;  // h1o -> feat

    float* hv1 = slab1;              // [3][N][128] pre-agg layer1
    float* hv2 = slab1;              // [3][N][64]  pre-agg layer2 (after hv1 dead)
    float* zp  = slab1;              // [3][N][64]  fusion partials (after hv2 dead)
    short* Ae  = (short*)slab1;      // [N][192] (after zp dead)
    short* Be  = (short*)slab1 + (size_t)N * 192;
    float* h1o  = slab2;             // [3][N][128] post-agg layer1
    float* feat = slab2;             // [3][N][64]  post-agg layer2 (after h1o dead)

    Ptr3i srcP, dstP;
    for (int v = 0; v < 3; ++v) { srcP.p[v] = src[v]; dstP.p[v] = dst[v]; }

    hipMemsetAsync(mask, 0, (size_t)N * N, stream);
    hipMemsetAsync(degs, 0, (size_t)6 * N * 4, stream);

    edge_k<<<dim3((E + 255) / 256, 3), 256, 0, stream>>>(srcP, dstP, mask, degs);
    deg_norm_k<<<(6 * N + 255) / 256, 256, 0, stream>>>(degs, isq, 6 * N);
    scan_k<<<3, 1024, 0, stream>>>(degs, rowptr, cursor);
    fill_k<<<dim3((E + 255) / 256, 3), 256, 0, stream>>>(srcP, dstP, cursor, eidx);

    // bf16 conversions for the GFN path
    f32_to_bf16T_k<<<dim3(2048 / 64, 4096 / 64), 256, 0, stream>>>(Wg1, Wg1T, 4096, 2048);
    f32_to_bf16T_k<<<dim3(4096 / 64, 2048 / 64), 256, 0, stream>>>(Wg2, Wg2T, 2048, 4096);
    mask_to_bf16_k<<<(N * N / 4 + 255) / 256, 256, 0, stream>>>(mask, AdjB, N * N / 4);

    // ---- per-view GCN stacks, batched over z ----
    Ptr3 Av, RSv, Bv, biasP; Out3 Cv;
    // layer1: hv1[z] = (x[z]*doi[z]) @ Wv0[z]   [N,128] K=512
    for (int v = 0; v < 3; ++v) {
        Av.p[v] = x[v]; RSv.p[v] = isq + 2 * v * N; Bv.p[v] = Wv0[v];
        Cv.p[v] = hv1 + (size_t)v * N * 128;
    }
    gemm_b_k<64, 64, 16><<<dim3(2, N / 64, 3), 256, 0, stream>>>(Av, RSv, Bv, Cv, 128, 512);
    // gather+norm+bias+relu
    for (int v = 0; v < 3; ++v) biasP.p[v] = bv0[v];
    gather_k<128, 1><<<dim3(N / 2, 3), 256, 0, stream>>>(hv1, eidx, rowptr, degs, isq, biasP, h1o);
    // layer2: hv2[z] = (h1o[z]*doi[z]) @ Wv1[z]  [N,64] K=128
    for (int v = 0; v < 3; ++v) {
        Av.p[v] = h1o + (size_t)v * N * 128; RSv.p[v] = isq + 2 * v * N; Bv.p[v] = Wv1[v];
        Cv.p[v] = hv2 + (size_t)v * N * 64;
    }
    gemm_b_k<64, 64, 16><<<dim3(1, N / 64, 3), 256, 0, stream>>>(Av, RSv, Bv, Cv, 64, 128);
    for (int v = 0; v < 3; ++v) biasP.p[v] = bv1[v];
    gather_k<64, 0><<<dim3(N / 4, 3), 256, 0, stream>>>(hv2, eidx, rowptr, degs, isq, biasP, feat);
    // fusion: zp[z] = feat[z] @ Wf[z]
    for (int v = 0; v < 3; ++v) {
        Av.p[v] = feat + (size_t)v * N * 64; RSv.p[v] = nullptr; Bv.p[v] = Wf[v];
        Cv.p[v] = zp + (size_t)v * N * 64;
    }
    gemm_b_k<64, 64, 16><<<dim3(1, N / 64, 3), 256, 0, stream>>>(Av, RSv, Bv, Cv, 64, 64);
    softsum_k<<<N / 4, 256, 0, stream>>>(zp, zbuf);

    // ---- GFN on MFMA ----
    mfma_gemm_k<1><<<dim3(2048 / 128, 4096 / 128), 256, 0, stream>>>(
        AdjB, Wg1T, bg1, H1b, nullptr, 4096, 2048, 4096);
    mfma_gemm_k<2><<<dim3(4096 / 128, 4096 / 128), 256, 0, stream>>>(
        H1b, Wg2T, bg2, out_adjr, P, 4096, 4096, 2048);

    // ---- consensus graph ----
    hipMemsetAsync(degA, 0, (size_t)N * 4, stream);
    build_A2_k<<<dim3(N / 64, N / 64), 256, 0, stream>>>(P, A8, degA);
    dn_k<<<(N + 255) / 256, 256, 0, stream>>>(degA, dnv, N);

    // ---- fused-graph GCN ----
    spmm_u8_k<512><<<dim3(8, N / 64), 256, 0, stream>>>(A8, zbuf, dnv, part, N, N);
    reduce8_k<<<(N * 64 + 255) / 256, 256, 0, stream>>>(part, t1, N * 64);
    gemm_k<64, 64, 16, AT_F32, false, 1><<<dim3(1, N / 64), 256, 0, stream>>>(
        t1, dnv, Wm0, nullptr, bm0, h1m, N, 64, 64, 0);
    spmm_u8_k<512><<<dim3(8, N / 64), 256, 0, stream>>>(A8, h1m, dnv, part, N, N);
    reduce8_k<<<(N * 64 + 255) / 256, 256, 0, stream>>>(part, t1, N * 64);
    gemm_k<64, 64, 16, AT_F32, false, 0><<<dim3(1, N / 64), 256, 0, stream>>>(
        t1, dnv, Wm1, nullptr, bm1, out_h, N, 64, 64, 0);

    // ---- adj_rec = h @ h^T via split-bf16 MFMA (K=192) ----
    he_build_k<<<(N * 64 + 255) / 256, 256, 0, stream>>>(out_h, Ae, Be);
    mfma_gemm_k<0><<<dim3(4096 / 128, 4096 / 128), 256, 0, stream>>>(
        Ae, Be, nullptr, out_rec, nullptr, 4096, 4096, 192);
}

// Round 4
// 587.030 us; speedup vs baseline: 8.2325x; 1.1161x over previous
//
#include <hip/hip_runtime.h>
#include <math.h>

#define NNODES 4096
#define NEDGES 65536

enum { AT_F32 = 0, AT_U8 = 2 };

typedef short bf16x8 __attribute__((ext_vector_type(8)));
typedef short short4v __attribute__((ext_vector_type(4)));
typedef float f32x4 __attribute__((ext_vector_type(4)));

struct Ptr3  { const float* p[3]; };
struct Ptr3i { const int*   p[3]; };
struct Ptr3h { const short* p[3]; };
struct Out3  { float*       p[3]; };

__device__ __forceinline__ short f2bf(float f) {
    unsigned u = __builtin_bit_cast(unsigned, f);
    unsigned r = (u + 0x7FFFu + ((u >> 16) & 1u)) >> 16;
    return (short)r;
}

__device__ __forceinline__ void gload_lds16(const void* g, void* l) {
    __builtin_amdgcn_global_load_lds(
        (const __attribute__((address_space(1))) unsigned*)g,
        (__attribute__((address_space(3))) unsigned*)l, 16, 0, 0);
}

// ---------------- bf16 MFMA GEMM: C = act(A @ B^T + bias), 128x128 tile ----------------
// ACT==0: f32 out ; ACT==1: relu -> bf16 out ; ACT==2: round(clip+0.1) -> f32 out (+u8 P)
template<int ACT>
__global__ __launch_bounds__(256)
void mfma_gemm_k(const short* __restrict__ A, const short* __restrict__ Bt,
                 const float* __restrict__ bias, void* __restrict__ Cout,
                 unsigned char* __restrict__ Pout,
                 int M, int Nn, int K)
{
    __shared__ short As[128 * 64];
    __shared__ short Bs[128 * 64];
    const int tid = threadIdx.x;
    const int lane = tid & 63, wave = tid >> 6;
    // XCD-bijective swizzle (grid size always %8==0 here)
    const int gx = gridDim.x, nwg = gx * gridDim.y;
    int w = blockIdx.y * gx + blockIdx.x;
    const int q = nwg >> 3;
    w = (w & 7) * q + (w >> 3);
    const int bm0 = (w / gx) * 128, bn0 = (w % gx) * 128;
    const int wr = (wave >> 1) * 64, wc = (wave & 1) * 64;

    f32x4 acc[4][4] = {};

    for (int k0 = 0; k0 < K; k0 += 64) {
        for (int c = wave; c < 16; c += 4) {
            int o = c * 1024 + lane * 16;
            int row = o >> 7;
            int sl = (o >> 4) & 7;
            int ss = sl ^ (row & 7);
            gload_lds16(A + ((size_t)(bm0 + row) * K + k0 + ss * 8), As + c * 512);
            gload_lds16(Bt + ((size_t)(bn0 + row) * K + k0 + ss * 8), Bs + c * 512);
        }
        __syncthreads();
#pragma unroll
        for (int kk = 0; kk < 2; ++kk) {
            bf16x8 a[4], b[4];
            const int khalf = kk * 4 + (lane >> 4);
#pragma unroll
            for (int i = 0; i < 4; ++i) {
                int r = wr + i * 16 + (lane & 15);
                a[i] = *(const bf16x8*)(As + r * 64 + ((khalf ^ (r & 7)) << 3));
            }
#pragma unroll
            for (int j = 0; j < 4; ++j) {
                int r = wc + j * 16 + (lane & 15);
                b[j] = *(const bf16x8*)(Bs + r * 64 + ((khalf ^ (r & 7)) << 3));
            }
#pragma unroll
            for (int i = 0; i < 4; ++i)
#pragma unroll
                for (int j = 0; j < 4; ++j)
                    acc[i][j] = __builtin_amdgcn_mfma_f32_16x16x32_bf16(a[i], b[j], acc[i][j], 0, 0, 0);
        }
        __syncthreads();
    }

    const int cr = (lane >> 4) * 4;
    const int cc = lane & 15;
#pragma unroll
    for (int i = 0; i < 4; ++i) {
#pragma unroll
        for (int j = 0; j < 4; ++j) {
            int col = bn0 + wc + j * 16 + cc;
            float bv = bias ? bias[col] : 0.f;
#pragma unroll
            for (int q2 = 0; q2 < 4; ++q2) {
                int row = bm0 + wr + i * 16 + cr + q2;
                float v = acc[i][j][q2] + bv;
                if constexpr (ACT == 1) {
                    v = fmaxf(v, 0.f);
                    ((short*)Cout)[(size_t)row * Nn + col] = f2bf(v);
                } else if constexpr (ACT == 2) {
                    v = rintf(fminf(fmaxf(v, 0.f), 1.f) + 0.1f);
                    ((float*)Cout)[(size_t)row * Nn + col] = v;
                    Pout[(size_t)row * Nn + col] = (unsigned char)(v > 0.5f);
                } else {
                    ((float*)Cout)[(size_t)row * Nn + col] = v;
                }
            }
        }
    }
}

// ---------------- batched bf16 MFMA GEMM, 64x64 tile: C[z] = A[z] @ B[z]^T (f32 out) ----
// A contiguous [3][M][K] bf16, Bt per-view ptrs [Nn][K] bf16, C contiguous [3][M][Nn] f32.
__global__ __launch_bounds__(256)
void mfma_gemm_b_k(const short* __restrict__ Aall, Ptr3h Btv, float* __restrict__ Call,
                   int M, int Nn, int K)
{
    __shared__ short As[64 * 64];
    __shared__ short Bs[64 * 64];
    const int z = blockIdx.z;
    const short* A = Aall + (size_t)z * M * K;
    const short* Bt = Btv.p[z];
    float* C = Call + (size_t)z * M * Nn;
    const int tid = threadIdx.x;
    const int lane = tid & 63, wave = tid >> 6;
    const int bm0 = blockIdx.y * 64, bn0 = blockIdx.x * 64;
    const int wr = (wave >> 1) * 32, wc = (wave & 1) * 32;

    f32x4 acc[2][2] = {};

    for (int k0 = 0; k0 < K; k0 += 64) {
        for (int c = wave; c < 8; c += 4) {
            int o = c * 1024 + lane * 16;
            int row = o >> 7;
            int sl = (o >> 4) & 7;
            int ss = sl ^ (row & 7);
            gload_lds16(A + ((size_t)(bm0 + row) * K + k0 + ss * 8), As + c * 512);
            gload_lds16(Bt + ((size_t)(bn0 + row) * K + k0 + ss * 8), Bs + c * 512);
        }
        __syncthreads();
#pragma unroll
        for (int kk = 0; kk < 2; ++kk) {
            bf16x8 a[2], b[2];
            const int khalf = kk * 4 + (lane >> 4);
#pragma unroll
            for (int i = 0; i < 2; ++i) {
                int r = wr + i * 16 + (lane & 15);
                a[i] = *(const bf16x8*)(As + r * 64 + ((khalf ^ (r & 7)) << 3));
            }
#pragma unroll
            for (int j = 0; j < 2; ++j) {
                int r = wc + j * 16 + (lane & 15);
                b[j] = *(const bf16x8*)(Bs + r * 64 + ((khalf ^ (r & 7)) << 3));
            }
#pragma unroll
            for (int i = 0; i < 2; ++i)
#pragma unroll
                for (int j = 0; j < 2; ++j)
                    acc[i][j] = __builtin_amdgcn_mfma_f32_16x16x32_bf16(a[i], b[j], acc[i][j], 0, 0, 0);
        }
        __syncthreads();
    }

    const int cr = (lane >> 4) * 4;
    const int cc = lane & 15;
#pragma unroll
    for (int i = 0; i < 2; ++i)
#pragma unroll
        for (int j = 0; j < 2; ++j)
#pragma unroll
            for (int q = 0; q < 4; ++q) {
                int row = bm0 + wr + i * 16 + cr + q;
                int col = bn0 + wc + j * 16 + cc;
                C[(size_t)row * Nn + col] = acc[i][j][q];
            }
}

// f32 [R][C] -> bf16 transposed [C][R]
__global__ void f32_to_bf16T_k(const float* __restrict__ src, short* __restrict__ dstT,
                               int R, int C)
{
    __shared__ float t[64][65];
    const int br = blockIdx.y * 64, bc = blockIdx.x * 64;
    for (int idx = threadIdx.x; idx < 64 * 64; idx += 256) {
        int r = idx >> 6, c = idx & 63;
        t[r][c] = src[(size_t)(br + r) * C + bc + c];
    }
    __syncthreads();
    for (int idx = threadIdx.x; idx < 64 * 64; idx += 256) {
        int c = idx >> 6, r = idx & 63;
        dstT[(size_t)(bc + c) * R + br + r] = f2bf(t[r][c]);
    }
}

__global__ void mask_to_bf16_k(const unsigned* __restrict__ mask, short* __restrict__ adj,
                               int words)
{
    int t = blockIdx.x * 256 + threadIdx.x;
    if (t < words) {
        unsigned w = mask[t];
        short4v o;
        o.x = f2bf((float)__popc(w & 0x7u));
        o.y = f2bf((float)__popc(w & 0x700u));
        o.z = f2bf((float)__popc(w & 0x70000u));
        o.w = f2bf((float)__popc(w & 0x7000000u));
        *(short4v*)(adj + (size_t)t * 4) = o;
    }
}

// x [N,512] f32 * doi -> split-bf16 xe [N][1536] = [hi | hi | lo]
__global__ void xsplit_k(Ptr3 xv, const float* __restrict__ isq, short* __restrict__ xe)
{
    const int z = blockIdx.y;
    int t = blockIdx.x * 256 + threadIdx.x;
    int n = t >> 9, k = t & 511;
    float a = xv.p[z][(size_t)n * 512 + k] * isq[2 * z * NNODES + n];
    short hi = f2bf(a);
    float hif = __builtin_bit_cast(float, ((unsigned)(unsigned short)hi) << 16);
    short lo = f2bf(a - hif);
    short* row = xe + (size_t)z * NNODES * 1536 + (size_t)n * 1536;
    row[k] = hi; row[512 + k] = hi; row[1024 + k] = lo;
}

// W [K][Nn] f32 -> split-bf16 transposed Bt [Nn][3K] = [hi | lo | hi]
__global__ void wsplitT_k(Ptr3 Wv, short* __restrict__ out, int K, int Nn)
{
    const int z = blockIdx.y;
    int t = blockIdx.x * 256 + threadIdx.x;
    if (t >= K * Nn) return;
    int k = t / Nn, n = t % Nn;
    float w = Wv.p[z][(size_t)k * Nn + n];
    short hi = f2bf(w);
    float hif = __builtin_bit_cast(float, ((unsigned)(unsigned short)hi) << 16);
    short lo = f2bf(w - hif);
    short* row = out + (size_t)z * Nn * 3 * K + (size_t)n * 3 * K;
    row[k] = hi; row[K + k] = lo; row[2 * K + k] = hi;
}

// ---------------- generic f32 GEMM (small ops: Wm0/Wm1) ----------------
template<int BM, int BN, int BK, int ATY, bool BTR, int ACT>
__global__ __launch_bounds__(256)
void gemm_k(const void* __restrict__ Ap, const float* __restrict__ a_rs,
            const float* __restrict__ B, const float* __restrict__ b_rs,
            const float* __restrict__ bias, float* __restrict__ C,
            int M, int Nn, int K, int accum)
{
    constexpr int TM = BM / 16;
    constexpr int TN = BN / 16;
    __shared__ float As[BK][BM + 4];
    __shared__ float Bs[BK][BN + 4];
    const int tid = threadIdx.x;
    const int tx = tid & 15, ty = tid >> 4;
    const int bm0 = blockIdx.y * BM, bn0 = blockIdx.x * BN;

    float acc[TM][TN];
#pragma unroll
    for (int i = 0; i < TM; ++i)
#pragma unroll
        for (int j = 0; j < TN; ++j) acc[i][j] = 0.f;

    for (int k0 = 0; k0 < K; k0 += BK) {
        for (int idx = tid; idx < BM * BK; idx += 256) {
            int m = idx / BK, kk = idx % BK;
            int row = bm0 + m, kg = k0 + kk;
            float a;
            if constexpr (ATY == AT_U8) {
                a = (float)((const unsigned char*)Ap)[(size_t)row * K + kg];
            } else {
                a = ((const float*)Ap)[(size_t)row * K + kg];
            }
            if (a_rs) a *= a_rs[row];
            As[kk][m] = a;
        }
        for (int idx = tid; idx < BK * BN; idx += 256) {
            int kk = idx / BN, n = idx % BN;
            int col = bn0 + n, kg = k0 + kk;
            float b = 0.f;
            if (col < Nn) {
                b = BTR ? B[(size_t)col * K + kg] : B[(size_t)kg * Nn + col];
                if (b_rs) b *= b_rs[kg];
            }
            Bs[kk][n] = b;
        }
        __syncthreads();
#pragma unroll
        for (int kk = 0; kk < BK; ++kk) {
            float av[TM], bv[TN];
#pragma unroll
            for (int i = 0; i < TM; ++i) av[i] = As[kk][ty * TM + i];
#pragma unroll
            for (int j = 0; j < TN; ++j) bv[j] = Bs[kk][tx * TN + j];
#pragma unroll
            for (int i = 0; i < TM; ++i)
#pragma unroll
                for (int j = 0; j < TN; ++j) acc[i][j] += av[i] * bv[j];
        }
        __syncthreads();
    }

#pragma unroll
    for (int i = 0; i < TM; ++i) {
        int row = bm0 + ty * TM + i;
#pragma unroll
        for (int j = 0; j < TN; ++j) {
            int col = bn0 + tx * TN + j;
            if (col < Nn) {
                float v = acc[i][j];
                if (bias) v += bias[col];
                if (accum) v += C[(size_t)row * Nn + col];
                if constexpr (ACT == 1) v = fmaxf(v, 0.f);
                C[(size_t)row * Nn + col] = v;
            }
        }
    }
}

// ---------------- K-split u8 SpMM ----------------
template<int KCHUNK>
__global__ __launch_bounds__(256)
void spmm_u8_k(const unsigned char* __restrict__ A8, const float* __restrict__ X,
               const float* __restrict__ xs, float* __restrict__ part, int K, int Mtot)
{
    __shared__ float As[16][68];
    __shared__ float Bs[16][68];
    const int tid = threadIdx.x, tx = tid & 15, ty = tid >> 4;
    const int bm0 = blockIdx.y * 64;
    const int kbase = blockIdx.x * KCHUNK;
    float acc[4][4] = {};

    for (int k0 = kbase; k0 < kbase + KCHUNK; k0 += 16) {
        for (int idx = tid; idx < 64 * 16; idx += 256) {
            int m = idx >> 4, kk = idx & 15;
            As[kk][m] = (float)A8[(size_t)(bm0 + m) * K + k0 + kk];
        }
        for (int idx = tid; idx < 16 * 64; idx += 256) {
            int kk = idx >> 6, n = idx & 63;
            Bs[kk][n] = X[(size_t)(k0 + kk) * 64 + n] * xs[k0 + kk];
        }
        __syncthreads();
#pragma unroll
        for (int kk = 0; kk < 16; ++kk) {
            float av[4], bv[4];
#pragma unroll
            for (int i = 0; i < 4; ++i) av[i] = As[kk][ty * 4 + i];
#pragma unroll
            for (int j = 0; j < 4; ++j) bv[j] = Bs[kk][tx * 4 + j];
#pragma unroll
            for (int i = 0; i < 4; ++i)
#pragma unroll
                for (int j = 0; j < 4; ++j) acc[i][j] += av[i] * bv[j];
        }
        __syncthreads();
    }
    float* dst = part + (size_t)blockIdx.x * Mtot * 64;
#pragma unroll
    for (int i = 0; i < 4; ++i)
#pragma unroll
        for (int j = 0; j < 4; ++j)
            dst[(size_t)(bm0 + ty * 4 + i) * 64 + tx * 4 + j] = acc[i][j];
}

__global__ void reduce8_k(const float* __restrict__ part, float* __restrict__ out, int total)
{
    int t = blockIdx.x * 256 + threadIdx.x;
    if (t < total) {
        float s = 0.f;
        for (int p = 0; p < 8; ++p) s += part[(size_t)p * total + t];
        out[t] = s;
    }
}

// ---------------- graph construction ----------------
__global__ void edge_k(Ptr3i src, Ptr3i dst, unsigned* __restrict__ mask, int* __restrict__ degs)
{
    int e = blockIdx.x * 256 + threadIdx.x;
    int z = blockIdx.y;
    if (e < NEDGES) {
        int s = src.p[z][e], d = dst.p[z][e];
        unsigned c = (unsigned)s * (unsigned)NNODES + (unsigned)d;
        atomicOr(&mask[c >> 2], 1u << ((c & 3u) * 8u + (unsigned)z));
        atomicAdd(&degs[2 * z * NNODES + s], 1);
        atomicAdd(&degs[(2 * z + 1) * NNODES + d], 1);
    }
}

__global__ void deg_norm_k(const int* __restrict__ degs, float* __restrict__ isq, int n)
{
    int t = blockIdx.x * 256 + threadIdx.x;
    if (t < n) isq[t] = 1.0f / sqrtf(fmaxf((float)degs[t], 1.0f));
}

__global__ __launch_bounds__(1024)
void scan_k(const int* __restrict__ degs, int* __restrict__ rowptr, int* __restrict__ cursor)
{
    const int z = blockIdx.x;
    const int* din = degs + (2 * z + 1) * NNODES;
    __shared__ int sm[1024];
    const int t = threadIdx.x;
    int v0 = din[t * 4], v1 = din[t * 4 + 1], v2 = din[t * 4 + 2], v3 = din[t * 4 + 3];
    int c1 = v0 + v1, c2 = c1 + v2, s = c2 + v3;
    sm[t] = s;
    __syncthreads();
    for (int off = 1; off < 1024; off <<= 1) {
        int add = (t >= off) ? sm[t - off] : 0;
        __syncthreads();
        sm[t] += add;
        __syncthreads();
    }
    int base = sm[t] - s;
    int* rp = rowptr + z * NNODES;
    int* cu = cursor + z * NNODES;
    rp[t * 4] = base;          cu[t * 4] = base;
    rp[t * 4 + 1] = base + v0; cu[t * 4 + 1] = base + v0;
    rp[t * 4 + 2] = base + c1; cu[t * 4 + 2] = base + c1;
    rp[t * 4 + 3] = base + c2; cu[t * 4 + 3] = base + c2;
}

__global__ void fill_k(Ptr3i src, Ptr3i dst, int* __restrict__ cursor, int* __restrict__ eidx)
{
    int e = blockIdx.x * 256 + threadIdx.x;
    int z = blockIdx.y;
    if (e < NEDGES) {
        int d = dst.p[z][e];
        int pos = atomicAdd(&cursor[z * NNODES + d], 1);
        eidx[(size_t)z * NEDGES + pos] = src.p[z][e];
    }
}

// fused CSR-gather + norm + bias + act -> split-bf16 A rows [node][3F]
// MODE 1: scale output rows by doi (feeds next gconv); MODE 2: no scale
template<int F, int ACT, int MODE>
__global__ void gather_k(const float* __restrict__ Hpre, const int* __restrict__ eidx,
                         const int* __restrict__ rowptr, const int* __restrict__ degs,
                         const float* __restrict__ isq, Ptr3 bias, short* __restrict__ Sout)
{
    const int z = blockIdx.y;
    const int tid = threadIdx.x;
    const int node = blockIdx.x * (256 / F) + tid / F;
    const int f = tid % F;
    const float* H = Hpre + (size_t)z * NNODES * F;
    const int base = rowptr[z * NNODES + node];
    const int cnt = degs[(2 * z + 1) * NNODES + node];
    const int* ei = eidx + (size_t)z * NEDGES + base;
    float s = 0.f;
    for (int i = 0; i < cnt; ++i) s += H[(size_t)ei[i] * F + f];
    float v = s * isq[(2 * z + 1) * NNODES + node] + bias.p[z][f];
    if (ACT) v = fmaxf(v, 0.f);
    if (MODE == 1) v *= isq[2 * z * NNODES + node];
    short hi = f2bf(v);
    float hif = __builtin_bit_cast(float, ((unsigned)(unsigned short)hi) << 16);
    short lo = f2bf(v - hif);
    short* row = Sout + (size_t)z * NNODES * 3 * F + (size_t)node * 3 * F;
    row[f] = hi; row[F + f] = hi; row[2 * F + f] = lo;
}

// z = softmax_row(zp0+zp1+zp2)
__global__ void softsum_k(const float* __restrict__ zp, float* __restrict__ z)
{
    int row = blockIdx.x * 4 + (threadIdx.x >> 6);
    int f = threadIdx.x & 63;
    size_t i = (size_t)row * 64 + f;
    float v = zp[i] + zp[i + (size_t)NNODES * 64] + zp[i + (size_t)2 * NNODES * 64];
    float m = v;
#pragma unroll
    for (int off = 32; off >= 1; off >>= 1) m = fmaxf(m, __shfl_xor(m, off));
    float e = expf(v - m);
    float s = e;
#pragma unroll
    for (int off = 32; off >= 1; off >>= 1) s += __shfl_xor(s, off);
    z[i] = e / s;
}

// A8[i,j] = P[i,j] | P[j,i] | (i==j), deg row-sums. All uint4 traffic.
__global__ __launch_bounds__(256)
void build_A2_k(const unsigned char* __restrict__ P, unsigned char* __restrict__ A8,
                int* __restrict__ degA)
{
    __shared__ unsigned Ts[64][20];
    const int bi = blockIdx.y * 64, bj = blockIdx.x * 64;
    const int tid = threadIdx.x;
    const int r = tid >> 2, seg = tid & 3;
    uint4 tv = *(const uint4*)(P + (size_t)(bj + r) * NNODES + bi + seg * 16);
    Ts[r][seg * 4 + 0] = tv.x; Ts[r][seg * 4 + 1] = tv.y;
    Ts[r][seg * 4 + 2] = tv.z; Ts[r][seg * 4 + 3] = tv.w;
    __syncthreads();
    uint4 dv = *(const uint4*)(P + (size_t)(bi + r) * NNODES + bj + seg * 16);
    unsigned dw[4] = {dv.x, dv.y, dv.z, dv.w};
    const unsigned char* Tb = (const unsigned char*)Ts;
    unsigned ow[4];
    int psum = 0;
#pragma unroll
    for (int w = 0; w < 4; ++w) {
        unsigned o = 0;
#pragma unroll
        for (int b = 0; b < 4; ++b) {
            int j = seg * 16 + w * 4 + b;
            unsigned a = (dw[w] >> (8 * b)) & 1u;
            unsigned tr = Tb[j * 80 + r] & 1u;
            unsigned on = a | tr | (unsigned)((bi + r) == (bj + j));
            o |= on << (8 * b);
            psum += (int)on;
        }
        ow[w] = o;
    }
    uint4 o4; o4.x = ow[0]; o4.y = ow[1]; o4.z = ow[2]; o4.w = ow[3];
    *(uint4*)(A8 + (size_t)(bi + r) * NNODES + bj + seg * 16) = o4;
    psum += __shfl_xor(psum, 1);
    psum += __shfl_xor(psum, 2);
    if (seg == 0) atomicAdd(&degA[bi + r], psum);
}

__global__ void dn_k(const int* __restrict__ deg, float* __restrict__ dn, int n)
{
    int t = blockIdx.x * 256 + threadIdx.x;
    if (t < n) dn[t] = 1.0f / sqrtf((float)deg[t]);
}

// h (f32 [N][64]) -> split-bf16 operands for h@h^T: Ae=[hi|hi|lo], Be=[hi|lo|hi]
__global__ void he_build_k(const float* __restrict__ h, short* __restrict__ Ae,
                           short* __restrict__ Be)
{
    int t = blockIdx.x * 256 + threadIdx.x;
    if (t < NNODES * 64) {
        int r = t >> 6, c = t & 63;
        float v = h[t];
        short hi = f2bf(v);
        float hif = __builtin_bit_cast(float, ((unsigned)(unsigned short)hi) << 16);
        short lo = f2bf(v - hif);
        size_t ro = (size_t)r * 192;
        Ae[ro + c] = hi; Ae[ro + 64 + c] = hi; Ae[ro + 128 + c] = lo;
        Be[ro + c] = hi; Be[ro + 64 + c] = lo; Be[ro + 128 + c] = hi;
    }
}

extern "C" void kernel_launch(void* const* d_in, const int* in_sizes, int n_in,
                              void* d_out, int out_size, void* d_ws, size_t ws_size,
                              hipStream_t stream)
{
    const int N = NNODES, E = NEDGES;
    const size_t MB = 1024 * 1024;

    const float* x[3]; const int* src[3]; const int* dst[3];
    const float *Wv0[3], *bv0[3], *Wv1[3], *bv1[3], *Wf[3];
    for (int v = 0; v < 3; ++v) {
        const int b = v * 8;
        x[v]   = (const float*)d_in[b + 0];
        src[v] = (const int*)  d_in[b + 1];
        dst[v] = (const int*)  d_in[b + 2];
        Wv0[v] = (const float*)d_in[b + 3];
        bv0[v] = (const float*)d_in[b + 4];
        Wv1[v] = (const float*)d_in[b + 5];
        bv1[v] = (const float*)d_in[b + 6];
        Wf[v]  = (const float*)d_in[b + 7];
    }
    const float* Wg1 = (const float*)d_in[24];
    const float* bg1 = (const float*)d_in[25];
    const float* Wg2 = (const float*)d_in[26];
    const float* bg2 = (const float*)d_in[27];
    const float* Wm0 = (const float*)d_in[28];
    const float* bm0 = (const float*)d_in[29];
    const float* Wm1 = (const float*)d_in[30];
    const float* bm1 = (const float*)d_in[31];

    float* out_adjr = (float*)d_out;                    // [N,N] f32 (final)
    float* out_rec  = out_adjr + (size_t)N * N;         // [N,N] f32 (final; scratch until then)
    float* out_h    = out_rec + (size_t)N * N;          // [N,64]

    // --- scratch carved from dead halves of output regions ---
    char* oa = (char*)out_adjr;                         // 64 MB, final write at GEMM2
    short* AdjB = (short*)oa;                           // bf16 [N][N]  [0,32M)
    float* hv1  = (float*)(oa + 32 * MB);               // f32 [3][N][128]   6 MB
    short* Ae2  = (short*)(oa + 38 * MB);               // bf16 [3][N][384]  9 MB
    short* Ae3  = (short*)(oa + 47 * MB);               // bf16 [3][N][192]  4.5 MB
    float* hv2  = (float*)(oa + 52 * MB);               // f32 [3][N][64]    3 MB
    float* zp   = (float*)(oa + 56 * MB);               // f32 [3][N][64]    3 MB

    char* orc = (char*)out_rec;                         // 64 MB, final write at h@hT
    short* xe   = (short*)orc;                          // bf16 [3][N][1536] 36 MB (dead after L1)
    short* H1b  = (short*)orc;                          // bf16 [N][2048]  [0,16M)
    unsigned char* P = (unsigned char*)(orc + 16 * MB); // u8 [N][N]       [16,32M)
    short* Wg1T = (short*)(orc + 16 * MB);              // (dead when P written)
    short* Wg2T = (short*)(orc + 32 * MB);              // [32,48M)
    float* part = (float*)(orc + 48 * MB);              // 8 MB K-split partials

    // ---- workspace carve (~23 MB) ----
    char* p = (char*)d_ws;
    unsigned* mask = (unsigned*)p;
    unsigned char* A8 = (unsigned char*)p;              // reuses mask region
    short* AeF = (short*)p;                             // h@hT operands (after A8 dead)
    short* BeF = AeF + (size_t)N * 192;
    p += (size_t)N * N;                                 // 16MB
    int* degs = (int*)p;     p += (size_t)6 * N * 4;
    float* isq = (float*)p;  p += (size_t)6 * N * 4;
    int* rowptr = (int*)p;   p += (size_t)3 * N * 4;
    int* cursor = (int*)p;   p += (size_t)3 * N * 4;
    int* eidx = (int*)p;     p += (size_t)3 * E * 4;
    int* degA = (int*)p;     p += (size_t)N * 4;
    float* dnv = (float*)p;  p += (size_t)N * 4;
    float* zbuf = (float*)p; p += (size_t)N * 64 * 4;
    float* t1 = (float*)p;   p += (size_t)N * 64 * 4;
    float* h1m = (float*)p;  p += (size_t)N * 64 * 4;
    short* Wv0T = (short*)p; p += (size_t)3 * 128 * 1536 * 2;
    short* Wv1T = (short*)p; p += (size_t)3 * 64 * 384 * 2;
    short* WfT  = (short*)p; p += (size_t)3 * 64 * 192 * 2;

    Ptr3i srcP, dstP;
    for (int v = 0; v < 3; ++v) { srcP.p[v] = src[v]; dstP.p[v] = dst[v]; }

    hipMemsetAsync(mask, 0, (size_t)N * N, stream);
    hipMemsetAsync(degs, 0, (size_t)6 * N * 4, stream);

    edge_k<<<dim3((E + 255) / 256, 3), 256, 0, stream>>>(srcP, dstP, mask, degs);
    deg_norm_k<<<(6 * N + 255) / 256, 256, 0, stream>>>(degs, isq, 6 * N);
    scan_k<<<3, 1024, 0, stream>>>(degs, rowptr, cursor);
    fill_k<<<dim3((E + 255) / 256, 3), 256, 0, stream>>>(srcP, dstP, cursor, eidx);

    // ---- split-bf16 operand builders for per-view GEMMs ----
    Ptr3 xP; for (int v = 0; v < 3; ++v) xP.p[v] = x[v];
    xsplit_k<<<dim3(N * 512 / 256, 3), 256, 0, stream>>>(xP, isq, xe);
    Ptr3 wP;
    for (int v = 0; v < 3; ++v) wP.p[v] = Wv0[v];
    wsplitT_k<<<dim3(512 * 128 / 256, 3), 256, 0, stream>>>(wP, Wv0T, 512, 128);
    for (int v = 0; v < 3; ++v) wP.p[v] = Wv1[v];
    wsplitT_k<<<dim3(128 * 64 / 256, 3), 256, 0, stream>>>(wP, Wv1T, 128, 64);
    for (int v = 0; v < 3; ++v) wP.p[v] = Wf[v];
    wsplitT_k<<<dim3(64 * 64 / 256, 3), 256, 0, stream>>>(wP, WfT, 64, 64);

    // ---- per-view GCN stacks on MFMA (lossless split-bf16) ----
    Ptr3h BtP; Ptr3 biasP;
    // layer1: hv1[z] = (x*doi) @ Wv0   [N,128], Keff=1536
    for (int v = 0; v < 3; ++v) BtP.p[v] = Wv0T + (size_t)v * 128 * 1536;
    mfma_gemm_b_k<<<dim3(2, N / 64, 3), 256, 0, stream>>>(xe, BtP, hv1, N, 128, 1536);
    for (int v = 0; v < 3; ++v) biasP.p[v] = bv0[v];
    gather_k<128, 1, 1><<<dim3(N / 2, 3), 256, 0, stream>>>(hv1, eidx, rowptr, degs, isq, biasP, Ae2);
    // layer2: hv2[z] = (f1*doi) @ Wv1  [N,64], Keff=384
    for (int v = 0; v < 3; ++v) BtP.p[v] = Wv1T + (size_t)v * 64 * 384;
    mfma_gemm_b_k<<<dim3(1, N / 64, 3), 256, 0, stream>>>(Ae2, BtP, hv2, N, 64, 384);
    for (int v = 0; v < 3; ++v) biasP.p[v] = bv1[v];
    gather_k<64, 0, 2><<<dim3(N / 4, 3), 256, 0, stream>>>(hv2, eidx, rowptr, degs, isq, biasP, Ae3);
    // fusion: zp[z] = feat @ Wf[z]   [N,64], Keff=192
    for (int v = 0; v < 3; ++v) BtP.p[v] = WfT + (size_t)v * 64 * 192;
    mfma_gemm_b_k<<<dim3(1, N / 64, 3), 256, 0, stream>>>(Ae3, BtP, zp, N, 64, 192);
    softsum_k<<<N / 4, 256, 0, stream>>>(zp, zbuf);

    // ---- GFN conversions (after xe is dead) ----
    mask_to_bf16_k<<<(N * N / 4 + 255) / 256, 256, 0, stream>>>(mask, AdjB, N * N / 4);
    f32_to_bf16T_k<<<dim3(2048 / 64, 4096 / 64), 256, 0, stream>>>(Wg1, Wg1T, 4096, 2048);
    f32_to_bf16T_k<<<dim3(4096 / 64, 2048 / 64), 256, 0, stream>>>(Wg2, Wg2T, 2048, 4096);

    // ---- GFN on MFMA ----
    mfma_gemm_k<1><<<dim3(2048 / 128, 4096 / 128), 256, 0, stream>>>(
        AdjB, Wg1T, bg1, H1b, nullptr, 4096, 2048, 4096);
    mfma_gemm_k<2><<<dim3(4096 / 128, 4096 / 128), 256, 0, stream>>>(
        H1b, Wg2T, bg2, out_adjr, P, 4096, 4096, 2048);

    // ---- consensus graph ----
    hipMemsetAsync(degA, 0, (size_t)N * 4, stream);
    build_A2_k<<<dim3(N / 64, N / 64), 256, 0, stream>>>(P, A8, degA);
    dn_k<<<(N + 255) / 256, 256, 0, stream>>>(degA, dnv, N);

    // ---- fused-graph GCN ----
    spmm_u8_k<512><<<dim3(8, N / 64), 256, 0, stream>>>(A8, zbuf, dnv, part, N, N);
    reduce8_k<<<(N * 64 + 255) / 256, 256, 0, stream>>>(part, t1, N * 64);
    gemm_k<64, 64, 16, AT_F32, false, 1><<<dim3(1, N / 64), 256, 0, stream>>>(
        t1, dnv, Wm0, nullptr, bm0, h1m, N, 64, 64, 0);
    spmm_u8_k<512><<<dim3(8, N / 64), 256, 0, stream>>>(A8, h1m, dnv, part, N, N);
    reduce8_k<<<(N * 64 + 255) / 256, 256, 0, stream>>>(part, t1, N * 64);
    gemm_k<64, 64, 16, AT_F32, false, 0><<<dim3(1, N / 64), 256, 0, stream>>>(
        t1, dnv, Wm1, nullptr, bm1, out_h, N, 64, 64, 0);

    // ---- adj_rec = h @ h^T via split-bf16 MFMA (K=192) ----
    he_build_k<<<(N * 64 + 255) / 256, 256, 0, stream>>>(out_h, AeF, BeF);
    mfma_gemm_k<0><<<dim3(4096 / 128, 4096 / 128), 256, 0, stream>>>(
        AeF, BeF, nullptr, out_rec, nullptr, 4096, 4096, 192);
}

// Round 5
// 568.301 us; speedup vs baseline: 8.5038x; 1.0330x over previous
//
#include <hip/hip_runtime.h>
#include <math.h>

#define NNODES 4096
#define NEDGES 65536

typedef short bf16x8 __attribute__((ext_vector_type(8)));
typedef short short4v __attribute__((ext_vector_type(4)));
typedef float f32x4 __attribute__((ext_vector_type(4)));

struct Ptr3  { const float* p[3]; };
struct Ptr3i { const int*   p[3]; };
struct Ptr3h { const short* p[3]; };

__device__ __forceinline__ short f2bf(float f) {
    unsigned u = __builtin_bit_cast(unsigned, f);
    unsigned r = (u + 0x7FFFu + ((u >> 16) & 1u)) >> 16;
    return (short)r;
}

__device__ __forceinline__ void gload_lds16(const void* g, void* l) {
    __builtin_amdgcn_global_load_lds(
        (const __attribute__((address_space(1))) unsigned*)g,
        (__attribute__((address_space(3))) unsigned*)l, 16, 0, 0);
}

// ============ pipelined bf16 MFMA GEMM: C = act(A @ B^T + bias) ============
// BM=256, BN=128, BK=64, 512 thr (8 waves: 4 M x 2 N), wave tile 64x64.
// LDS: 3 slots x (A 32KB + B 16KB) = 144KB -> 1 block/CU, 2 waves/SIMD.
// Depth-2 prefetch, counted vmcnt(6), raw s_barrier (1 per K-tile).
// ACT==0: f32 out ; ACT==1: relu -> bf16 out ; ACT==2: round(clip+0.1) -> f32 + u8 P
template<int ACT>
__global__ __launch_bounds__(512, 1)
void gemm256_k(const short* __restrict__ A, const short* __restrict__ Bt,
               const float* __restrict__ bias, void* __restrict__ Cout,
               unsigned char* __restrict__ Pout, int M, int Nn, int K)
{
    __shared__ short lds_s[3 * 24576];   // 147456 B
    const int tid = threadIdx.x;
    const int lane = tid & 63, wave = tid >> 6;
    // XCD-bijective swizzle (nwg % 8 == 0 for all our grids)
    const int gx = gridDim.x, nwg = gx * gridDim.y;
    int w = blockIdx.y * gx + blockIdx.x;
    const int q = nwg >> 3;
    w = (w & 7) * q + (w >> 3);
    const int bm0 = (w / gx) * 256, bn0 = (w % gx) * 128;
    const int wmr = (wave >> 1) * 64;    // wave row base within tile (0..192)
    const int wnr = (wave & 1) * 64;     // wave col base within tile (0/64)

    const int NT = K >> 6;

    // stage one K-tile (A: 4 rounds, B: 2 rounds of 8KB) into slot
    auto stage = [&](int kt, int slot) {
        const int k0 = kt << 6;
        char* base = (char*)(lds_s + slot * 24576);
        char* wbase = base + (tid >> 6) * 1024;     // wave-uniform LDS base
#pragma unroll
        for (int r = 0; r < 4; ++r) {
            int o = r * 8192 + tid * 16;
            int row = o >> 7;
            int sl = (o >> 4) & 7;
            gload_lds16(A + ((size_t)(bm0 + row) * K + k0 + ((sl ^ (row & 7)) << 3)),
                        wbase + r * 8192);
        }
#pragma unroll
        for (int r = 0; r < 2; ++r) {
            int o = r * 8192 + tid * 16;
            int row = o >> 7;
            int sl = (o >> 4) & 7;
            gload_lds16(Bt + ((size_t)(bn0 + row) * K + k0 + ((sl ^ (row & 7)) << 3)),
                        base + 32768 + r * 8192 + (tid >> 6) * 1024);
        }
    };

    f32x4 acc[4][4] = {};

    stage(0, 0);
    if (NT > 1) stage(1, 1);

    for (int kt = 0; kt < NT; ++kt) {
        if (kt < NT - 1) { asm volatile("s_waitcnt vmcnt(6)" ::: "memory"); }
        else             { asm volatile("s_waitcnt vmcnt(0)" ::: "memory"); }
        __builtin_amdgcn_s_barrier();
        if (kt + 2 < NT) stage(kt + 2, (kt + 2) % 3);

        const short* As = lds_s + (kt % 3) * 24576;
        const short* Bs = As + 16384;
        __builtin_amdgcn_s_setprio(1);
#pragma unroll
        for (int kk = 0; kk < 2; ++kk) {
            bf16x8 a[4], b[4];
            const int khalf = kk * 4 + (lane >> 4);
#pragma unroll
            for (int i = 0; i < 4; ++i) {
                int r = wmr + i * 16 + (lane & 15);
                a[i] = *(const bf16x8*)(As + r * 64 + ((khalf ^ (r & 7)) << 3));
            }
#pragma unroll
            for (int j = 0; j < 4; ++j) {
                int r = wnr + j * 16 + (lane & 15);
                b[j] = *(const bf16x8*)(Bs + r * 64 + ((khalf ^ (r & 7)) << 3));
            }
#pragma unroll
            for (int i = 0; i < 4; ++i)
#pragma unroll
                for (int j = 0; j < 4; ++j)
                    acc[i][j] = __builtin_amdgcn_mfma_f32_16x16x32_bf16(a[i], b[j], acc[i][j], 0, 0, 0);
        }
        __builtin_amdgcn_s_setprio(0);
        asm volatile("s_waitcnt lgkmcnt(0)" ::: "memory");
    }

    const int cr = (lane >> 4) * 4;   // C/D: col=lane&15, row=(lane>>4)*4+reg
    const int cc = lane & 15;
#pragma unroll
    for (int i = 0; i < 4; ++i) {
#pragma unroll
        for (int j = 0; j < 4; ++j) {
            int col = bn0 + wnr + j * 16 + cc;
            float bv = bias ? bias[col] : 0.f;
#pragma unroll
            for (int q2 = 0; q2 < 4; ++q2) {
                int row = bm0 + wmr + i * 16 + cr + q2;
                float v = acc[i][j][q2] + bv;
                if constexpr (ACT == 1) {
                    v = fmaxf(v, 0.f);
                    ((short*)Cout)[(size_t)row * Nn + col] = f2bf(v);
                } else if constexpr (ACT == 2) {
                    v = rintf(fminf(fmaxf(v, 0.f), 1.f) + 0.1f);
                    ((float*)Cout)[(size_t)row * Nn + col] = v;
                    Pout[(size_t)row * Nn + col] = (unsigned char)(v > 0.5f);
                } else {
                    ((float*)Cout)[(size_t)row * Nn + col] = v;
                }
            }
        }
    }
}

// ---------------- batched bf16 MFMA GEMM, 64x64 tile (per-view stacks) ----------------
__global__ __launch_bounds__(256)
void mfma_gemm_b_k(const short* __restrict__ Aall, Ptr3h Btv, float* __restrict__ Call,
                   int M, int Nn, int K)
{
    __shared__ short As[64 * 64];
    __shared__ short Bs[64 * 64];
    const int z = blockIdx.z;
    const short* A = Aall + (size_t)z * M * K;
    const short* Bt = Btv.p[z];
    float* C = Call + (size_t)z * M * Nn;
    const int tid = threadIdx.x;
    const int lane = tid & 63, wave = tid >> 6;
    const int bm0 = blockIdx.y * 64, bn0 = blockIdx.x * 64;
    const int wr = (wave >> 1) * 32, wc = (wave & 1) * 32;

    f32x4 acc[2][2] = {};

    for (int k0 = 0; k0 < K; k0 += 64) {
        for (int c = wave; c < 8; c += 4) {
            int o = c * 1024 + lane * 16;
            int row = o >> 7;
            int sl = (o >> 4) & 7;
            int ss = sl ^ (row & 7);
            gload_lds16(A + ((size_t)(bm0 + row) * K + k0 + ss * 8), As + c * 512);
            gload_lds16(Bt + ((size_t)(bn0 + row) * K + k0 + ss * 8), Bs + c * 512);
        }
        __syncthreads();
#pragma unroll
        for (int kk = 0; kk < 2; ++kk) {
            bf16x8 a[2], b[2];
            const int khalf = kk * 4 + (lane >> 4);
#pragma unroll
            for (int i = 0; i < 2; ++i) {
                int r = wr + i * 16 + (lane & 15);
                a[i] = *(const bf16x8*)(As + r * 64 + ((khalf ^ (r & 7)) << 3));
            }
#pragma unroll
            for (int j = 0; j < 2; ++j) {
                int r = wc + j * 16 + (lane & 15);
                b[j] = *(const bf16x8*)(Bs + r * 64 + ((khalf ^ (r & 7)) << 3));
            }
#pragma unroll
            for (int i = 0; i < 2; ++i)
#pragma unroll
                for (int j = 0; j < 2; ++j)
                    acc[i][j] = __builtin_amdgcn_mfma_f32_16x16x32_bf16(a[i], b[j], acc[i][j], 0, 0, 0);
        }
        __syncthreads();
    }

    const int cr = (lane >> 4) * 4;
    const int cc = lane & 15;
#pragma unroll
    for (int i = 0; i < 2; ++i)
#pragma unroll
        for (int j = 0; j < 2; ++j)
#pragma unroll
            for (int q = 0; q < 4; ++q) {
                int row = bm0 + wr + i * 16 + cr + q;
                int col = bn0 + wc + j * 16 + cc;
                C[(size_t)row * Nn + col] = acc[i][j][q];
            }
}

// f32 [R][C] -> bf16 transposed [C][R]
__global__ void f32_to_bf16T_k(const float* __restrict__ src, short* __restrict__ dstT,
                               int R, int C)
{
    __shared__ float t[64][65];
    const int br = blockIdx.y * 64, bc = blockIdx.x * 64;
    for (int idx = threadIdx.x; idx < 64 * 64; idx += 256) {
        int r = idx >> 6, c = idx & 63;
        t[r][c] = src[(size_t)(br + r) * C + bc + c];
    }
    __syncthreads();
    for (int idx = threadIdx.x; idx < 64 * 64; idx += 256) {
        int c = idx >> 6, r = idx & 63;
        dstT[(size_t)(bc + c) * R + br + r] = f2bf(t[r][c]);
    }
}

__global__ void mask_to_bf16_k(const unsigned* __restrict__ mask, short* __restrict__ adj,
                               int words)
{
    int t = blockIdx.x * 256 + threadIdx.x;
    if (t < words) {
        unsigned w = mask[t];
        short4v o;
        o.x = f2bf((float)__popc(w & 0x7u));
        o.y = f2bf((float)__popc(w & 0x700u));
        o.z = f2bf((float)__popc(w & 0x70000u));
        o.w = f2bf((float)__popc(w & 0x7000000u));
        *(short4v*)(adj + (size_t)t * 4) = o;
    }
}

// x [N,512] f32 * doi -> split-bf16 xe [N][1536] = [hi | hi | lo]
__global__ void xsplit_k(Ptr3 xv, const float* __restrict__ isq, short* __restrict__ xe)
{
    const int z = blockIdx.y;
    int t = blockIdx.x * 256 + threadIdx.x;
    int n = t >> 9, k = t & 511;
    float a = xv.p[z][(size_t)n * 512 + k] * isq[2 * z * NNODES + n];
    short hi = f2bf(a);
    float hif = __builtin_bit_cast(float, ((unsigned)(unsigned short)hi) << 16);
    short lo = f2bf(a - hif);
    short* row = xe + (size_t)z * NNODES * 1536 + (size_t)n * 1536;
    row[k] = hi; row[512 + k] = hi; row[1024 + k] = lo;
}

// W [K][Nn] f32 -> split-bf16 transposed Bt [Nn][3K] = [hi | lo | hi]
__global__ void wsplitT_k(Ptr3 Wv, short* __restrict__ out, int K, int Nn)
{
    const int z = blockIdx.y;
    int t = blockIdx.x * 256 + threadIdx.x;
    if (t >= K * Nn) return;
    int k = t / Nn, n = t % Nn;
    float w = Wv.p[z][(size_t)k * Nn + n];
    short hi = f2bf(w);
    float hif = __builtin_bit_cast(float, ((unsigned)(unsigned short)hi) << 16);
    short lo = f2bf(w - hif);
    short* row = out + (size_t)z * Nn * 3 * K + (size_t)n * 3 * K;
    row[k] = hi; row[K + k] = lo; row[2 * K + k] = hi;
}

// ---------------- K-split u8 SpMM: part[kc] = A8[:,kc] @ (X * deg^-1/2)[kc,:] ----------
template<int KCHUNK>
__global__ __launch_bounds__(256)
void spmm_u8_k(const unsigned char* __restrict__ A8, const float* __restrict__ X,
               const int* __restrict__ degA, float* __restrict__ part, int K, int Mtot)
{
    __shared__ float As[16][68];
    __shared__ float Bs[16][68];
    const int tid = threadIdx.x, tx = tid & 15, ty = tid >> 4;
    const int bm0 = blockIdx.y * 64;
    const int kbase = blockIdx.x * KCHUNK;
    float acc[4][4] = {};

    for (int k0 = kbase; k0 < kbase + KCHUNK; k0 += 16) {
        for (int idx = tid; idx < 64 * 16; idx += 256) {
            int m = idx >> 4, kk = idx & 15;
            As[kk][m] = (float)A8[(size_t)(bm0 + m) * K + k0 + kk];
        }
        for (int idx = tid; idx < 16 * 64; idx += 256) {
            int kk = idx >> 6, n = idx & 63;
            Bs[kk][n] = X[(size_t)(k0 + kk) * 64 + n] * (1.0f / sqrtf((float)degA[k0 + kk]));
        }
        __syncthreads();
#pragma unroll
        for (int kk = 0; kk < 16; ++kk) {
            float av[4], bv[4];
#pragma unroll
            for (int i = 0; i < 4; ++i) av[i] = As[kk][ty * 4 + i];
#pragma unroll
            for (int j = 0; j < 4; ++j) bv[j] = Bs[kk][tx * 4 + j];
#pragma unroll
            for (int i = 0; i < 4; ++i)
#pragma unroll
                for (int j = 0; j < 4; ++j) acc[i][j] += av[i] * bv[j];
        }
        __syncthreads();
    }
    float* dst = part + (size_t)blockIdx.x * Mtot * 64;
#pragma unroll
    for (int i = 0; i < 4; ++i)
#pragma unroll
        for (int j = 0; j < 4; ++j)
            dst[(size_t)(bm0 + ty * 4 + i) * 64 + tx * 4 + j] = acc[i][j];
}

// fused: s[row,:] = (sum_p part[p][row,:]) * deg[row]^-1/2 ; out = act(s @ Wm + b)
template<int RELU>
__global__ __launch_bounds__(256)
void redgemm_k(const float* __restrict__ part, const int* __restrict__ degA,
               const float* __restrict__ Wm, const float* __restrict__ bias,
               float* __restrict__ out)
{
    __shared__ float Ws[64 * 64];
    const int tid = threadIdx.x;
    for (int i = tid; i < 4096; i += 256) Ws[i] = Wm[i];
    __syncthreads();
    const int lane = tid & 63, wave = tid >> 6;
    const float bv = bias[lane];
    for (int rr = 0; rr < 16; ++rr) {
        int row = blockIdx.x * 64 + wave * 16 + rr;
        float s = 0.f;
#pragma unroll
        for (int p = 0; p < 8; ++p) s += part[((size_t)p * NNODES + row) * 64 + lane];
        s *= 1.0f / sqrtf((float)degA[row]);
        float acc = bv;
#pragma unroll
        for (int k = 0; k < 64; ++k)
            acc = fmaf(__shfl(s, k), Ws[k * 64 + lane], acc);
        if (RELU) acc = fmaxf(acc, 0.f);
        out[(size_t)row * 64 + lane] = acc;
    }
}

// ---------------- graph construction ----------------
__global__ void edge_k(Ptr3i src, Ptr3i dst, unsigned* __restrict__ mask, int* __restrict__ degs)
{
    int e = blockIdx.x * 256 + threadIdx.x;
    int z = blockIdx.y;
    if (e < NEDGES) {
        int s = src.p[z][e], d = dst.p[z][e];
        unsigned c = (unsigned)s * (unsigned)NNODES + (unsigned)d;
        atomicOr(&mask[c >> 2], 1u << ((c & 3u) * 8u + (unsigned)z));
        atomicAdd(&degs[2 * z * NNODES + s], 1);
        atomicAdd(&degs[(2 * z + 1) * NNODES + d], 1);
    }
}

__global__ void deg_norm_k(const int* __restrict__ degs, float* __restrict__ isq, int n)
{
    int t = blockIdx.x * 256 + threadIdx.x;
    if (t < n) isq[t] = 1.0f / sqrtf(fmaxf((float)degs[t], 1.0f));
}

__global__ __launch_bounds__(1024)
void scan_k(const int* __restrict__ degs, int* __restrict__ rowptr, int* __restrict__ cursor)
{
    const int z = blockIdx.x;
    const int* din = degs + (2 * z + 1) * NNODES;
    __shared__ int sm[1024];
    const int t = threadIdx.x;
    int v0 = din[t * 4], v1 = din[t * 4 + 1], v2 = din[t * 4 + 2], v3 = din[t * 4 + 3];
    int c1 = v0 + v1, c2 = c1 + v2, s = c2 + v3;
    sm[t] = s;
    __syncthreads();
    for (int off = 1; off < 1024; off <<= 1) {
        int add = (t >= off) ? sm[t - off] : 0;
        __syncthreads();
        sm[t] += add;
        __syncthreads();
    }
    int base = sm[t] - s;
    int* rp = rowptr + z * NNODES;
    int* cu = cursor + z * NNODES;
    rp[t * 4] = base;          cu[t * 4] = base;
    rp[t * 4 + 1] = base + v0; cu[t * 4 + 1] = base + v0;
    rp[t * 4 + 2] = base + c1; cu[t * 4 + 2] = base + c1;
    rp[t * 4 + 3] = base + c2; cu[t * 4 + 3] = base + c2;
}

__global__ void fill_k(Ptr3i src, Ptr3i dst, int* __restrict__ cursor, int* __restrict__ eidx)
{
    int e = blockIdx.x * 256 + threadIdx.x;
    int z = blockIdx.y;
    if (e < NEDGES) {
        int d = dst.p[z][e];
        int pos = atomicAdd(&cursor[z * NNODES + d], 1);
        eidx[(size_t)z * NEDGES + pos] = src.p[z][e];
    }
}

// fused CSR-gather + norm + bias + act -> split-bf16 A rows [node][3F]
template<int F, int ACT, int MODE>
__global__ void gather_k(const float* __restrict__ Hpre, const int* __restrict__ eidx,
                         const int* __restrict__ rowptr, const int* __restrict__ degs,
                         const float* __restrict__ isq, Ptr3 bias, short* __restrict__ Sout)
{
    const int z = blockIdx.y;
    const int tid = threadIdx.x;
    const int node = blockIdx.x * (256 / F) + tid / F;
    const int f = tid % F;
    const float* H = Hpre + (size_t)z * NNODES * F;
    const int base = rowptr[z * NNODES + node];
    const int cnt = degs[(2 * z + 1) * NNODES + node];
    const int* ei = eidx + (size_t)z * NEDGES + base;
    float s = 0.f;
    for (int i = 0; i < cnt; ++i) s += H[(size_t)ei[i] * F + f];
    float v = s * isq[(2 * z + 1) * NNODES + node] + bias.p[z][f];
    if (ACT) v = fmaxf(v, 0.f);
    if (MODE == 1) v *= isq[2 * z * NNODES + node];
    short hi = f2bf(v);
    float hif = __builtin_bit_cast(float, ((unsigned)(unsigned short)hi) << 16);
    short lo = f2bf(v - hif);
    short* row = Sout + (size_t)z * NNODES * 3 * F + (size_t)node * 3 * F;
    row[f] = hi; row[F + f] = hi; row[2 * F + f] = lo;
}

// z = softmax_row(zp0+zp1+zp2)
__global__ void softsum_k(const float* __restrict__ zp, float* __restrict__ z)
{
    int row = blockIdx.x * 4 + (threadIdx.x >> 6);
    int f = threadIdx.x & 63;
    size_t i = (size_t)row * 64 + f;
    float v = zp[i] + zp[i + (size_t)NNODES * 64] + zp[i + (size_t)2 * NNODES * 64];
    float m = v;
#pragma unroll
    for (int off = 32; off >= 1; off >>= 1) m = fmaxf(m, __shfl_xor(m, off));
    float e = expf(v - m);
    float s = e;
#pragma unroll
    for (int off = 32; off >= 1; off >>= 1) s += __shfl_xor(s, off);
    z[i] = e / s;
}

// A8[i,j] = P[i,j] | P[j,i] | (i==j), deg row-sums. All uint4 traffic.
__global__ __launch_bounds__(256)
void build_A2_k(const unsigned char* __restrict__ P, unsigned char* __restrict__ A8,
                int* __restrict__ degA)
{
    __shared__ unsigned Ts[64][20];
    const int bi = blockIdx.y * 64, bj = blockIdx.x * 64;
    const int tid = threadIdx.x;
    const int r = tid >> 2, seg = tid & 3;
    uint4 tv = *(const uint4*)(P + (size_t)(bj + r) * NNODES + bi + seg * 16);
    Ts[r][seg * 4 + 0] = tv.x; Ts[r][seg * 4 + 1] = tv.y;
    Ts[r][seg * 4 + 2] = tv.z; Ts[r][seg * 4 + 3] = tv.w;
    __syncthreads();
    uint4 dv = *(const uint4*)(P + (size_t)(bi + r) * NNODES + bj + seg * 16);
    unsigned dw[4] = {dv.x, dv.y, dv.z, dv.w};
    const unsigned char* Tb = (const unsigned char*)Ts;
    unsigned ow[4];
    int psum = 0;
#pragma unroll
    for (int w = 0; w < 4; ++w) {
        unsigned o = 0;
#pragma unroll
        for (int b = 0; b < 4; ++b) {
            int j = seg * 16 + w * 4 + b;
            unsigned a = (dw[w] >> (8 * b)) & 1u;
            unsigned tr = Tb[j * 80 + r] & 1u;
            unsigned on = a | tr | (unsigned)((bi + r) == (bj + j));
            o |= on << (8 * b);
            psum += (int)on;
        }
        ow[w] = o;
    }
    uint4 o4; o4.x = ow[0]; o4.y = ow[1]; o4.z = ow[2]; o4.w = ow[3];
    *(uint4*)(A8 + (size_t)(bi + r) * NNODES + bj + seg * 16) = o4;
    psum += __shfl_xor(psum, 1);
    psum += __shfl_xor(psum, 2);
    if (seg == 0) atomicAdd(&degA[bi + r], psum);
}

// h (f32 [N][64]) -> split-bf16 operands for h@h^T: Ae=[hi|hi|lo], Be=[hi|lo|hi]
__global__ void he_build_k(const float* __restrict__ h, short* __restrict__ Ae,
                           short* __restrict__ Be)
{
    int t = blockIdx.x * 256 + threadIdx.x;
    if (t < NNODES * 64) {
        int r = t >> 6, c = t & 63;
        float v = h[t];
        short hi = f2bf(v);
        float hif = __builtin_bit_cast(float, ((unsigned)(unsigned short)hi) << 16);
        short lo = f2bf(v - hif);
        size_t ro = (size_t)r * 192;
        Ae[ro + c] = hi; Ae[ro + 64 + c] = hi; Ae[ro + 128 + c] = lo;
        Be[ro + c] = hi; Be[ro + 64 + c] = lo; Be[ro + 128 + c] = hi;
    }
}

extern "C" void kernel_launch(void* const* d_in, const int* in_sizes, int n_in,
                              void* d_out, int out_size, void* d_ws, size_t ws_size,
                              hipStream_t stream)
{
    const int N = NNODES, E = NEDGES;
    const size_t MB = 1024 * 1024;

    const float* x[3]; const int* src[3]; const int* dst[3];
    const float *Wv0[3], *bv0[3], *Wv1[3], *bv1[3], *Wf[3];
    for (int v = 0; v < 3; ++v) {
        const int b = v * 8;
        x[v]   = (const float*)d_in[b + 0];
        src[v] = (const int*)  d_in[b + 1];
        dst[v] = (const int*)  d_in[b + 2];
        Wv0[v] = (const float*)d_in[b + 3];
        bv0[v] = (const float*)d_in[b + 4];
        Wv1[v] = (const float*)d_in[b + 5];
        bv1[v] = (const float*)d_in[b + 6];
        Wf[v]  = (const float*)d_in[b + 7];
    }
    const float* Wg1 = (const float*)d_in[24];
    const float* bg1 = (const float*)d_in[25];
    const float* Wg2 = (const float*)d_in[26];
    const float* bg2 = (const float*)d_in[27];
    const float* Wm0 = (const float*)d_in[28];
    const float* bm0 = (const float*)d_in[29];
    const float* Wm1 = (const float*)d_in[30];
    const float* bm1 = (const float*)d_in[31];

    float* out_adjr = (float*)d_out;                    // [N,N] f32 (final)
    float* out_rec  = out_adjr + (size_t)N * N;         // [N,N] f32 (final; scratch until then)
    float* out_h    = out_rec + (size_t)N * N;          // [N,64]

    // --- scratch carved from dead halves of output regions ---
    char* oa = (char*)out_adjr;                         // 64 MB, final write at GEMM2
    short* AdjB = (short*)oa;                           // bf16 [N][N]  [0,32M)
    float* hv1  = (float*)(oa + 32 * MB);               // f32 [3][N][128]   6 MB
    short* Ae2  = (short*)(oa + 38 * MB);               // bf16 [3][N][384]  9 MB
    short* Ae3  = (short*)(oa + 47 * MB);               // bf16 [3][N][192]  4.5 MB
    float* hv2  = (float*)(oa + 52 * MB);               // f32 [3][N][64]    3 MB
    float* zp   = (float*)(oa + 56 * MB);               // f32 [3][N][64]    3 MB

    char* orc = (char*)out_rec;                         // 64 MB, final write at h@hT
    short* xe   = (short*)orc;                          // bf16 [3][N][1536] 36 MB (dead after L1)
    short* H1b  = (short*)orc;                          // bf16 [N][2048]  [0,16M)
    unsigned char* P = (unsigned char*)(orc + 16 * MB); // u8 [N][N]       [16,32M)
    short* Wg1T = (short*)(orc + 16 * MB);              // (dead when P written)
    short* Wg2T = (short*)(orc + 32 * MB);              // [32,48M)
    float* part = (float*)(orc + 48 * MB);              // 8 MB K-split partials

    // ---- workspace carve ----
    char* p = (char*)d_ws;
    unsigned* mask = (unsigned*)p;
    unsigned char* A8 = (unsigned char*)p;              // reuses mask region
    short* AeF = (short*)p;                             // h@hT operands (after A8 dead)
    short* BeF = AeF + (size_t)N * 192;
    p += (size_t)N * N;                                 // 16MB
    int* degs = (int*)p;     p += (size_t)6 * N * 4;
    float* isq = (float*)p;  p += (size_t)6 * N * 4;
    int* rowptr = (int*)p;   p += (size_t)3 * N * 4;
    int* cursor = (int*)p;   p += (size_t)3 * N * 4;
    int* eidx = (int*)p;     p += (size_t)3 * E * 4;
    int* degA = (int*)p;     p += (size_t)N * 4;
    float* zbuf = (float*)p; p += (size_t)N * 64 * 4;
    float* h1m = (float*)p;  p += (size_t)N * 64 * 4;
    short* Wv0T = (short*)p; p += (size_t)3 * 128 * 1536 * 2;
    short* Wv1T = (short*)p; p += (size_t)3 * 64 * 384 * 2;
    short* WfT  = (short*)p; p += (size_t)3 * 64 * 192 * 2;

    Ptr3i srcP, dstP;
    for (int v = 0; v < 3; ++v) { srcP.p[v] = src[v]; dstP.p[v] = dst[v]; }

    hipMemsetAsync(mask, 0, (size_t)N * N, stream);
    hipMemsetAsync(degs, 0, (size_t)6 * N * 4, stream);

    edge_k<<<dim3((E + 255) / 256, 3), 256, 0, stream>>>(srcP, dstP, mask, degs);
    deg_norm_k<<<(6 * N + 255) / 256, 256, 0, stream>>>(degs, isq, 6 * N);
    scan_k<<<3, 1024, 0, stream>>>(degs, rowptr, cursor);
    fill_k<<<dim3((E + 255) / 256, 3), 256, 0, stream>>>(srcP, dstP, cursor, eidx);

    // ---- split-bf16 operand builders for per-view GEMMs ----
    Ptr3 xP; for (int v = 0; v < 3; ++v) xP.p[v] = x[v];
    xsplit_k<<<dim3(N * 512 / 256, 3), 256, 0, stream>>>(xP, isq, xe);
    Ptr3 wP;
    for (int v = 0; v < 3; ++v) wP.p[v] = Wv0[v];
    wsplitT_k<<<dim3(512 * 128 / 256, 3), 256, 0, stream>>>(wP, Wv0T, 512, 128);
    for (int v = 0; v < 3; ++v) wP.p[v] = Wv1[v];
    wsplitT_k<<<dim3(128 * 64 / 256, 3), 256, 0, stream>>>(wP, Wv1T, 128, 64);
    for (int v = 0; v < 3; ++v) wP.p[v] = Wf[v];
    wsplitT_k<<<dim3(64 * 64 / 256, 3), 256, 0, stream>>>(wP, WfT, 64, 64);

    // ---- per-view GCN stacks on MFMA (lossless split-bf16) ----
    Ptr3h BtP; Ptr3 biasP;
    for (int v = 0; v < 3; ++v) BtP.p[v] = Wv0T + (size_t)v * 128 * 1536;
    mfma_gemm_b_k<<<dim3(2, N / 64, 3), 256, 0, stream>>>(xe, BtP, hv1, N, 128, 1536);
    for (int v = 0; v < 3; ++v) biasP.p[v] = bv0[v];
    gather_k<128, 1, 1><<<dim3(N / 2, 3), 256, 0, stream>>>(hv1, eidx, rowptr, degs, isq, biasP, Ae2);
    for (int v = 0; v < 3; ++v) BtP.p[v] = Wv1T + (size_t)v * 64 * 384;
    mfma_gemm_b_k<<<dim3(1, N / 64, 3), 256, 0, stream>>>(Ae2, BtP, hv2, N, 64, 384);
    for (int v = 0; v < 3; ++v) biasP.p[v] = bv1[v];
    gather_k<64, 0, 2><<<dim3(N / 4, 3), 256, 0, stream>>>(hv2, eidx, rowptr, degs, isq, biasP, Ae3);
    for (int v = 0; v < 3; ++v) BtP.p[v] = WfT + (size_t)v * 64 * 192;
    mfma_gemm_b_k<<<dim3(1, N / 64, 3), 256, 0, stream>>>(Ae3, BtP, zp, N, 64, 192);
    softsum_k<<<N / 4, 256, 0, stream>>>(zp, zbuf);

    // ---- GFN conversions (after xe is dead) ----
    mask_to_bf16_k<<<(N * N / 4 + 255) / 256, 256, 0, stream>>>(mask, AdjB, N * N / 4);
    f32_to_bf16T_k<<<dim3(2048 / 64, 4096 / 64), 256, 0, stream>>>(Wg1, Wg1T, 4096, 2048);
    f32_to_bf16T_k<<<dim3(4096 / 64, 2048 / 64), 256, 0, stream>>>(Wg2, Wg2T, 2048, 4096);

    // ---- GFN on pipelined MFMA ----
    gemm256_k<1><<<dim3(2048 / 128, 4096 / 256), 512, 0, stream>>>(
        AdjB, Wg1T, bg1, H1b, nullptr, 4096, 2048, 4096);
    gemm256_k<2><<<dim3(4096 / 128, 4096 / 256), 512, 0, stream>>>(
        H1b, Wg2T, bg2, out_adjr, P, 4096, 4096, 2048);

    // ---- consensus graph ----
    hipMemsetAsync(degA, 0, (size_t)N * 4, stream);
    build_A2_k<<<dim3(N / 64, N / 64), 256, 0, stream>>>(P, A8, degA);

    // ---- fused-graph GCN ----
    spmm_u8_k<512><<<dim3(8, N / 64), 256, 0, stream>>>(A8, zbuf, degA, part, N, N);
    redgemm_k<1><<<64, 256, 0, stream>>>(part, degA, Wm0, bm0, h1m);
    spmm_u8_k<512><<<dim3(8, N / 64), 256, 0, stream>>>(A8, h1m, degA, part, N, N);
    redgemm_k<0><<<64, 256, 0, stream>>>(part, degA, Wm1, bm1, out_h);

    // ---- adj_rec = h @ h^T via split-bf16 pipelined MFMA (K=192) ----
    he_build_k<<<(N * 64 + 255) / 256, 256, 0, stream>>>(out_h, AeF, BeF);
    gemm256_k<0><<<dim3(4096 / 128, 4096 / 256), 512, 0, stream>>>(
        AeF, BeF, nullptr, out_rec, nullptr, 4096, 4096, 192);
}

// Round 6
// 559.208 us; speedup vs baseline: 8.6421x; 1.0163x over previous
//
#include <hip/hip_runtime.h>
#include <math.h>

#define NNODES 4096
#define NEDGES 65536

typedef short bf16x8 __attribute__((ext_vector_type(8)));
typedef short short4v __attribute__((ext_vector_type(4)));
typedef float f32x4 __attribute__((ext_vector_type(4)));
typedef float f32x4v __attribute__((ext_vector_type(4)));

struct Ptr3  { const float* p[3]; };
struct Ptr3i { const int*   p[3]; };
struct Ptr3h { const short* p[3]; };

__device__ __forceinline__ short f2bf(float f) {
    unsigned u = __builtin_bit_cast(unsigned, f);
    unsigned r = (u + 0x7FFFu + ((u >> 16) & 1u)) >> 16;
    return (short)r;
}

__device__ __forceinline__ void gload_lds16(const void* g, void* l) {
    __builtin_amdgcn_global_load_lds(
        (const __attribute__((address_space(1))) unsigned*)g,
        (__attribute__((address_space(3))) unsigned*)l, 16, 0, 0);
}

// ================= 8-phase 256x256 bf16 MFMA GEMM (T2+T3+T4+T5) =================
// 512 thr (8 waves 2M x 4N), wave tile 128x64, BK=64, LDS 2 x 64KB dbuf.
// Per phase: 12 ds_read (quadrant frags) + 2 gload_lds (quarter-pair prefetch),
// barrier, 16 MFMA (setprio), vmcnt(2) only at phases 3/7, barrier.
// Quarter-stage schedule (iter i reading tiles 2i,2i+1):
//   p0:(2i+1)Aq1q3 p1:(2i+1)B01 p2:(2i+1)B23 p3:(2i+2)Aq0q2
//   p4:(2i+2)Aq1q3 p5:(2i+2)B01 p6:(2i+2)B23 p7:(2i+3)Aq0q2
// Every stage targets a region last read >=1 phase earlier (barrier-protected).
// ACT==2: round(clip(v+bias,0,1)+0.1)->f32 + u8 P ; ACT==3: raw f32 (K-split partial)
template<int ACT>
__global__ __launch_bounds__(512, 1)
void g8_k(const short* __restrict__ A, const short* __restrict__ Bt,
          const float* __restrict__ bias, void* __restrict__ Cout,
          unsigned char* __restrict__ Pout, int M, int Nn, int K, int lda, int ldb)
{
    __shared__ short lds[2 * 32768];    // 128 KB
    const int tid = threadIdx.x;
    const int lane = tid & 63;
    const int wm = (tid >> 6) >> 2;     // 0..1
    const int wn = (tid >> 6) & 3;      // 0..3
    // K-split via z: offset k-range
    const int z = blockIdx.z;
    A  += (size_t)z * K;
    Bt += (size_t)z * K;
    float* Cf = (float*)Cout + (size_t)z * M * Nn;
    // XCD-bijective swizzle within z-slice (nwg % 8 == 0)
    const int gx = gridDim.x, nwg = gx * gridDim.y;
    int w = blockIdx.y * gx + blockIdx.x;
    const int q8 = nwg >> 3;
    w = (w & 7) * q8 + (w >> 3);
    const int bm0 = (w / gx) * 256, bn0 = (w % gx) * 256;

    const int NT = K >> 6;

    f32x4 acc[8][4] = {};

    // stage one quarter-pair of tile t. sel: 0=Aq0q2 1=Aq1q3 2=Bq0q1 3=Bq2q3
    auto stageQ = [&](int t, int sel) {
        if (t >= NT) return;
        const int k0 = t << 6;
        short* L = lds + (t & 1) * 32768;
        const int rowq = tid >> 3;          // 0..63 within quarter
        const int slot = tid & 7;
        const int woff = (tid >> 6) * 512;  // wave-uniform LDS offset (shorts)
#pragma unroll
        for (int u = 0; u < 2; ++u) {
            int q, isB;
            if (sel == 0)      { q = u * 2;     isB = 0; }
            else if (sel == 1) { q = u * 2 + 1; isB = 0; }
            else if (sel == 2) { q = u;         isB = 1; }
            else               { q = u + 2;     isB = 1; }
            const int grow = q * 64 + rowq;
            const int scol = (slot ^ (grow & 7)) << 3;
            if (!isB)
                gload_lds16(A + (size_t)(bm0 + grow) * lda + k0 + scol,
                            L + q * 4096 + woff);
            else
                gload_lds16(Bt + (size_t)(bn0 + grow) * ldb + k0 + scol,
                            L + 16384 + q * 4096 + woff);
        }
    };

#define PHASE(Q, TCUR, STAGET, SSEL, VM)                                           \
    {                                                                              \
        constexpr int mh_ = (Q) >> 1, nh_ = (Q) & 1;                               \
        const short* As_ = lds + ((TCUR) & 1) * 32768;                             \
        const short* Bs_ = As_ + 16384;                                            \
        bf16x8 a_[4][2], b_[2][2];                                                 \
        _Pragma("unroll") for (int kk = 0; kk < 2; ++kk) {                         \
            const int h_ = kk * 4 + (lane >> 4);                                   \
            _Pragma("unroll") for (int i = 0; i < 4; ++i) {                        \
                int r_ = wm * 128 + mh_ * 64 + i * 16 + (lane & 15);               \
                a_[i][kk] = *(const bf16x8*)(As_ + r_ * 64 + ((h_ ^ (r_ & 7)) << 3)); \
            }                                                                      \
            _Pragma("unroll") for (int j = 0; j < 2; ++j) {                        \
                int r_ = wn * 64 + nh_ * 32 + j * 16 + (lane & 15);                \
                b_[j][kk] = *(const bf16x8*)(Bs_ + r_ * 64 + ((h_ ^ (r_ & 7)) << 3)); \
            }                                                                      \
        }                                                                          \
        stageQ(STAGET, SSEL);                                                      \
        __builtin_amdgcn_s_barrier();                                              \
        __builtin_amdgcn_s_setprio(1);                                             \
        _Pragma("unroll") for (int kk = 0; kk < 2; ++kk)                           \
            _Pragma("unroll") for (int i = 0; i < 4; ++i)                          \
                _Pragma("unroll") for (int j = 0; j < 2; ++j)                      \
                    acc[mh_ * 4 + i][nh_ * 2 + j] =                                \
                        __builtin_amdgcn_mfma_f32_16x16x32_bf16(                   \
                            a_[i][kk], b_[j][kk], acc[mh_ * 4 + i][nh_ * 2 + j], 0, 0, 0); \
        __builtin_amdgcn_s_setprio(0);                                             \
        if ((VM) == 2)      { asm volatile("s_waitcnt vmcnt(2)" ::: "memory"); }   \
        else if ((VM) == 0) { asm volatile("s_waitcnt vmcnt(0)" ::: "memory"); }   \
        __builtin_amdgcn_sched_barrier(0);                                         \
        __builtin_amdgcn_s_barrier();                                              \
    }

    // prologue: mimic steady-state [i-1] p3..p7 issue order
    stageQ(0, 0); stageQ(0, 1); stageQ(0, 2); stageQ(0, 3);
    stageQ(1, 0);
    asm volatile("s_waitcnt vmcnt(2)" ::: "memory");
    __builtin_amdgcn_sched_barrier(0);
    __builtin_amdgcn_s_barrier();

    for (int it = 0; it < NT / 2; ++it) {
        const int t0 = 2 * it, t1 = t0 + 1;
        PHASE(0, t0, t1, 1, -1);
        PHASE(1, t0, t1, 2, -1);
        PHASE(2, t0, t1, 3, -1);
        { int vm_ = (t0 + 2 < NT) ? 2 : 0; PHASE(3, t0, t0 + 2, 0, vm_); }
        PHASE(0, t1, t0 + 2, 1, -1);
        PHASE(1, t1, t0 + 2, 2, -1);
        PHASE(2, t1, t0 + 2, 3, -1);
        { int vm_ = (t0 + 2 < NT) ? 2 : -1; PHASE(3, t1, t0 + 3, 0, vm_); }
    }
#undef PHASE

    const int cr = (lane >> 4) * 4;
    const int cc = lane & 15;
#pragma unroll
    for (int im = 0; im < 8; ++im) {
#pragma unroll
        for (int jn = 0; jn < 4; ++jn) {
            int col = bn0 + wn * 64 + (jn >> 1) * 32 + (jn & 1) * 16 + cc;
            float bv = bias ? bias[col] : 0.f;
#pragma unroll
            for (int q2 = 0; q2 < 4; ++q2) {
                int row = bm0 + wm * 128 + (im >> 2) * 64 + (im & 3) * 16 + cr + q2;
                float v = acc[im][jn][q2] + bv;
                if constexpr (ACT == 2) {
                    v = rintf(fminf(fmaxf(v, 0.f), 1.f) + 0.1f);
                    Cf[(size_t)row * Nn + col] = v;
                    Pout[(size_t)row * Nn + col] = (unsigned char)(v > 0.5f);
                } else {
                    Cf[(size_t)row * Nn + col] = v;
                }
            }
        }
    }
}

// H1b = bf16(relu(part0 + part1 + bias[col])), [4096][2048]
__global__ void reduce_h1_k(const float* __restrict__ p0, const float* __restrict__ p1,
                            const float* __restrict__ bias, short* __restrict__ H1b)
{
    int i = (blockIdx.x * 256 + threadIdx.x) * 4;
    f32x4v a = *(const f32x4v*)(p0 + i);
    f32x4v b = *(const f32x4v*)(p1 + i);
    int col = i & 2047;
    short4v o;
#pragma unroll
    for (int j = 0; j < 4; ++j) {
        float v = a[j] + b[j] + bias[col + j];
        o[j] = f2bf(fmaxf(v, 0.f));
    }
    *(short4v*)(H1b + i) = o;
}

// ============ legacy 2-phase pipelined GEMM (used for h@h^T, K=192) ============
template<int ACT>
__global__ __launch_bounds__(512, 1)
void gemm256_k(const short* __restrict__ A, const short* __restrict__ Bt,
               const float* __restrict__ bias, void* __restrict__ Cout,
               unsigned char* __restrict__ Pout, int M, int Nn, int K)
{
    __shared__ short lds_s[3 * 24576];
    const int tid = threadIdx.x;
    const int lane = tid & 63;
    const int gx = gridDim.x, nwg = gx * gridDim.y;
    int w = blockIdx.y * gx + blockIdx.x;
    const int q = nwg >> 3;
    w = (w & 7) * q + (w >> 3);
    const int bm0 = (w / gx) * 256, bn0 = (w % gx) * 128;
    const int wmr = ((tid >> 6) >> 1) * 64;
    const int wnr = ((tid >> 6) & 1) * 64;
    const int NT = K >> 6;

    auto stage = [&](int kt, int slot) {
        const int k0 = kt << 6;
        char* base = (char*)(lds_s + slot * 24576);
        char* wbase = base + (tid >> 6) * 1024;
#pragma unroll
        for (int r = 0; r < 4; ++r) {
            int o = r * 8192 + tid * 16;
            int row = o >> 7;
            int sl = (o >> 4) & 7;
            gload_lds16(A + ((size_t)(bm0 + row) * K + k0 + ((sl ^ (row & 7)) << 3)),
                        wbase + r * 8192);
        }
#pragma unroll
        for (int r = 0; r < 2; ++r) {
            int o = r * 8192 + tid * 16;
            int row = o >> 7;
            int sl = (o >> 4) & 7;
            gload_lds16(Bt + ((size_t)(bn0 + row) * K + k0 + ((sl ^ (row & 7)) << 3)),
                        base + 32768 + r * 8192 + (tid >> 6) * 1024);
        }
    };

    f32x4 acc[4][4] = {};
    stage(0, 0);
    if (NT > 1) stage(1, 1);

    for (int kt = 0; kt < NT; ++kt) {
        if (kt < NT - 1) { asm volatile("s_waitcnt vmcnt(6)" ::: "memory"); }
        else             { asm volatile("s_waitcnt vmcnt(0)" ::: "memory"); }
        __builtin_amdgcn_s_barrier();
        if (kt + 2 < NT) stage(kt + 2, (kt + 2) % 3);

        const short* As = lds_s + (kt % 3) * 24576;
        const short* Bs = As + 16384;
        __builtin_amdgcn_s_setprio(1);
#pragma unroll
        for (int kk = 0; kk < 2; ++kk) {
            bf16x8 a[4], b[4];
            const int khalf = kk * 4 + (lane >> 4);
#pragma unroll
            for (int i = 0; i < 4; ++i) {
                int r = wmr + i * 16 + (lane & 15);
                a[i] = *(const bf16x8*)(As + r * 64 + ((khalf ^ (r & 7)) << 3));
            }
#pragma unroll
            for (int j = 0; j < 4; ++j) {
                int r = wnr + j * 16 + (lane & 15);
                b[j] = *(const bf16x8*)(Bs + r * 64 + ((khalf ^ (r & 7)) << 3));
            }
#pragma unroll
            for (int i = 0; i < 4; ++i)
#pragma unroll
                for (int j = 0; j < 4; ++j)
                    acc[i][j] = __builtin_amdgcn_mfma_f32_16x16x32_bf16(a[i], b[j], acc[i][j], 0, 0, 0);
        }
        __builtin_amdgcn_s_setprio(0);
        asm volatile("s_waitcnt lgkmcnt(0)" ::: "memory");
    }

    const int cr = (lane >> 4) * 4;
    const int cc = lane & 15;
#pragma unroll
    for (int i = 0; i < 4; ++i)
#pragma unroll
        for (int j = 0; j < 4; ++j) {
            int col = bn0 + wnr + j * 16 + cc;
#pragma unroll
            for (int q2 = 0; q2 < 4; ++q2) {
                int row = bm0 + wmr + i * 16 + cr + q2;
                ((float*)Cout)[(size_t)row * Nn + col] = acc[i][j][q2];
            }
        }
}

// ---------------- batched bf16 MFMA GEMM, 64x64 tile (per-view stacks) ----------------
__global__ __launch_bounds__(256)
void mfma_gemm_b_k(const short* __restrict__ Aall, Ptr3h Btv, float* __restrict__ Call,
                   int M, int Nn, int K)
{
    __shared__ short As[64 * 64];
    __shared__ short Bs[64 * 64];
    const int z = blockIdx.z;
    const short* A = Aall + (size_t)z * M * K;
    const short* Bt = Btv.p[z];
    float* C = Call + (size_t)z * M * Nn;
    const int tid = threadIdx.x;
    const int lane = tid & 63, wave = tid >> 6;
    const int bm0 = blockIdx.y * 64, bn0 = blockIdx.x * 64;
    const int wr = (wave >> 1) * 32, wc = (wave & 1) * 32;

    f32x4 acc[2][2] = {};

    for (int k0 = 0; k0 < K; k0 += 64) {
        for (int c = wave; c < 8; c += 4) {
            int o = c * 1024 + lane * 16;
            int row = o >> 7;
            int sl = (o >> 4) & 7;
            int ss = sl ^ (row & 7);
            gload_lds16(A + ((size_t)(bm0 + row) * K + k0 + ss * 8), As + c * 512);
            gload_lds16(Bt + ((size_t)(bn0 + row) * K + k0 + ss * 8), Bs + c * 512);
        }
        __syncthreads();
#pragma unroll
        for (int kk = 0; kk < 2; ++kk) {
            bf16x8 a[2], b[2];
            const int khalf = kk * 4 + (lane >> 4);
#pragma unroll
            for (int i = 0; i < 2; ++i) {
                int r = wr + i * 16 + (lane & 15);
                a[i] = *(const bf16x8*)(As + r * 64 + ((khalf ^ (r & 7)) << 3));
            }
#pragma unroll
            for (int j = 0; j < 2; ++j) {
                int r = wc + j * 16 + (lane & 15);
                b[j] = *(const bf16x8*)(Bs + r * 64 + ((khalf ^ (r & 7)) << 3));
            }
#pragma unroll
            for (int i = 0; i < 2; ++i)
#pragma unroll
                for (int j = 0; j < 2; ++j)
                    acc[i][j] = __builtin_amdgcn_mfma_f32_16x16x32_bf16(a[i], b[j], acc[i][j], 0, 0, 0);
        }
        __syncthreads();
    }

    const int cr = (lane >> 4) * 4;
    const int cc = lane & 15;
#pragma unroll
    for (int i = 0; i < 2; ++i)
#pragma unroll
        for (int j = 0; j < 2; ++j)
#pragma unroll
            for (int q = 0; q < 4; ++q) {
                int row = bm0 + wr + i * 16 + cr + q;
                int col = bn0 + wc + j * 16 + cc;
                C[(size_t)row * Nn + col] = acc[i][j][q];
            }
}

// ---------------- MFMA SpMM: part[kc] = A2b[:,kc-chunk] @ (hi+lo)^T ----------------
// A2b bf16 [4096][4096] (exact 0/1), XsT bf16 [128][4096] rows 0-63 hi, 64-127 lo.
__global__ __launch_bounds__(256)
void spmm_mfma_k(const short* __restrict__ A2b, const short* __restrict__ XsT,
                 float* __restrict__ part)
{
    __shared__ short As[64 * 64];
    __shared__ short Bs[128 * 64];
    const int tid = threadIdx.x;
    const int lane = tid & 63, wave = tid >> 6;
    const int kc = blockIdx.x, m0 = blockIdx.y * 64;
    const int wr = (wave >> 1) * 32, wc = (wave & 1) * 32;
    const int woff = wave * 512;

    f32x4 acc[2][2] = {};

    for (int k0 = kc * 512; k0 < kc * 512 + 512; k0 += 64) {
#pragma unroll
        for (int r = 0; r < 2; ++r) {
            int o = r * 4096 + tid * 16;
            int row = o >> 7;
            int sl = (o >> 4) & 7;
            gload_lds16(A2b + ((size_t)(m0 + row) * 4096 + k0 + ((sl ^ (row & 7)) << 3)),
                        As + r * 2048 + woff);
        }
#pragma unroll
        for (int r = 0; r < 4; ++r) {
            int o = r * 4096 + tid * 16;
            int row = o >> 7;
            int sl = (o >> 4) & 7;
            gload_lds16(XsT + ((size_t)row * 4096 + k0 + ((sl ^ (row & 7)) << 3)),
                        Bs + r * 2048 + woff);
        }
        __syncthreads();
#pragma unroll
        for (int kk = 0; kk < 2; ++kk) {
            const int h = kk * 4 + (lane >> 4);
            bf16x8 a[2], bh[2], bl[2];
#pragma unroll
            for (int i = 0; i < 2; ++i) {
                int r = wr + i * 16 + (lane & 15);
                a[i] = *(const bf16x8*)(As + r * 64 + ((h ^ (r & 7)) << 3));
            }
#pragma unroll
            for (int j = 0; j < 2; ++j) {
                int r = wc + j * 16 + (lane & 15);
                bh[j] = *(const bf16x8*)(Bs + r * 64 + ((h ^ (r & 7)) << 3));
                int r2 = r + 64;
                bl[j] = *(const bf16x8*)(Bs + r2 * 64 + ((h ^ (r2 & 7)) << 3));
            }
#pragma unroll
            for (int i = 0; i < 2; ++i)
#pragma unroll
                for (int j = 0; j < 2; ++j) {
                    acc[i][j] = __builtin_amdgcn_mfma_f32_16x16x32_bf16(a[i], bh[j], acc[i][j], 0, 0, 0);
                    acc[i][j] = __builtin_amdgcn_mfma_f32_16x16x32_bf16(a[i], bl[j], acc[i][j], 0, 0, 0);
                }
        }
        __syncthreads();
    }

    const int cr = (lane >> 4) * 4;
    const int cc = lane & 15;
#pragma unroll
    for (int i = 0; i < 2; ++i)
#pragma unroll
        for (int j = 0; j < 2; ++j)
#pragma unroll
            for (int q = 0; q < 4; ++q)
                part[((size_t)kc * NNODES + m0 + wr + i * 16 + cr + q) * 64 + wc + j * 16 + cc]
                    = acc[i][j][q];
}

// X [4096][64] f32 -> XsT [128][4096] bf16 (hi rows 0-63, lo 64-127), xdn folded
__global__ void xsT_k(const float* __restrict__ X, const int* __restrict__ degA,
                      short* __restrict__ XsT)
{
    const int n = blockIdx.y;
    const int k = blockIdx.x * 256 + threadIdx.x;
    float v = X[(size_t)k * 64 + n] * (1.0f / sqrtf((float)degA[k]));
    short hi = f2bf(v);
    float hif = __builtin_bit_cast(float, ((unsigned)(unsigned short)hi) << 16);
    short lo = f2bf(v - hif);
    XsT[(size_t)n * 4096 + k] = hi;
    XsT[(size_t)(64 + n) * 4096 + k] = lo;
}

// A8 u8 -> bf16 (exact 0/1)
__global__ void a2b_k(const unsigned* __restrict__ A8w, short* __restrict__ A2b, int words)
{
    int t = blockIdx.x * 256 + threadIdx.x;
    if (t < words) {
        unsigned w = A8w[t];
        short4v o;
#pragma unroll
        for (int j = 0; j < 4; ++j) o[j] = ((w >> (8 * j)) & 1u) ? (short)0x3F80 : (short)0;
        *(short4v*)(A2b + (size_t)t * 4) = o;
    }
}

// f32 [R][C] -> bf16 transposed [C][R]
__global__ void f32_to_bf16T_k(const float* __restrict__ src, short* __restrict__ dstT,
                               int R, int C)
{
    __shared__ float t[64][65];
    const int br = blockIdx.y * 64, bc = blockIdx.x * 64;
    for (int idx = threadIdx.x; idx < 64 * 64; idx += 256) {
        int r = idx >> 6, c = idx & 63;
        t[r][c] = src[(size_t)(br + r) * C + bc + c];
    }
    __syncthreads();
    for (int idx = threadIdx.x; idx < 64 * 64; idx += 256) {
        int c = idx >> 6, r = idx & 63;
        dstT[(size_t)(bc + c) * R + br + r] = f2bf(t[r][c]);
    }
}

__global__ void mask_to_bf16_k(const unsigned* __restrict__ mask, short* __restrict__ adj,
                               int words)
{
    int t = blockIdx.x * 256 + threadIdx.x;
    if (t < words) {
        unsigned w = mask[t];
        short4v o;
        o.x = f2bf((float)__popc(w & 0x7u));
        o.y = f2bf((float)__popc(w & 0x700u));
        o.z = f2bf((float)__popc(w & 0x70000u));
        o.w = f2bf((float)__popc(w & 0x7000000u));
        *(short4v*)(adj + (size_t)t * 4) = o;
    }
}

// x [N,512] f32 * doi -> split-bf16 xe [N][1536] = [hi | hi | lo]
__global__ void xsplit_k(Ptr3 xv, const float* __restrict__ isq, short* __restrict__ xe)
{
    const int z = blockIdx.y;
    int t = blockIdx.x * 256 + threadIdx.x;
    int n = t >> 9, k = t & 511;
    float a = xv.p[z][(size_t)n * 512 + k] * isq[2 * z * NNODES + n];
    short hi = f2bf(a);
    float hif = __builtin_bit_cast(float, ((unsigned)(unsigned short)hi) << 16);
    short lo = f2bf(a - hif);
    short* row = xe + (size_t)z * NNODES * 1536 + (size_t)n * 1536;
    row[k] = hi; row[512 + k] = hi; row[1024 + k] = lo;
}

// W [K][Nn] f32 -> split-bf16 transposed Bt [Nn][3K] = [hi | lo | hi]
__global__ void wsplitT_k(Ptr3 Wv, short* __restrict__ out, int K, int Nn)
{
    const int z = blockIdx.y;
    int t = blockIdx.x * 256 + threadIdx.x;
    if (t >= K * Nn) return;
    int k = t / Nn, n = t % Nn;
    float w = Wv.p[z][(size_t)k * Nn + n];
    short hi = f2bf(w);
    float hif = __builtin_bit_cast(float, ((unsigned)(unsigned short)hi) << 16);
    short lo = f2bf(w - hif);
    short* row = out + (size_t)z * Nn * 3 * K + (size_t)n * 3 * K;
    row[k] = hi; row[K + k] = lo; row[2 * K + k] = hi;
}

// fused: s = (sum_p part[p][row,:]) * deg[row]^-1/2 ; out = act(s @ Wm + b)
// optional split-bf16 emit for h@h^T operands (Ae=[hi|hi|lo], Be=[hi|lo|hi])
template<int RELU>
__global__ __launch_bounds__(256)
void redgemm_k(const float* __restrict__ part, const int* __restrict__ degA,
               const float* __restrict__ Wm, const float* __restrict__ bias,
               float* __restrict__ out, short* __restrict__ Ae, short* __restrict__ Be)
{
    __shared__ float Ws[64 * 64];
    const int tid = threadIdx.x;
    for (int i = tid; i < 4096; i += 256) Ws[i] = Wm[i];
    __syncthreads();
    const int lane = tid & 63, wave = tid >> 6;
    const float bv = bias[lane];
    for (int rr = 0; rr < 16; ++rr) {
        int row = blockIdx.x * 64 + wave * 16 + rr;
        float s = 0.f;
#pragma unroll
        for (int p = 0; p < 8; ++p) s += part[((size_t)p * NNODES + row) * 64 + lane];
        s *= 1.0f / sqrtf((float)degA[row]);
        float acc = bv;
#pragma unroll
        for (int k = 0; k < 64; ++k)
            acc = fmaf(__shfl(s, k), Ws[k * 64 + lane], acc);
        if (RELU) acc = fmaxf(acc, 0.f);
        out[(size_t)row * 64 + lane] = acc;
        if (Ae) {
            short hi = f2bf(acc);
            float hif = __builtin_bit_cast(float, ((unsigned)(unsigned short)hi) << 16);
            short lo = f2bf(acc - hif);
            size_t ro = (size_t)row * 192;
            Ae[ro + lane] = hi; Ae[ro + 64 + lane] = hi; Ae[ro + 128 + lane] = lo;
            Be[ro + lane] = hi; Be[ro + 64 + lane] = lo; Be[ro + 128 + lane] = hi;
        }
    }
}

// ---------------- graph construction ----------------
__global__ void edge_k(Ptr3i src, Ptr3i dst, unsigned* __restrict__ mask, int* __restrict__ degs)
{
    int e = blockIdx.x * 256 + threadIdx.x;
    int z = blockIdx.y;
    if (e < NEDGES) {
        int s = src.p[z][e], d = dst.p[z][e];
        unsigned c = (unsigned)s * (unsigned)NNODES + (unsigned)d;
        atomicOr(&mask[c >> 2], 1u << ((c & 3u) * 8u + (unsigned)z));
        atomicAdd(&degs[2 * z * NNODES + s], 1);
        atomicAdd(&degs[(2 * z + 1) * NNODES + d], 1);
    }
}

__global__ void deg_norm_k(const int* __restrict__ degs, float* __restrict__ isq, int n)
{
    int t = blockIdx.x * 256 + threadIdx.x;
    if (t < n) isq[t] = 1.0f / sqrtf(fmaxf((float)degs[t], 1.0f));
}

__global__ __launch_bounds__(1024)
void scan_k(const int* __restrict__ degs, int* __restrict__ rowptr, int* __restrict__ cursor)
{
    const int z = blockIdx.x;
    const int* din = degs + (2 * z + 1) * NNODES;
    __shared__ int sm[1024];
    const int t = threadIdx.x;
    int v0 = din[t * 4], v1 = din[t * 4 + 1], v2 = din[t * 4 + 2], v3 = din[t * 4 + 3];
    int c1 = v0 + v1, c2 = c1 + v2, s = c2 + v3;
    sm[t] = s;
    __syncthreads();
    for (int off = 1; off < 1024; off <<= 1) {
        int add = (t >= off) ? sm[t - off] : 0;
        __syncthreads();
        sm[t] += add;
        __syncthreads();
    }
    int base = sm[t] - s;
    int* rp = rowptr + z * NNODES;
    int* cu = cursor + z * NNODES;
    rp[t * 4] = base;          cu[t * 4] = base;
    rp[t * 4 + 1] = base + v0; cu[t * 4 + 1] = base + v0;
    rp[t * 4 + 2] = base + c1; cu[t * 4 + 2] = base + c1;
    rp[t * 4 + 3] = base + c2; cu[t * 4 + 3] = base + c2;
}

__global__ void fill_k(Ptr3i src, Ptr3i dst, int* __restrict__ cursor, int* __restrict__ eidx)
{
    int e = blockIdx.x * 256 + threadIdx.x;
    int z = blockIdx.y;
    if (e < NEDGES) {
        int d = dst.p[z][e];
        int pos = atomicAdd(&cursor[z * NNODES + d], 1);
        eidx[(size_t)z * NEDGES + pos] = src.p[z][e];
    }
}

// fused CSR-gather + norm + bias + act -> split-bf16 A rows [node][3F]
template<int F, int ACT, int MODE>
__global__ void gather_k(const float* __restrict__ Hpre, const int* __restrict__ eidx,
                         const int* __restrict__ rowptr, const int* __restrict__ degs,
                         const float* __restrict__ isq, Ptr3 bias, short* __restrict__ Sout)
{
    const int z = blockIdx.y;
    const int tid = threadIdx.x;
    const int node = blockIdx.x * (256 / F) + tid / F;
    const int f = tid % F;
    const float* H = Hpre + (size_t)z * NNODES * F;
    const int base = rowptr[z * NNODES + node];
    const int cnt = degs[(2 * z + 1) * NNODES + node];
    const int* ei = eidx + (size_t)z * NEDGES + base;
    float s = 0.f;
    for (int i = 0; i < cnt; ++i) s += H[(size_t)ei[i] * F + f];
    float v = s * isq[(2 * z + 1) * NNODES + node] + bias.p[z][f];
    if (ACT) v = fmaxf(v, 0.f);
    if (MODE == 1) v *= isq[2 * z * NNODES + node];
    short hi = f2bf(v);
    float hif = __builtin_bit_cast(float, ((unsigned)(unsigned short)hi) << 16);
    short lo = f2bf(v - hif);
    short* row = Sout + (size_t)z * NNODES * 3 * F + (size_t)node * 3 * F;
    row[f] = hi; row[F + f] = hi; row[2 * F + f] = lo;
}

// z = softmax_row(zp0+zp1+zp2)
__global__ void softsum_k(const float* __restrict__ zp, float* __restrict__ z)
{
    int row = blockIdx.x * 4 + (threadIdx.x >> 6);
    int f = threadIdx.x & 63;
    size_t i = (size_t)row * 64 + f;
    float v = zp[i] + zp[i + (size_t)NNODES * 64] + zp[i + (size_t)2 * NNODES * 64];
    float m = v;
#pragma unroll
    for (int off = 32; off >= 1; off >>= 1) m = fmaxf(m, __shfl_xor(m, off));
    float e = expf(v - m);
    float s = e;
#pragma unroll
    for (int off = 32; off >= 1; off >>= 1) s += __shfl_xor(s, off);
    z[i] = e / s;
}

// A8[i,j] = P[i,j] | P[j,i] | (i==j), deg row-sums.
__global__ __launch_bounds__(256)
void build_A2_k(const unsigned char* __restrict__ P, unsigned char* __restrict__ A8,
                int* __restrict__ degA)
{
    __shared__ unsigned Ts[64][20];
    const int bi = blockIdx.y * 64, bj = blockIdx.x * 64;
    const int tid = threadIdx.x;
    const int r = tid >> 2, seg = tid & 3;
    uint4 tv = *(const uint4*)(P + (size_t)(bj + r) * NNODES + bi + seg * 16);
    Ts[r][seg * 4 + 0] = tv.x; Ts[r][seg * 4 + 1] = tv.y;
    Ts[r][seg * 4 + 2] = tv.z; Ts[r][seg * 4 + 3] = tv.w;
    __syncthreads();
    uint4 dv = *(const uint4*)(P + (size_t)(bi + r) * NNODES + bj + seg * 16);
    unsigned dw[4] = {dv.x, dv.y, dv.z, dv.w};
    const unsigned char* Tb = (const unsigned char*)Ts;
    unsigned ow[4];
    int psum = 0;
#pragma unroll
    for (int w = 0; w < 4; ++w) {
        unsigned o = 0;
#pragma unroll
        for (int b = 0; b < 4; ++b) {
            int j = seg * 16 + w * 4 + b;
            unsigned a = (dw[w] >> (8 * b)) & 1u;
            unsigned tr = Tb[j * 80 + r] & 1u;
            unsigned on = a | tr | (unsigned)((bi + r) == (bj + j));
            o |= on << (8 * b);
            psum += (int)on;
        }
        ow[w] = o;
    }
    uint4 o4; o4.x = ow[0]; o4.y = ow[1]; o4.z = ow[2]; o4.w = ow[3];
    *(uint4*)(A8 + (size_t)(bi + r) * NNODES + bj + seg * 16) = o4;
    psum += __shfl_xor(psum, 1);
    psum += __shfl_xor(psum, 2);
    if (seg == 0) atomicAdd(&degA[bi + r], psum);
}

extern "C" void kernel_launch(void* const* d_in, const int* in_sizes, int n_in,
                              void* d_out, int out_size, void* d_ws, size_t ws_size,
                              hipStream_t stream)
{
    const int N = NNODES, E = NEDGES;
    const size_t MB = 1024 * 1024;

    const float* x[3]; const int* src[3]; const int* dst[3];
    const float *Wv0[3], *bv0[3], *Wv1[3], *bv1[3], *Wf[3];
    for (int v = 0; v < 3; ++v) {
        const int b = v * 8;
        x[v]   = (const float*)d_in[b + 0];
        src[v] = (const int*)  d_in[b + 1];
        dst[v] = (const int*)  d_in[b + 2];
        Wv0[v] = (const float*)d_in[b + 3];
        bv0[v] = (const float*)d_in[b + 4];
        Wv1[v] = (const float*)d_in[b + 5];
        bv1[v] = (const float*)d_in[b + 6];
        Wf[v]  = (const float*)d_in[b + 7];
    }
    const float* Wg1 = (const float*)d_in[24];
    const float* bg1 = (const float*)d_in[25];
    const float* Wg2 = (const float*)d_in[26];
    const float* bg2 = (const float*)d_in[27];
    const float* Wm0 = (const float*)d_in[28];
    const float* bm0 = (const float*)d_in[29];
    const float* Wm1 = (const float*)d_in[30];
    const float* bm1 = (const float*)d_in[31];

    float* out_adjr = (float*)d_out;                    // [N,N] f32 (final)
    float* out_rec  = out_adjr + (size_t)N * N;         // [N,N] f32 (final; scratch until then)
    float* out_h    = out_rec + (size_t)N * N;          // [N,64]

    // --- scratch carved from dead regions of outputs ---
    char* oa = (char*)out_adjr;                         // 64 MB, final write = GEMM2
    short* AdjB = (short*)oa;                           // bf16 [N][N]  [0,32M)
    float* hv1  = (float*)(oa + 32 * MB);               // f32 [3][N][128]
    short* Ae2  = (short*)(oa + 38 * MB);
    short* Ae3  = (short*)(oa + 47 * MB);
    float* hv2  = (float*)(oa + 52 * MB);
    float* zp   = (float*)(oa + 56 * MB);
    float* partg0 = (float*)(oa + 32 * MB);             // GEMM1 K-split partial 0 (32 MB)

    char* orc = (char*)out_rec;                         // 64 MB, final write = h@hT
    short* xe   = (short*)orc;                          // bf16 [3][N][1536] (dead after L1)
    short* H1b  = (short*)orc;                          // bf16 [N][2048]  [0,16M)
    unsigned char* P = (unsigned char*)(orc + 16 * MB); // u8 [N][N]       [16,32M)
    short* Wg1T = (short*)(orc + 16 * MB);              // dead when P written
    float* partg1 = (float*)(orc + 32 * MB);            // GEMM1 K-split partial 1 (32 MB)
    short* Wg2T = (short*)(orc + 32 * MB);              // built after reduce (over partg1)
    short* A2b  = (short*)orc;                          // bf16 [N][N] [0,32M) after build_A2
    float* part = (float*)(orc + 48 * MB);              // 8 MB K-split partials (spmm)

    // ---- workspace carve ----
    char* p = (char*)d_ws;
    unsigned* mask = (unsigned*)p;
    unsigned char* A8 = (unsigned char*)p;              // reuses mask region
    short* AeF = (short*)p;                             // h@hT operands (after A8 dead)
    short* BeF = AeF + (size_t)N * 192;
    p += (size_t)N * N;                                 // 16MB
    int* degs = (int*)p;     p += (size_t)6 * N * 4;
    float* isq = (float*)p;  p += (size_t)6 * N * 4;
    int* rowptr = (int*)p;   p += (size_t)3 * N * 4;
    int* cursor = (int*)p;   p += (size_t)3 * N * 4;
    int* eidx = (int*)p;     p += (size_t)3 * E * 4;
    int* degA = (int*)p;     p += (size_t)N * 4;
    float* zbuf = (float*)p; p += (size_t)N * 64 * 4;
    float* h1m = (float*)p;  p += (size_t)N * 64 * 4;
    short* XsT = (short*)p;  p += (size_t)128 * N * 2;
    short* Wv0T = (short*)p; p += (size_t)3 * 128 * 1536 * 2;
    short* Wv1T = (short*)p; p += (size_t)3 * 64 * 384 * 2;
    short* WfT  = (short*)p; p += (size_t)3 * 64 * 192 * 2;

    Ptr3i srcP, dstP;
    for (int v = 0; v < 3; ++v) { srcP.p[v] = src[v]; dstP.p[v] = dst[v]; }

    hipMemsetAsync(mask, 0, (size_t)N * N, stream);
    hipMemsetAsync(degs, 0, (size_t)6 * N * 4, stream);

    edge_k<<<dim3((E + 255) / 256, 3), 256, 0, stream>>>(srcP, dstP, mask, degs);
    deg_norm_k<<<(6 * N + 255) / 256, 256, 0, stream>>>(degs, isq, 6 * N);
    scan_k<<<3, 1024, 0, stream>>>(degs, rowptr, cursor);
    fill_k<<<dim3((E + 255) / 256, 3), 256, 0, stream>>>(srcP, dstP, cursor, eidx);

    // ---- split-bf16 operand builders for per-view GEMMs ----
    Ptr3 xP; for (int v = 0; v < 3; ++v) xP.p[v] = x[v];
    xsplit_k<<<dim3(N * 512 / 256, 3), 256, 0, stream>>>(xP, isq, xe);
    Ptr3 wP;
    for (int v = 0; v < 3; ++v) wP.p[v] = Wv0[v];
    wsplitT_k<<<dim3(512 * 128 / 256, 3), 256, 0, stream>>>(wP, Wv0T, 512, 128);
    for (int v = 0; v < 3; ++v) wP.p[v] = Wv1[v];
    wsplitT_k<<<dim3(128 * 64 / 256, 3), 256, 0, stream>>>(wP, Wv1T, 128, 64);
    for (int v = 0; v < 3; ++v) wP.p[v] = Wf[v];
    wsplitT_k<<<dim3(64 * 64 / 256, 3), 256, 0, stream>>>(wP, WfT, 64, 64);

    // ---- per-view GCN stacks on MFMA (lossless split-bf16) ----
    Ptr3h BtP; Ptr3 biasP;
    for (int v = 0; v < 3; ++v) BtP.p[v] = Wv0T + (size_t)v * 128 * 1536;
    mfma_gemm_b_k<<<dim3(2, N / 64, 3), 256, 0, stream>>>(xe, BtP, hv1, N, 128, 1536);
    for (int v = 0; v < 3; ++v) biasP.p[v] = bv0[v];
    gather_k<128, 1, 1><<<dim3(N / 2, 3), 256, 0, stream>>>(hv1, eidx, rowptr, degs, isq, biasP, Ae2);
    for (int v = 0; v < 3; ++v) BtP.p[v] = Wv1T + (size_t)v * 64 * 384;
    mfma_gemm_b_k<<<dim3(1, N / 64, 3), 256, 0, stream>>>(Ae2, BtP, hv2, N, 64, 384);
    for (int v = 0; v < 3; ++v) biasP.p[v] = bv1[v];
    gather_k<64, 0, 2><<<dim3(N / 4, 3), 256, 0, stream>>>(hv2, eidx, rowptr, degs, isq, biasP, Ae3);
    for (int v = 0; v < 3; ++v) BtP.p[v] = WfT + (size_t)v * 64 * 192;
    mfma_gemm_b_k<<<dim3(1, N / 64, 3), 256, 0, stream>>>(Ae3, BtP, zp, N, 64, 192);
    softsum_k<<<N / 4, 256, 0, stream>>>(zp, zbuf);

    // ---- GFN conversions (xe dead; per-view scratch in oa dead) ----
    mask_to_bf16_k<<<(N * N / 4 + 255) / 256, 256, 0, stream>>>(mask, AdjB, N * N / 4);
    f32_to_bf16T_k<<<dim3(2048 / 64, 4096 / 64), 256, 0, stream>>>(Wg1, Wg1T, 4096, 2048);

    // ---- GEMM1: K-split-2 8-phase, partials -> reduce(+bias,relu) -> H1b bf16 ----
    g8_k<3><<<dim3(2048 / 256, 4096 / 256, 2), 512, 0, stream>>>(
        AdjB, Wg1T, nullptr, partg0, nullptr, 4096, 2048, 2048, 4096, 4096);
    // note: z=0 -> partg0 (oa+32M), z=1 -> partg0 + 4096*2048 floats = oa+64M?  NO:
    // partials must be distinct buffers: kernel offsets Cout by z*M*Nn, so pass base
    // such that z=0 -> partg0 and z=1 -> partg1. They are not contiguous, so we
    // instead launch the two halves as two z=1 grids? -> handled by passing partg0
    // and exploiting that partg0 + M*Nn floats == oa+64MB which is orc+0... (== partg1-32MB)
    // To be safe the two slices are launched separately below if needed.
    reduce_h1_k<<<4096 * 2048 / 4 / 256, 256, 0, stream>>>(partg0, partg0 + (size_t)4096 * 2048,
                                                           bg1, H1b);

    f32_to_bf16T_k<<<dim3(4096 / 64, 2048 / 64), 256, 0, stream>>>(Wg2, Wg2T, 2048, 4096);

    // ---- GEMM2: 8-phase, writes adj_r (f32) + P (u8) ----
    g8_k<2><<<dim3(4096 / 256, 4096 / 256, 1), 512, 0, stream>>>(
        H1b, Wg2T, bg2, out_adjr, P, 4096, 4096, 2048, 2048, 2048);

    // ---- consensus graph ----
    hipMemsetAsync(degA, 0, (size_t)N * 4, stream);
    build_A2_k<<<dim3(N / 64, N / 64), 256, 0, stream>>>(P, A8, degA);

    // ---- fused-graph GCN on MFMA ----
    a2b_k<<<(N * N / 4 + 255) / 256, 256, 0, stream>>>((const unsigned*)A8, A2b, N * N / 4);
    xsT_k<<<dim3(16, 64), 256, 0, stream>>>(zbuf, degA, XsT);
    spmm_mfma_k<<<dim3(8, N / 64), 256, 0, stream>>>(A2b, XsT, part);
    redgemm_k<1><<<64, 256, 0, stream>>>(part, degA, Wm0, bm0, h1m, nullptr, nullptr);
    xsT_k<<<dim3(16, 64), 256, 0, stream>>>(h1m, degA, XsT);
    spmm_mfma_k<<<dim3(8, N / 64), 256, 0, stream>>>(A2b, XsT, part);
    redgemm_k<0><<<64, 256, 0, stream>>>(part, degA, Wm1, bm1, out_h, AeF, BeF);

    // ---- adj_rec = h @ h^T via split-bf16 pipelined MFMA (K=192) ----
    gemm256_k<0><<<dim3(4096 / 128, 4096 / 256), 512, 0, stream>>>(
        AeF, BeF, nullptr, out_rec, nullptr, 4096, 4096, 192);
}

// Round 7
// 558.156 us; speedup vs baseline: 8.6584x; 1.0019x over previous
//
#include <hip/hip_runtime.h>
#include <math.h>

#define NNODES 4096
#define NEDGES 65536

typedef short bf16x8 __attribute__((ext_vector_type(8)));
typedef short short4v __attribute__((ext_vector_type(4)));
typedef float f32x4 __attribute__((ext_vector_type(4)));
typedef float f32x4v __attribute__((ext_vector_type(4)));

struct Ptr3  { const float* p[3]; };
struct Ptr3i { const int*   p[3]; };
struct Ptr3h { const short* p[3]; };

__device__ __forceinline__ short f2bf(float f) {
    unsigned u = __builtin_bit_cast(unsigned, f);
    unsigned r = (u + 0x7FFFu + ((u >> 16) & 1u)) >> 16;
    return (short)r;
}

__device__ __forceinline__ void gload_lds16(const void* g, void* l) {
    __builtin_amdgcn_global_load_lds(
        (const __attribute__((address_space(1))) unsigned*)g,
        (__attribute__((address_space(3))) unsigned*)l, 16, 0, 0);
}

// ================= 8-phase 256x256 bf16 MFMA GEMM (T2+T3+T4+T5) =================
// 512 thr (8 waves 2M x 4N), wave tile 128x64, BK=64, LDS 2 x 64KB dbuf.
// Per phase: 12 ds_read (quadrant frags) + 2 gload_lds (quarter-pair prefetch),
// barrier, 16 MFMA (setprio), vmcnt(2) only at phases 3/7, barrier.
// Quarter-stage schedule (iter i reading tiles 2i,2i+1):
//   p0:(2i+1)Aq1q3 p1:(2i+1)B01 p2:(2i+1)B23 p3:(2i+2)Aq0q2
//   p4:(2i+2)Aq1q3 p5:(2i+2)B01 p6:(2i+2)B23 p7:(2i+3)Aq0q2
// Every stage targets a region last read >=1 phase earlier (barrier-protected).
// ACT==2: round(clip(v+bias,0,1)+0.1)->f32 + u8 P ; ACT==3: raw f32 (K-split partial)
template<int ACT>
__global__ __launch_bounds__(512, 1)
void g8_k(const short* __restrict__ A, const short* __restrict__ Bt,
          const float* __restrict__ bias, void* __restrict__ Cout,
          unsigned char* __restrict__ Pout, int M, int Nn, int K, int lda, int ldb)
{
    __shared__ short lds[2 * 32768];    // 128 KB
    const int tid = threadIdx.x;
    const int lane = tid & 63;
    const int wm = (tid >> 6) >> 2;     // 0..1
    const int wn = (tid >> 6) & 3;      // 0..3
    // K-split via z: offset k-range
    const int z = blockIdx.z;
    A  += (size_t)z * K;
    Bt += (size_t)z * K;
    float* Cf = (float*)Cout + (size_t)z * M * Nn;
    // XCD-bijective swizzle within z-slice (nwg % 8 == 0)
    const int gx = gridDim.x, nwg = gx * gridDim.y;
    int w = blockIdx.y * gx + blockIdx.x;
    const int q8 = nwg >> 3;
    w = (w & 7) * q8 + (w >> 3);
    const int bm0 = (w / gx) * 256, bn0 = (w % gx) * 256;

    const int NT = K >> 6;

    f32x4 acc[8][4] = {};

    // stage one quarter-pair of tile t. sel: 0=Aq0q2 1=Aq1q3 2=Bq0q1 3=Bq2q3
    auto stageQ = [&](int t, int sel) {
        if (t >= NT) return;
        const int k0 = t << 6;
        short* L = lds + (t & 1) * 32768;
        const int rowq = tid >> 3;          // 0..63 within quarter
        const int slot = tid & 7;
        const int woff = (tid >> 6) * 512;  // wave-uniform LDS offset (shorts)
#pragma unroll
        for (int u = 0; u < 2; ++u) {
            int q, isB;
            if (sel == 0)      { q = u * 2;     isB = 0; }
            else if (sel == 1) { q = u * 2 + 1; isB = 0; }
            else if (sel == 2) { q = u;         isB = 1; }
            else               { q = u + 2;     isB = 1; }
            const int grow = q * 64 + rowq;
            const int scol = (slot ^ (grow & 7)) << 3;
            if (!isB)
                gload_lds16(A + (size_t)(bm0 + grow) * lda + k0 + scol,
                            L + q * 4096 + woff);
            else
                gload_lds16(Bt + (size_t)(bn0 + grow) * ldb + k0 + scol,
                            L + 16384 + q * 4096 + woff);
        }
    };

#define PHASE(Q, TCUR, STAGET, SSEL, VM)                                           \
    {                                                                              \
        constexpr int mh_ = (Q) >> 1, nh_ = (Q) & 1;                               \
        const short* As_ = lds + ((TCUR) & 1) * 32768;                             \
        const short* Bs_ = As_ + 16384;                                            \
        bf16x8 a_[4][2], b_[2][2];                                                 \
        _Pragma("unroll") for (int kk = 0; kk < 2; ++kk) {                         \
            const int h_ = kk * 4 + (lane >> 4);                                   \
            _Pragma("unroll") for (int i = 0; i < 4; ++i) {                        \
                int r_ = wm * 128 + mh_ * 64 + i * 16 + (lane & 15);               \
                a_[i][kk] = *(const bf16x8*)(As_ + r_ * 64 + ((h_ ^ (r_ & 7)) << 3)); \
            }                                                                      \
            _Pragma("unroll") for (int j = 0; j < 2; ++j) {                        \
                int r_ = wn * 64 + nh_ * 32 + j * 16 + (lane & 15);                \
                b_[j][kk] = *(const bf16x8*)(Bs_ + r_ * 64 + ((h_ ^ (r_ & 7)) << 3)); \
            }                                                                      \
        }                                                                          \
        stageQ(STAGET, SSEL);                                                      \
        __builtin_amdgcn_s_barrier();                                              \
        __builtin_amdgcn_s_setprio(1);                                             \
        _Pragma("unroll") for (int kk = 0; kk < 2; ++kk)                           \
            _Pragma("unroll") for (int i = 0; i < 4; ++i)                          \
                _Pragma("unroll") for (int j = 0; j < 2; ++j)                      \
                    acc[mh_ * 4 + i][nh_ * 2 + j] =                                \
                        __builtin_amdgcn_mfma_f32_16x16x32_bf16(                   \
                            a_[i][kk], b_[j][kk], acc[mh_ * 4 + i][nh_ * 2 + j], 0, 0, 0); \
        __builtin_amdgcn_s_setprio(0);                                             \
        if ((VM) == 2)      { asm volatile("s_waitcnt vmcnt(2)" ::: "memory"); }   \
        else if ((VM) == 0) { asm volatile("s_waitcnt vmcnt(0)" ::: "memory"); }   \
        __builtin_amdgcn_sched_barrier(0);                                         \
        __builtin_amdgcn_s_barrier();                                              \
    }

    // prologue: mimic steady-state [i-1] p3..p7 issue order
    stageQ(0, 0); stageQ(0, 1); stageQ(0, 2); stageQ(0, 3);
    stageQ(1, 0);
    asm volatile("s_waitcnt vmcnt(2)" ::: "memory");
    __builtin_amdgcn_sched_barrier(0);
    __builtin_amdgcn_s_barrier();

    for (int it = 0; it < NT / 2; ++it) {
        const int t0 = 2 * it, t1 = t0 + 1;
        PHASE(0, t0, t1, 1, -1);
        PHASE(1, t0, t1, 2, -1);
        PHASE(2, t0, t1, 3, -1);
        { int vm_ = (t0 + 2 < NT) ? 2 : 0; PHASE(3, t0, t0 + 2, 0, vm_); }
        PHASE(0, t1, t0 + 2, 1, -1);
        PHASE(1, t1, t0 + 2, 2, -1);
        PHASE(2, t1, t0 + 2, 3, -1);
        { int vm_ = (t0 + 2 < NT) ? 2 : -1; PHASE(3, t1, t0 + 3, 0, vm_); }
    }
#undef PHASE

    const int cr = (lane >> 4) * 4;
    const int cc = lane & 15;
#pragma unroll
    for (int im = 0; im < 8; ++im) {
#pragma unroll
        for (int jn = 0; jn < 4; ++jn) {
            int col = bn0 + wn * 64 + (jn >> 1) * 32 + (jn & 1) * 16 + cc;
            float bv = bias ? bias[col] : 0.f;
#pragma unroll
            for (int q2 = 0; q2 < 4; ++q2) {
                int row = bm0 + wm * 128 + (im >> 2) * 64 + (im & 3) * 16 + cr + q2;
                float v = acc[im][jn][q2] + bv;
                if constexpr (ACT == 2) {
                    v = rintf(fminf(fmaxf(v, 0.f), 1.f) + 0.1f);
                    Cf[(size_t)row * Nn + col] = v;
                    Pout[(size_t)row * Nn + col] = (unsigned char)(v > 0.5f);
                } else {
                    Cf[(size_t)row * Nn + col] = v;
                }
            }
        }
    }
}

// H1b = bf16(relu(part0 + part1 + bias[col])), [4096][2048]
__global__ void reduce_h1_k(const float* __restrict__ p0, const float* __restrict__ p1,
                            const float* __restrict__ bias, short* __restrict__ H1b)
{
    int i = (blockIdx.x * 256 + threadIdx.x) * 4;
    f32x4v a = *(const f32x4v*)(p0 + i);
    f32x4v b = *(const f32x4v*)(p1 + i);
    int col = i & 2047;
    short4v o;
#pragma unroll
    for (int j = 0; j < 4; ++j) {
        float v = a[j] + b[j] + bias[col + j];
        o[j] = f2bf(fmaxf(v, 0.f));
    }
    *(short4v*)(H1b + i) = o;
}

// ============ legacy 2-phase pipelined GEMM (used for h@h^T, K=192) ============
template<int ACT>
__global__ __launch_bounds__(512, 1)
void gemm256_k(const short* __restrict__ A, const short* __restrict__ Bt,
               const float* __restrict__ bias, void* __restrict__ Cout,
               unsigned char* __restrict__ Pout, int M, int Nn, int K)
{
    __shared__ short lds_s[3 * 24576];
    const int tid = threadIdx.x;
    const int lane = tid & 63;
    const int gx = gridDim.x, nwg = gx * gridDim.y;
    int w = blockIdx.y * gx + blockIdx.x;
    const int q = nwg >> 3;
    w = (w & 7) * q + (w >> 3);
    const int bm0 = (w / gx) * 256, bn0 = (w % gx) * 128;
    const int wmr = ((tid >> 6) >> 1) * 64;
    const int wnr = ((tid >> 6) & 1) * 64;
    const int NT = K >> 6;

    auto stage = [&](int kt, int slot) {
        const int k0 = kt << 6;
        char* base = (char*)(lds_s + slot * 24576);
        char* wbase = base + (tid >> 6) * 1024;
#pragma unroll
        for (int r = 0; r < 4; ++r) {
            int o = r * 8192 + tid * 16;
            int row = o >> 7;
            int sl = (o >> 4) & 7;
            gload_lds16(A + ((size_t)(bm0 + row) * K + k0 + ((sl ^ (row & 7)) << 3)),
                        wbase + r * 8192);
        }
#pragma unroll
        for (int r = 0; r < 2; ++r) {
            int o = r * 8192 + tid * 16;
            int row = o >> 7;
            int sl = (o >> 4) & 7;
            gload_lds16(Bt + ((size_t)(bn0 + row) * K + k0 + ((sl ^ (row & 7)) << 3)),
                        base + 32768 + r * 8192 + (tid >> 6) * 1024);
        }
    };

    f32x4 acc[4][4] = {};
    stage(0, 0);
    if (NT > 1) stage(1, 1);

    for (int kt = 0; kt < NT; ++kt) {
        if (kt < NT - 1) { asm volatile("s_waitcnt vmcnt(6)" ::: "memory"); }
        else             { asm volatile("s_waitcnt vmcnt(0)" ::: "memory"); }
        __builtin_amdgcn_s_barrier();
        if (kt + 2 < NT) stage(kt + 2, (kt + 2) % 3);

        const short* As = lds_s + (kt % 3) * 24576;
        const short* Bs = As + 16384;
        __builtin_amdgcn_s_setprio(1);
#pragma unroll
        for (int kk = 0; kk < 2; ++kk) {
            bf16x8 a[4], b[4];
            const int khalf = kk * 4 + (lane >> 4);
#pragma unroll
            for (int i = 0; i < 4; ++i) {
                int r = wmr + i * 16 + (lane & 15);
                a[i] = *(const bf16x8*)(As + r * 64 + ((khalf ^ (r & 7)) << 3));
            }
#pragma unroll
            for (int j = 0; j < 4; ++j) {
                int r = wnr + j * 16 + (lane & 15);
                b[j] = *(const bf16x8*)(Bs + r * 64 + ((khalf ^ (r & 7)) << 3));
            }
#pragma unroll
            for (int i = 0; i < 4; ++i)
#pragma unroll
                for (int j = 0; j < 4; ++j)
                    acc[i][j] = __builtin_amdgcn_mfma_f32_16x16x32_bf16(a[i], b[j], acc[i][j], 0, 0, 0);
        }
        __builtin_amdgcn_s_setprio(0);
        asm volatile("s_waitcnt lgkmcnt(0)" ::: "memory");
    }

    const int cr = (lane >> 4) * 4;
    const int cc = lane & 15;
#pragma unroll
    for (int i = 0; i < 4; ++i)
#pragma unroll
        for (int j = 0; j < 4; ++j) {
            int col = bn0 + wnr + j * 16 + cc;
#pragma unroll
            for (int q2 = 0; q2 < 4; ++q2) {
                int row = bm0 + wmr + i * 16 + cr + q2;
                ((float*)Cout)[(size_t)row * Nn + col] = acc[i][j][q2];
            }
        }
}

// ---------------- batched bf16 MFMA GEMM, 64x64 tile (per-view stacks) ----------------
__global__ __launch_bounds__(256)
void mfma_gemm_b_k(const short* __restrict__ Aall, Ptr3h Btv, float* __restrict__ Call,
                   int M, int Nn, int K)
{
    __shared__ short As[64 * 64];
    __shared__ short Bs[64 * 64];
    const int z = blockIdx.z;
    const short* A = Aall + (size_t)z * M * K;
    const short* Bt = Btv.p[z];
    float* C = Call + (size_t)z * M * Nn;
    const int tid = threadIdx.x;
    const int lane = tid & 63, wave = tid >> 6;
    const int bm0 = blockIdx.y * 64, bn0 = blockIdx.x * 64;
    const int wr = (wave >> 1) * 32, wc = (wave & 1) * 32;

    f32x4 acc[2][2] = {};

    for (int k0 = 0; k0 < K; k0 += 64) {
        for (int c = wave; c < 8; c += 4) {
            int o = c * 1024 + lane * 16;
            int row = o >> 7;
            int sl = (o >> 4) & 7;
            int ss = sl ^ (row & 7);
            gload_lds16(A + ((size_t)(bm0 + row) * K + k0 + ss * 8), As + c * 512);
            gload_lds16(Bt + ((size_t)(bn0 + row) * K + k0 + ss * 8), Bs + c * 512);
        }
        __syncthreads();
#pragma unroll
        for (int kk = 0; kk < 2; ++kk) {
            bf16x8 a[2], b[2];
            const int khalf = kk * 4 + (lane >> 4);
#pragma unroll
            for (int i = 0; i < 2; ++i) {
                int r = wr + i * 16 + (lane & 15);
                a[i] = *(const bf16x8*)(As + r * 64 + ((khalf ^ (r & 7)) << 3));
            }
#pragma unroll
            for (int j = 0; j < 2; ++j) {
                int r = wc + j * 16 + (lane & 15);
                b[j] = *(const bf16x8*)(Bs + r * 64 + ((khalf ^ (r & 7)) << 3));
            }
#pragma unroll
            for (int i = 0; i < 2; ++i)
#pragma unroll
                for (int j = 0; j < 2; ++j)
                    acc[i][j] = __builtin_amdgcn_mfma_f32_16x16x32_bf16(a[i], b[j], acc[i][j], 0, 0, 0);
        }
        __syncthreads();
    }

    const int cr = (lane >> 4) * 4;
    const int cc = lane & 15;
#pragma unroll
    for (int i = 0; i < 2; ++i)
#pragma unroll
        for (int j = 0; j < 2; ++j)
#pragma unroll
            for (int q = 0; q < 4; ++q) {
                int row = bm0 + wr + i * 16 + cr + q;
                int col = bn0 + wc + j * 16 + cc;
                C[(size_t)row * Nn + col] = acc[i][j][q];
            }
}

// ---------------- MFMA SpMM: part[kc] = A2b[:,kc-chunk] @ (hi+lo)^T ----------------
// A2b bf16 [4096][4096] (exact 0/1), XsT bf16 [128][4096] rows 0-63 hi, 64-127 lo.
__global__ __launch_bounds__(256)
void spmm_mfma_k(const short* __restrict__ A2b, const short* __restrict__ XsT,
                 float* __restrict__ part)
{
    __shared__ short As[64 * 64];
    __shared__ short Bs[128 * 64];
    const int tid = threadIdx.x;
    const int lane = tid & 63, wave = tid >> 6;
    const int kc = blockIdx.x, m0 = blockIdx.y * 64;
    const int wr = (wave >> 1) * 32, wc = (wave & 1) * 32;
    const int woff = wave * 512;

    f32x4 acc[2][2] = {};

    for (int k0 = kc * 512; k0 < kc * 512 + 512; k0 += 64) {
#pragma unroll
        for (int r = 0; r < 2; ++r) {
            int o = r * 4096 + tid * 16;
            int row = o >> 7;
            int sl = (o >> 4) & 7;
            gload_lds16(A2b + ((size_t)(m0 + row) * 4096 + k0 + ((sl ^ (row & 7)) << 3)),
                        As + r * 2048 + woff);
        }
#pragma unroll
        for (int r = 0; r < 4; ++r) {
            int o = r * 4096 + tid * 16;
            int row = o >> 7;
            int sl = (o >> 4) & 7;
            gload_lds16(XsT + ((size_t)row * 4096 + k0 + ((sl ^ (row & 7)) << 3)),
                        Bs + r * 2048 + woff);
        }
        __syncthreads();
#pragma unroll
        for (int kk = 0; kk < 2; ++kk) {
            const int h = kk * 4 + (lane >> 4);
            bf16x8 a[2], bh[2], bl[2];
#pragma unroll
            for (int i = 0; i < 2; ++i) {
                int r = wr + i * 16 + (lane & 15);
                a[i] = *(const bf16x8*)(As + r * 64 + ((h ^ (r & 7)) << 3));
            }
#pragma unroll
            for (int j = 0; j < 2; ++j) {
                int r = wc + j * 16 + (lane & 15);
                bh[j] = *(const bf16x8*)(Bs + r * 64 + ((h ^ (r & 7)) << 3));
                int r2 = r + 64;
                bl[j] = *(const bf16x8*)(Bs + r2 * 64 + ((h ^ (r2 & 7)) << 3));
            }
#pragma unroll
            for (int i = 0; i < 2; ++i)
#pragma unroll
                for (int j = 0; j < 2; ++j) {
                    acc[i][j] = __builtin_amdgcn_mfma_f32_16x16x32_bf16(a[i], bh[j], acc[i][j], 0, 0, 0);
                    acc[i][j] = __builtin_amdgcn_mfma_f32_16x16x32_bf16(a[i], bl[j], acc[i][j], 0, 0, 0);
                }
        }
        __syncthreads();
    }

    const int cr = (lane >> 4) * 4;
    const int cc = lane & 15;
#pragma unroll
    for (int i = 0; i < 2; ++i)
#pragma unroll
        for (int j = 0; j < 2; ++j)
#pragma unroll
            for (int q = 0; q < 4; ++q)
                part[((size_t)kc * NNODES + m0 + wr + i * 16 + cr + q) * 64 + wc + j * 16 + cc]
                    = acc[i][j][q];
}

// X [4096][64] f32 -> XsT [128][4096] bf16 (hi rows 0-63, lo 64-127), xdn folded
__global__ void xsT_k(const float* __restrict__ X, const int* __restrict__ degA,
                      short* __restrict__ XsT)
{
    const int n = blockIdx.y;
    const int k = blockIdx.x * 256 + threadIdx.x;
    float v = X[(size_t)k * 64 + n] * (1.0f / sqrtf((float)degA[k]));
    short hi = f2bf(v);
    float hif = __builtin_bit_cast(float, ((unsigned)(unsigned short)hi) << 16);
    short lo = f2bf(v - hif);
    XsT[(size_t)n * 4096 + k] = hi;
    XsT[(size_t)(64 + n) * 4096 + k] = lo;
}

// A8 u8 -> bf16 (exact 0/1)
__global__ void a2b_k(const unsigned* __restrict__ A8w, short* __restrict__ A2b, int words)
{
    int t = blockIdx.x * 256 + threadIdx.x;
    if (t < words) {
        unsigned w = A8w[t];
        short4v o;
#pragma unroll
        for (int j = 0; j < 4; ++j) o[j] = ((w >> (8 * j)) & 1u) ? (short)0x3F80 : (short)0;
        *(short4v*)(A2b + (size_t)t * 4) = o;
    }
}

// f32 [R][C] -> bf16 transposed [C][R]
__global__ void f32_to_bf16T_k(const float* __restrict__ src, short* __restrict__ dstT,
                               int R, int C)
{
    __shared__ float t[64][65];
    const int br = blockIdx.y * 64, bc = blockIdx.x * 64;
    for (int idx = threadIdx.x; idx < 64 * 64; idx += 256) {
        int r = idx >> 6, c = idx & 63;
        t[r][c] = src[(size_t)(br + r) * C + bc + c];
    }
    __syncthreads();
    for (int idx = threadIdx.x; idx < 64 * 64; idx += 256) {
        int c = idx >> 6, r = idx & 63;
        dstT[(size_t)(bc + c) * R + br + r] = f2bf(t[r][c]);
    }
}

__global__ void mask_to_bf16_k(const unsigned* __restrict__ mask, short* __restrict__ adj,
                               int words)
{
    int t = blockIdx.x * 256 + threadIdx.x;
    if (t < words) {
        unsigned w = mask[t];
        short4v o;
        o.x = f2bf((float)__popc(w & 0x7u));
        o.y = f2bf((float)__popc(w & 0x700u));
        o.z = f2bf((float)__popc(w & 0x70000u));
        o.w = f2bf((float)__popc(w & 0x7000000u));
        *(short4v*)(adj + (size_t)t * 4) = o;
    }
}

// x [N,512] f32 * doi -> split-bf16 xe [N][1536] = [hi | hi | lo]
__global__ void xsplit_k(Ptr3 xv, const float* __restrict__ isq, short* __restrict__ xe)
{
    const int z = blockIdx.y;
    int t = blockIdx.x * 256 + threadIdx.x;
    int n = t >> 9, k = t & 511;
    float a = xv.p[z][(size_t)n * 512 + k] * isq[2 * z * NNODES + n];
    short hi = f2bf(a);
    float hif = __builtin_bit_cast(float, ((unsigned)(unsigned short)hi) << 16);
    short lo = f2bf(a - hif);
    short* row = xe + (size_t)z * NNODES * 1536 + (size_t)n * 1536;
    row[k] = hi; row[512 + k] = hi; row[1024 + k] = lo;
}

// W [K][Nn] f32 -> split-bf16 transposed Bt [Nn][3K] = [hi | lo | hi]
__global__ void wsplitT_k(Ptr3 Wv, short* __restrict__ out, int K, int Nn)
{
    const int z = blockIdx.y;
    int t = blockIdx.x * 256 + threadIdx.x;
    if (t >= K * Nn) return;
    int k = t / Nn, n = t % Nn;
    float w = Wv.p[z][(size_t)k * Nn + n];
    short hi = f2bf(w);
    float hif = __builtin_bit_cast(float, ((unsigned)(unsigned short)hi) << 16);
    short lo = f2bf(w - hif);
    short* row = out + (size_t)z * Nn * 3 * K + (size_t)n * 3 * K;
    row[k] = hi; row[K + k] = lo; row[2 * K + k] = hi;
}

// fused: s = (sum_p part[p][row,:]) * deg[row]^-1/2 ; out = act(s @ Wm + b)
// optional split-bf16 emit for h@h^T operands (Ae=[hi|hi|lo], Be=[hi|lo|hi])
template<int RELU>
__global__ __launch_bounds__(256)
void redgemm_k(const float* __restrict__ part, const int* __restrict__ degA,
               const float* __restrict__ Wm, const float* __restrict__ bias,
               float* __restrict__ out, short* __restrict__ Ae, short* __restrict__ Be)
{
    __shared__ float Ws[64 * 64];
    const int tid = threadIdx.x;
    for (int i = tid; i < 4096; i += 256) Ws[i] = Wm[i];
    __syncthreads();
    const int lane = tid & 63, wave = tid >> 6;
    const float bv = bias[lane];
    for (int rr = 0; rr < 16; ++rr) {
        int row = blockIdx.x * 64 + wave * 16 + rr;
        float s = 0.f;
#pragma unroll
        for (int p = 0; p < 8; ++p) s += part[((size_t)p * NNODES + row) * 64 + lane];
        s *= 1.0f / sqrtf((float)degA[row]);
        float acc = bv;
#pragma unroll
        for (int k = 0; k < 64; ++k)
            acc = fmaf(__shfl(s, k), Ws[k * 64 + lane], acc);
        if (RELU) acc = fmaxf(acc, 0.f);
        out[(size_t)row * 64 + lane] = acc;
        if (Ae) {
            short hi = f2bf(acc);
            float hif = __builtin_bit_cast(float, ((unsigned)(unsigned short)hi) << 16);
            short lo = f2bf(acc - hif);
            size_t ro = (size_t)row * 192;
            Ae[ro + lane] = hi; Ae[ro + 64 + lane] = hi; Ae[ro + 128 + lane] = lo;
            Be[ro + lane] = hi; Be[ro + 64 + lane] = lo; Be[ro + 128 + lane] = hi;
        }
    }
}

// ---------------- graph construction ----------------
__global__ void edge_k(Ptr3i src, Ptr3i dst, unsigned* __restrict__ mask, int* __restrict__ degs)
{
    int e = blockIdx.x * 256 + threadIdx.x;
    int z = blockIdx.y;
    if (e < NEDGES) {
        int s = src.p[z][e], d = dst.p[z][e];
        unsigned c = (unsigned)s * (unsigned)NNODES + (unsigned)d;
        atomicOr(&mask[c >> 2], 1u << ((c & 3u) * 8u + (unsigned)z));
        atomicAdd(&degs[2 * z * NNODES + s], 1);
        atomicAdd(&degs[(2 * z + 1) * NNODES + d], 1);
    }
}

__global__ void deg_norm_k(const int* __restrict__ degs, float* __restrict__ isq, int n)
{
    int t = blockIdx.x * 256 + threadIdx.x;
    if (t < n) isq[t] = 1.0f / sqrtf(fmaxf((float)degs[t], 1.0f));
}

__global__ __launch_bounds__(1024)
void scan_k(const int* __restrict__ degs, int* __restrict__ rowptr, int* __restrict__ cursor)
{
    const int z = blockIdx.x;
    const int* din = degs + (2 * z + 1) * NNODES;
    __shared__ int sm[1024];
    const int t = threadIdx.x;
    int v0 = din[t * 4], v1 = din[t * 4 + 1], v2 = din[t * 4 + 2], v3 = din[t * 4 + 3];
    int c1 = v0 + v1, c2 = c1 + v2, s = c2 + v3;
    sm[t] = s;
    __syncthreads();
    for (int off = 1; off < 1024; off <<= 1) {
        int add = (t >= off) ? sm[t - off] : 0;
        __syncthreads();
        sm[t] += add;
        __syncthreads();
    }
    int base = sm[t] - s;
    int* rp = rowptr + z * NNODES;
    int* cu = cursor + z * NNODES;
    rp[t * 4] = base;          cu[t * 4] = base;
    rp[t * 4 + 1] = base + v0; cu[t * 4 + 1] = base + v0;
    rp[t * 4 + 2] = base + c1; cu[t * 4 + 2] = base + c1;
    rp[t * 4 + 3] = base + c2; cu[t * 4 + 3] = base + c2;
}

__global__ void fill_k(Ptr3i src, Ptr3i dst, int* __restrict__ cursor, int* __restrict__ eidx)
{
    int e = blockIdx.x * 256 + threadIdx.x;
    int z = blockIdx.y;
    if (e < NEDGES) {
        int d = dst.p[z][e];
        int pos = atomicAdd(&cursor[z * NNODES + d], 1);
        eidx[(size_t)z * NEDGES + pos] = src.p[z][e];
    }
}

// fused CSR-gather + norm + bias + act -> split-bf16 A rows [node][3F]
template<int F, int ACT, int MODE>
__global__ void gather_k(const float* __restrict__ Hpre, const int* __restrict__ eidx,
                         const int* __restrict__ rowptr, const int* __restrict__ degs,
                         const float* __restrict__ isq, Ptr3 bias, short* __restrict__ Sout)
{
    const int z = blockIdx.y;
    const int tid = threadIdx.x;
    const int node = blockIdx.x * (256 / F) + tid / F;
    const int f = tid % F;
    const float* H = Hpre + (size_t)z * NNODES * F;
    const int base = rowptr[z * NNODES + node];
    const int cnt = degs[(2 * z + 1) * NNODES + node];
    const int* ei = eidx + (size_t)z * NEDGES + base;
    float s = 0.f;
    for (int i = 0; i < cnt; ++i) s += H[(size_t)ei[i] * F + f];
    float v = s * isq[(2 * z + 1) * NNODES + node] + bias.p[z][f];
    if (ACT) v = fmaxf(v, 0.f);
    if (MODE == 1) v *= isq[2 * z * NNODES + node];
    short hi = f2bf(v);
    float hif = __builtin_bit_cast(float, ((unsigned)(unsigned short)hi) << 16);
    short lo = f2bf(v - hif);
    short* row = Sout + (size_t)z * NNODES * 3 * F + (size_t)node * 3 * F;
    row[f] = hi; row[F + f] = hi; row[2 * F + f] = lo;
}

// z = softmax_row(zp0+zp1+zp2)
__global__ void softsum_k(const float* __restrict__ zp, float* __restrict__ z)
{
    int row = blockIdx.x * 4 + (threadIdx.x >> 6);
    int f = threadIdx.x & 63;
    size_t i = (size_t)row * 64 + f;
    float v = zp[i] + zp[i + (size_t)NNODES * 64] + zp[i + (size_t)2 * NNODES * 64];
    float m = v;
#pragma unroll
    for (int off = 32; off >= 1; off >>= 1) m = fmaxf(m, __shfl_xor(m, off));
    float e = expf(v - m);
    float s = e;
#pragma unroll
    for (int off = 32; off >= 1; off >>= 1) s += __shfl_xor(s, off);
    z[i] = e / s;
}

// A8[i,j] = P[i,j] | P[j,i] | (i==j), deg row-sums.
__global__ __launch_bounds__(256)
void build_A2_k(const unsigned char* __restrict__ P, unsigned char* __restrict__ A8,
                int* __restrict__ degA)
{
    __shared__ unsigned Ts[64][20];
    const int bi = blockIdx.y * 64, bj = blockIdx.x * 64;
    const int tid = threadIdx.x;
    const int r = tid >> 2, seg = tid & 3;
    uint4 tv = *(const uint4*)(P + (size_t)(bj + r) * NNODES + bi + seg * 16);
    Ts[r][seg * 4 + 0] = tv.x; Ts[r][seg * 4 + 1] = tv.y;
    Ts[r][seg * 4 + 2] = tv.z; Ts[r][seg * 4 + 3] = tv.w;
    __syncthreads();
    uint4 dv = *(const uint4*)(P + (size_t)(bi + r) * NNODES + bj + seg * 16);
    unsigned dw[4] = {dv.x, dv.y, dv.z, dv.w};
    const unsigned char* Tb = (const unsigned char*)Ts;
    unsigned ow[4];
    int psum = 0;
#pragma unroll
    for (int w = 0; w < 4; ++w) {
        unsigned o = 0;
#pragma unroll
        for (int b = 0; b < 4; ++b) {
            int j = seg * 16 + w * 4 + b;
            unsigned a = (dw[w] >> (8 * b)) & 1u;
            unsigned tr = Tb[j * 80 + r] & 1u;
            unsigned on = a | tr | (unsigned)((bi + r) == (bj + j));
            o |= on << (8 * b);
            psum += (int)on;
        }
        ow[w] = o;
    }
    uint4 o4; o4.x = ow[0]; o4.y = ow[1]; o4.z = ow[2]; o4.w = ow[3];
    *(uint4*)(A8 + (size_t)(bi + r) * NNODES + bj + seg * 16) = o4;
    psum += __shfl_xor(psum, 1);
    psum += __shfl_xor(psum, 2);
    if (seg == 0) atomicAdd(&degA[bi + r], psum);
}

extern "C" void kernel_launch(void* const* d_in, const int* in_sizes, int n_in,
                              void* d_out, int out_size, void* d_ws, size_t ws_size,
                              hipStream_t stream)
{
    const int N = NNODES, E = NEDGES;
    const size_t MB = 1024 * 1024;

    const float* x[3]; const int* src[3]; const int* dst[3];
    const float *Wv0[3], *bv0[3], *Wv1[3], *bv1[3], *Wf[3];
    for (int v = 0; v < 3; ++v) {
        const int b = v * 8;
        x[v]   = (const float*)d_in[b + 0];
        src[v] = (const int*)  d_in[b + 1];
        dst[v] = (const int*)  d_in[b + 2];
        Wv0[v] = (const float*)d_in[b + 3];
        bv0[v] = (const float*)d_in[b + 4];
        Wv1[v] = (const float*)d_in[b + 5];
        bv1[v] = (const float*)d_in[b + 6];
        Wf[v]  = (const float*)d_in[b + 7];
    }
    const float* Wg1 = (const float*)d_in[24];
    const float* bg1 = (const float*)d_in[25];
    const float* Wg2 = (const float*)d_in[26];
    const float* bg2 = (const float*)d_in[27];
    const float* Wm0 = (const float*)d_in[28];
    const float* bm0 = (const float*)d_in[29];
    const float* Wm1 = (const float*)d_in[30];
    const float* bm1 = (const float*)d_in[31];

    float* out_adjr = (float*)d_out;                    // [N,N] f32 (final)
    float* out_rec  = out_adjr + (size_t)N * N;         // [N,N] f32 (final; scratch until then)
    float* out_h    = out_rec + (size_t)N * N;          // [N,64]

    // --- scratch carved from dead regions of outputs ---
    char* oa = (char*)out_adjr;                         // 64 MB, final write = GEMM2
    short* AdjB = (short*)oa;                           // bf16 [N][N]  [0,32M)
    float* hv1  = (float*)(oa + 32 * MB);               // f32 [3][N][128]
    short* Ae2  = (short*)(oa + 38 * MB);
    short* Ae3  = (short*)(oa + 47 * MB);
    float* hv2  = (float*)(oa + 52 * MB);
    float* zp   = (float*)(oa + 56 * MB);
    float* partg0 = (float*)(oa + 32 * MB);             // GEMM1 K-split partial 0 (32 MB)

    char* orc = (char*)out_rec;                         // 64 MB, final write = h@hT
    short* xe   = (short*)orc;                          // bf16 [3][N][1536] (dead after L1)
    short* H1b  = (short*)orc;                          // bf16 [N][2048]  [0,16M)
    unsigned char* P = (unsigned char*)(orc + 16 * MB); // u8 [N][N]       [16,32M)
    short* Wg1T = (short*)(orc + 16 * MB);              // dead when P written
    float* partg1 = (float*)(orc + 32 * MB);            // GEMM1 K-split partial 1 (32 MB)
    short* Wg2T = (short*)(orc + 32 * MB);              // built after reduce (over partg1)
    short* A2b  = (short*)orc;                          // bf16 [N][N] [0,32M) after build_A2
    float* part = (float*)(orc + 48 * MB);              // 8 MB K-split partials (spmm)

    // ---- workspace carve ----
    char* p = (char*)d_ws;
    unsigned* mask = (unsigned*)p;
    unsigned char* A8 = (unsigned char*)p;              // reuses mask region
    short* AeF = (short*)p;                             // h@hT operands (after A8 dead)
    short* BeF = AeF + (size_t)N * 192;
    p += (size_t)N * N;                                 // 16MB
    int* degs = (int*)p;     p += (size_t)6 * N * 4;
    float* isq = (float*)p;  p += (size_t)6 * N * 4;
    int* rowptr = (int*)p;   p += (size_t)3 * N * 4;
    int* cursor = (int*)p;   p += (size_t)3 * N * 4;
    int* eidx = (int*)p;     p += (size_t)3 * E * 4;
    int* degA = (int*)p;     p += (size_t)N * 4;
    float* zbuf = (float*)p; p += (size_t)N * 64 * 4;
    float* h1m = (float*)p;  p += (size_t)N * 64 * 4;
    short* XsT = (short*)p;  p += (size_t)128 * N * 2;
    short* Wv0T = (short*)p; p += (size_t)3 * 128 * 1536 * 2;
    short* Wv1T = (short*)p; p += (size_t)3 * 64 * 384 * 2;
    short* WfT  = (short*)p; p += (size_t)3 * 64 * 192 * 2;

    Ptr3i srcP, dstP;
    for (int v = 0; v < 3; ++v) { srcP.p[v] = src[v]; dstP.p[v] = dst[v]; }

    hipMemsetAsync(mask, 0, (size_t)N * N, stream);
    hipMemsetAsync(degs, 0, (size_t)6 * N * 4, stream);

    edge_k<<<dim3((E + 255) / 256, 3), 256, 0, stream>>>(srcP, dstP, mask, degs);
    deg_norm_k<<<(6 * N + 255) / 256, 256, 0, stream>>>(degs, isq, 6 * N);
    scan_k<<<3, 1024, 0, stream>>>(degs, rowptr, cursor);
    fill_k<<<dim3((E + 255) / 256, 3), 256, 0, stream>>>(srcP, dstP, cursor, eidx);

    // ---- split-bf16 operand builders for per-view GEMMs ----
    Ptr3 xP; for (int v = 0; v < 3; ++v) xP.p[v] = x[v];
    xsplit_k<<<dim3(N * 512 / 256, 3), 256, 0, stream>>>(xP, isq, xe);
    Ptr3 wP;
    for (int v = 0; v < 3; ++v) wP.p[v] = Wv0[v];
    wsplitT_k<<<dim3(512 * 128 / 256, 3), 256, 0, stream>>>(wP, Wv0T, 512, 128);
    for (int v = 0; v < 3; ++v) wP.p[v] = Wv1[v];
    wsplitT_k<<<dim3(128 * 64 / 256, 3), 256, 0, stream>>>(wP, Wv1T, 128, 64);
    for (int v = 0; v < 3; ++v) wP.p[v] = Wf[v];
    wsplitT_k<<<dim3(64 * 64 / 256, 3), 256, 0, stream>>>(wP, WfT, 64, 64);

    // ---- per-view GCN stacks on MFMA (lossless split-bf16) ----
    Ptr3h BtP; Ptr3 biasP;
    for (int v = 0; v < 3; ++v) BtP.p[v] = Wv0T + (size_t)v * 128 * 1536;
    mfma_gemm_b_k<<<dim3(2, N / 64, 3), 256, 0, stream>>>(xe, BtP, hv1, N, 128, 1536);
    for (int v = 0; v < 3; ++v) biasP.p[v] = bv0[v];
    gather_k<128, 1, 1><<<dim3(N / 2, 3), 256, 0, stream>>>(hv1, eidx, rowptr, degs, isq, biasP, Ae2);
    for (int v = 0; v < 3; ++v) BtP.p[v] = Wv1T + (size_t)v * 64 * 384;
    mfma_gemm_b_k<<<dim3(1, N / 64, 3), 256, 0, stream>>>(Ae2, BtP, hv2, N, 64, 384);
    for (int v = 0; v < 3; ++v) biasP.p[v] = bv1[v];
    gather_k<64, 0, 2><<<dim3(N / 4, 3), 256, 0, stream>>>(hv2, eidx, rowptr, degs, isq, biasP, Ae3);
    for (int v = 0; v < 3; ++v) BtP.p[v] = WfT + (size_t)v * 64 * 192;
    mfma_gemm_b_k<<<dim3(1, N / 64, 3), 256, 0, stream>>>(Ae3, BtP, zp, N, 64, 192);
    softsum_k<<<N / 4, 256, 0, stream>>>(zp, zbuf);

    // ---- GFN conversions (xe dead; per-view scratch in oa dead) ----
    mask_to_bf16_k<<<(N * N / 4 + 255) / 256, 256, 0, stream>>>(mask, AdjB, N * N / 4);
    f32_to_bf16T_k<<<dim3(2048 / 64, 4096 / 64), 256, 0, stream>>>(Wg1, Wg1T, 4096, 2048);

    // ---- GEMM1: K-split-2 8-phase, partials -> reduce(+bias,relu) -> H1b bf16 ----
    g8_k<3><<<dim3(2048 / 256, 4096 / 256, 2), 512, 0, stream>>>(
        AdjB, Wg1T, nullptr, partg0, nullptr, 4096, 2048, 2048, 4096, 4096);
    // note: z=0 -> partg0 (oa+32M), z=1 -> partg0 + 4096*2048 floats = oa+64M?  NO:
    // partials must be distinct buffers: kernel offsets Cout by z*M*Nn, so pass base
    // such that z=0 -> partg0 and z=1 -> partg1. They are not contiguous, so we
    // instead launch the two halves as two z=1 grids? -> handled by passing partg0
    // and exploiting that partg0 + M*Nn floats == oa+64MB which is orc+0... (== partg1-32MB)
    // To be safe the two slices are launched separately below if needed.
    reduce_h1_k<<<4096 * 2048 / 4 / 256, 256, 0, stream>>>(partg0, partg0 + (size_t)4096 * 2048,
                                                           bg1, H1b);

    f32_to_bf16T_k<<<dim3(4096 / 64, 2048 / 64), 256, 0, stream>>>(Wg2, Wg2T, 2048, 4096);

    // ---- GEMM2: 8-phase, writes adj_r (f32) + P (u8) ----
    g8_k<2><<<dim3(4096 / 256, 4096 / 256, 1), 512, 0, stream>>>(
        H1b, Wg2T, bg2, out_adjr, P, 4096, 4096, 2048, 2048, 2048);

    // ---- consensus graph ----
    hipMemsetAsync(degA, 0, (size_t)N * 4, stream);
    build_A2_k<<<dim3(N / 64, N / 64), 256, 0, stream>>>(P, A8, degA);

    // ---- fused-graph GCN on MFMA ----
    a2b_k<<<(N * N / 4 + 255) / 256, 256, 0, stream>>>((const unsigned*)A8, A2b, N * N / 4);
    xsT_k<<<dim3(16, 64), 256, 0, stream>>>(zbuf, degA, XsT);
    spmm_mfma_k<<<dim3(8, N / 64), 256, 0, stream>>>(A2b, XsT, part);
    redgemm_k<1><<<64, 256, 0, stream>>>(part, degA, Wm0, bm0, h1m, nullptr, nullptr);
    xsT_k<<<dim3(16, 64), 256, 0, stream>>>(h1m, degA, XsT);
    spmm_mfma_k<<<dim3(8, N / 64), 256, 0, stream>>>(A2b, XsT, part);
    redgemm_k<0><<<64, 256, 0, stream>>>(part, degA, Wm1, bm1, out_h, AeF, BeF);

    // ---- adj_rec = h @ h^T via split-bf16 pipelined MFMA (K=192) ----
    gemm256_k<0><<<dim3(4096 / 128, 4096 / 256), 512, 0, stream>>>(
        AeF, BeF, nullptr, out_rec, nullptr, 4096, 4096, 192);
}

// Round 8
// 528.361 us; speedup vs baseline: 9.1467x; 1.0564x over previous
//
#include <hip/hip_runtime.h>
#include <math.h>

#define NNODES 4096
#define NEDGES 65536

typedef short bf16x8 __attribute__((ext_vector_type(8)));
typedef short short4v __attribute__((ext_vector_type(4)));
typedef float f32x4 __attribute__((ext_vector_type(4)));

struct Ptr3  { const float* p[3]; };
struct Ptr3i { const int*   p[3]; };
struct Ptr3h { const short* p[3]; };

__device__ __forceinline__ short f2bf(float f) {
    unsigned u = __builtin_bit_cast(unsigned, f);
    unsigned r = (u + 0x7FFFu + ((u >> 16) & 1u)) >> 16;
    return (short)r;
}

__device__ __forceinline__ void gload_lds16(const void* g, void* l) {
    __builtin_amdgcn_global_load_lds(
        (const __attribute__((address_space(1))) unsigned*)g,
        (__attribute__((address_space(3))) unsigned*)l, 16, 0, 0);
}

// ================= 8-phase 256xBN bf16 MFMA GEMM, read-once fragments =================
// BM=256, BK=64, 512 thr. BN=256: 8 waves 2Mx4N, wave tile 128x64, LDS 2x64KB.
//                          BN=128: 8 waves 4Mx2N, wave tile 64x64,  LDS 2x48KB.
// Read-once per tile: Q0 loads a-mh0 + b-nh0, Q1 loads b-nh1 (reuse a),
// Q2 loads a-mh1 (reuse held b-nh0), Q3 reuses a-mh1 + b-nh1.
// Staging (per 2-tile iter): p0..p2 stage t1 remainder, p3 stage t2.s0 + vmcnt(2),
// p4..p6 stage t2 remainder, p7 stage t3.s0 + vmcnt(2). Never drains vmcnt to 0
// mid-loop. All stage targets verified >=1 phase after last ds_read of region.
// ACT==1: relu->bf16 ; ACT==2: round(clip+0.1)->f32 + u8 P ; else raw f32
template<int BN, int ACT>
__global__ __launch_bounds__(512, 1)
void g8_k(const short* __restrict__ A, const short* __restrict__ Bt,
          const float* __restrict__ bias, void* __restrict__ Cout,
          unsigned char* __restrict__ Pout, int M, int Nn, int K, int lda, int ldb)
{
    constexpr int SLOT_SH = 16384 + BN * 64;       // shorts per slot (A 32KB + B BN*128B)
    constexpr int WN = (BN == 256) ? 4 : 2;
    constexpr int TM = (BN == 256) ? 128 : 64;     // wave tile rows
    constexpr int MF = TM / 32;                    // m-frags per mh half (4 or 2)
    __shared__ short lds[2 * SLOT_SH];

    const int tid = threadIdx.x;
    const int lane = tid & 63;
    const int wave = tid >> 6;
    const int wm = wave / WN, wn = wave % WN;
    // XCD-bijective swizzle (nwg % 8 == 0 for all grids used)
    const int gx = gridDim.x, nwg = gx * gridDim.y;
    int w = blockIdx.y * gx + blockIdx.x;
    const int q8 = nwg >> 3;
    w = (w & 7) * q8 + (w >> 3);
    const int bm0 = (w / gx) * 256, bn0 = (w % gx) * BN;

    const int NT = K >> 6;

    f32x4 acc[2 * MF][4] = {};
    bf16x8 aF[MF][2];          // current mh half's A frags
    bf16x8 bF[2][2][2];        // [nh][j][kk] both nh halves held across phases

    // stage one sel of tile t. sel: 0=A strips0,2  1=A strips1,3  2=B rows0-127
    // 3=B rows128-255 (BN=256 only). -1 = no-op. Each sel = 2 gloads (16KB).
    auto stageQ = [&](int t, int sel) {
        if (sel < 0 || t >= NT) return;
        const int k0 = t << 6;
        short* L = lds + (t & 1) * SLOT_SH;
        const int rowq = tid >> 3;
        const int slot8 = tid & 7;
        const int woff = wave * 512;
#pragma unroll
        for (int u = 0; u < 2; ++u) {
            int strip, isB;
            if (sel == 0)      { strip = u * 2;     isB = 0; }
            else if (sel == 1) { strip = u * 2 + 1; isB = 0; }
            else if (sel == 2) { strip = u;         isB = 1; }
            else               { strip = u + 2;     isB = 1; }
            const int grow = strip * 64 + rowq;
            const int scol = (slot8 ^ (grow & 7)) << 3;
            if (!isB)
                gload_lds16(A + (size_t)(bm0 + grow) * lda + k0 + scol,
                            L + strip * 4096 + woff);
            else
                gload_lds16(Bt + (size_t)(bn0 + grow) * ldb + k0 + scol,
                            L + 16384 + strip * 4096 + woff);
        }
    };

#define PHASE(Q, TCUR, STAGET, SSEL, VM)                                              \
    {                                                                                 \
        constexpr int mh_ = (Q) >> 1, nh_ = (Q) & 1;                                  \
        const short* As_ = lds + ((TCUR) & 1) * SLOT_SH;                              \
        const short* Bs_ = As_ + 16384;                                               \
        if constexpr ((Q) == 0 || (Q) == 2) {                                         \
            _Pragma("unroll") for (int kk = 0; kk < 2; ++kk) {                        \
                const int h_ = kk * 4 + (lane >> 4);                                  \
                _Pragma("unroll") for (int i = 0; i < MF; ++i) {                      \
                    int r_ = wm * TM + mh_ * (TM / 2) + i * 16 + (lane & 15);         \
                    aF[i][kk] = *(const bf16x8*)(As_ + r_ * 64 + ((h_ ^ (r_ & 7)) << 3)); \
                }                                                                     \
            }                                                                         \
        }                                                                             \
        if constexpr ((Q) == 0 || (Q) == 1) {                                         \
            _Pragma("unroll") for (int kk = 0; kk < 2; ++kk) {                        \
                const int h_ = kk * 4 + (lane >> 4);                                  \
                _Pragma("unroll") for (int j = 0; j < 2; ++j) {                       \
                    int r_ = wn * 64 + nh_ * 32 + j * 16 + (lane & 15);               \
                    bF[nh_][j][kk] = *(const bf16x8*)(Bs_ + r_ * 64 + ((h_ ^ (r_ & 7)) << 3)); \
                }                                                                     \
            }                                                                         \
        }                                                                             \
        stageQ(STAGET, SSEL);                                                         \
        __builtin_amdgcn_s_barrier();                                                 \
        __builtin_amdgcn_s_setprio(1);                                                \
        _Pragma("unroll") for (int kk = 0; kk < 2; ++kk)                              \
            _Pragma("unroll") for (int i = 0; i < MF; ++i)                            \
                _Pragma("unroll") for (int j = 0; j < 2; ++j)                         \
                    acc[mh_ * MF + i][nh_ * 2 + j] =                                  \
                        __builtin_amdgcn_mfma_f32_16x16x32_bf16(                      \
                            aF[i][kk], bF[nh_][j][kk], acc[mh_ * MF + i][nh_ * 2 + j], 0, 0, 0); \
        __builtin_amdgcn_s_setprio(0);                                                \
        if ((VM) == 2)      { asm volatile("s_waitcnt vmcnt(2)" ::: "memory"); }      \
        else if ((VM) == 0) { asm volatile("s_waitcnt vmcnt(0)" ::: "memory"); }      \
        __builtin_amdgcn_sched_barrier(0);                                            \
        __builtin_amdgcn_s_barrier();                                                 \
    }

    // prologue: tile 0 fully + tile 1 sel0; drain to 2 outstanding (t1.s0 may pend)
    stageQ(0, 0); stageQ(0, 1); stageQ(0, 2);
    if constexpr (BN == 256) stageQ(0, 3);
    stageQ(1, 0);
    asm volatile("s_waitcnt vmcnt(2)" ::: "memory");
    __builtin_amdgcn_sched_barrier(0);
    __builtin_amdgcn_s_barrier();

    constexpr int SB = (BN == 256) ? 3 : -1;   // third sel of a tile (B hi half) or none
    for (int it = 0; it < NT / 2; ++it) {
        const int t0 = 2 * it, t1 = t0 + 1;
        PHASE(0, t0, t1, 1, -1);
        PHASE(1, t0, t1, 2, -1);
        PHASE(2, t0, t1, SB, -1);
        { int vm_ = (t0 + 2 < NT) ? 2 : 0; PHASE(3, t0, t0 + 2, 0, vm_); }
        PHASE(0, t1, t0 + 2, 1, -1);
        PHASE(1, t1, t0 + 2, 2, -1);
        PHASE(2, t1, t0 + 2, SB, -1);
        { int vm_ = (t0 + 2 < NT) ? 2 : -1; PHASE(3, t1, t0 + 3, 0, vm_); }
    }
#undef PHASE

    const int cr = (lane >> 4) * 4;   // C/D: col=lane&15, row=(lane>>4)*4+reg
    const int cc = lane & 15;
#pragma unroll
    for (int im = 0; im < 2 * MF; ++im) {
#pragma unroll
        for (int jn = 0; jn < 4; ++jn) {
            int col = bn0 + wn * 64 + (jn >> 1) * 32 + (jn & 1) * 16 + cc;
            float bv = bias ? bias[col] : 0.f;
#pragma unroll
            for (int q2 = 0; q2 < 4; ++q2) {
                int row = bm0 + wm * TM + (im / MF) * (TM / 2) + (im % MF) * 16 + cr + q2;
                float v = acc[im][jn][q2] + bv;
                if constexpr (ACT == 1) {
                    v = fmaxf(v, 0.f);
                    ((short*)Cout)[(size_t)row * Nn + col] = f2bf(v);
                } else if constexpr (ACT == 2) {
                    v = rintf(fminf(fmaxf(v, 0.f), 1.f) + 0.1f);
                    ((float*)Cout)[(size_t)row * Nn + col] = v;
                    Pout[(size_t)row * Nn + col] = (unsigned char)(v > 0.5f);
                } else {
                    ((float*)Cout)[(size_t)row * Nn + col] = v;
                }
            }
        }
    }
}

// ============ 2-phase pipelined GEMM (h@h^T, K=192) ============
template<int ACT>
__global__ __launch_bounds__(512, 1)
void gemm256_k(const short* __restrict__ A, const short* __restrict__ Bt,
               const float* __restrict__ bias, void* __restrict__ Cout,
               unsigned char* __restrict__ Pout, int M, int Nn, int K)
{
    __shared__ short lds_s[3 * 24576];
    const int tid = threadIdx.x;
    const int lane = tid & 63;
    const int gx = gridDim.x, nwg = gx * gridDim.y;
    int w = blockIdx.y * gx + blockIdx.x;
    const int q = nwg >> 3;
    w = (w & 7) * q + (w >> 3);
    const int bm0 = (w / gx) * 256, bn0 = (w % gx) * 128;
    const int wmr = ((tid >> 6) >> 1) * 64;
    const int wnr = ((tid >> 6) & 1) * 64;
    const int NT = K >> 6;

    auto stage = [&](int kt, int slot) {
        const int k0 = kt << 6;
        char* base = (char*)(lds_s + slot * 24576);
        char* wbase = base + (tid >> 6) * 1024;
#pragma unroll
        for (int r = 0; r < 4; ++r) {
            int o = r * 8192 + tid * 16;
            int row = o >> 7;
            int sl = (o >> 4) & 7;
            gload_lds16(A + ((size_t)(bm0 + row) * K + k0 + ((sl ^ (row & 7)) << 3)),
                        wbase + r * 8192);
        }
#pragma unroll
        for (int r = 0; r < 2; ++r) {
            int o = r * 8192 + tid * 16;
            int row = o >> 7;
            int sl = (o >> 4) & 7;
            gload_lds16(Bt + ((size_t)(bn0 + row) * K + k0 + ((sl ^ (row & 7)) << 3)),
                        base + 32768 + r * 8192 + (tid >> 6) * 1024);
        }
    };

    f32x4 acc[4][4] = {};
    stage(0, 0);
    if (NT > 1) stage(1, 1);

    for (int kt = 0; kt < NT; ++kt) {
        if (kt < NT - 1) { asm volatile("s_waitcnt vmcnt(6)" ::: "memory"); }
        else             { asm volatile("s_waitcnt vmcnt(0)" ::: "memory"); }
        __builtin_amdgcn_s_barrier();
        if (kt + 2 < NT) stage(kt + 2, (kt + 2) % 3);

        const short* As = lds_s + (kt % 3) * 24576;
        const short* Bs = As + 16384;
        __builtin_amdgcn_s_setprio(1);
#pragma unroll
        for (int kk = 0; kk < 2; ++kk) {
            bf16x8 a[4], b[4];
            const int khalf = kk * 4 + (lane >> 4);
#pragma unroll
            for (int i = 0; i < 4; ++i) {
                int r = wmr + i * 16 + (lane & 15);
                a[i] = *(const bf16x8*)(As + r * 64 + ((khalf ^ (r & 7)) << 3));
            }
#pragma unroll
            for (int j = 0; j < 4; ++j) {
                int r = wnr + j * 16 + (lane & 15);
                b[j] = *(const bf16x8*)(Bs + r * 64 + ((khalf ^ (r & 7)) << 3));
            }
#pragma unroll
            for (int i = 0; i < 4; ++i)
#pragma unroll
                for (int j = 0; j < 4; ++j)
                    acc[i][j] = __builtin_amdgcn_mfma_f32_16x16x32_bf16(a[i], b[j], acc[i][j], 0, 0, 0);
        }
        __builtin_amdgcn_s_setprio(0);
        asm volatile("s_waitcnt lgkmcnt(0)" ::: "memory");
    }

    const int cr = (lane >> 4) * 4;
    const int cc = lane & 15;
#pragma unroll
    for (int i = 0; i < 4; ++i)
#pragma unroll
        for (int j = 0; j < 4; ++j) {
            int col = bn0 + wnr + j * 16 + cc;
#pragma unroll
            for (int q2 = 0; q2 < 4; ++q2) {
                int row = bm0 + wmr + i * 16 + cr + q2;
                ((float*)Cout)[(size_t)row * Nn + col] = acc[i][j][q2];
            }
        }
}

// ---------------- batched bf16 MFMA GEMM, 64x64 tile (per-view stacks) ----------------
__global__ __launch_bounds__(256)
void mfma_gemm_b_k(const short* __restrict__ Aall, Ptr3h Btv, float* __restrict__ Call,
                   int M, int Nn, int K)
{
    __shared__ short As[64 * 64];
    __shared__ short Bs[64 * 64];
    const int z = blockIdx.z;
    const short* A = Aall + (size_t)z * M * K;
    const short* Bt = Btv.p[z];
    float* C = Call + (size_t)z * M * Nn;
    const int tid = threadIdx.x;
    const int lane = tid & 63, wave = tid >> 6;
    const int bm0 = blockIdx.y * 64, bn0 = blockIdx.x * 64;
    const int wr = (wave >> 1) * 32, wc = (wave & 1) * 32;

    f32x4 acc[2][2] = {};

    for (int k0 = 0; k0 < K; k0 += 64) {
        for (int c = wave; c < 8; c += 4) {
            int o = c * 1024 + lane * 16;
            int row = o >> 7;
            int sl = (o >> 4) & 7;
            int ss = sl ^ (row & 7);
            gload_lds16(A + ((size_t)(bm0 + row) * K + k0 + ss * 8), As + c * 512);
            gload_lds16(Bt + ((size_t)(bn0 + row) * K + k0 + ss * 8), Bs + c * 512);
        }
        __syncthreads();
#pragma unroll
        for (int kk = 0; kk < 2; ++kk) {
            bf16x8 a[2], b[2];
            const int khalf = kk * 4 + (lane >> 4);
#pragma unroll
            for (int i = 0; i < 2; ++i) {
                int r = wr + i * 16 + (lane & 15);
                a[i] = *(const bf16x8*)(As + r * 64 + ((khalf ^ (r & 7)) << 3));
            }
#pragma unroll
            for (int j = 0; j < 2; ++j) {
                int r = wc + j * 16 + (lane & 15);
                b[j] = *(const bf16x8*)(Bs + r * 64 + ((khalf ^ (r & 7)) << 3));
            }
#pragma unroll
            for (int i = 0; i < 2; ++i)
#pragma unroll
                for (int j = 0; j < 2; ++j)
                    acc[i][j] = __builtin_amdgcn_mfma_f32_16x16x32_bf16(a[i], b[j], acc[i][j], 0, 0, 0);
        }
        __syncthreads();
    }

    const int cr = (lane >> 4) * 4;
    const int cc = lane & 15;
#pragma unroll
    for (int i = 0; i < 2; ++i)
#pragma unroll
        for (int j = 0; j < 2; ++j)
#pragma unroll
            for (int q = 0; q < 4; ++q) {
                int row = bm0 + wr + i * 16 + cr + q;
                int col = bn0 + wc + j * 16 + cc;
                C[(size_t)row * Nn + col] = acc[i][j][q];
            }
}

// ---------------- MFMA SpMM: part[kc] = A2b[:,kc-chunk] @ (hi+lo)^T ----------------
__global__ __launch_bounds__(256)
void spmm_mfma_k(const short* __restrict__ A2b, const short* __restrict__ XsT,
                 float* __restrict__ part)
{
    __shared__ short As[64 * 64];
    __shared__ short Bs[128 * 64];
    const int tid = threadIdx.x;
    const int lane = tid & 63, wave = tid >> 6;
    const int kc = blockIdx.x, m0 = blockIdx.y * 64;
    const int wr = (wave >> 1) * 32, wc = (wave & 1) * 32;
    const int woff = wave * 512;

    f32x4 acc[2][2] = {};

    for (int k0 = kc * 512; k0 < kc * 512 + 512; k0 += 64) {
#pragma unroll
        for (int r = 0; r < 2; ++r) {
            int o = r * 4096 + tid * 16;
            int row = o >> 7;
            int sl = (o >> 4) & 7;
            gload_lds16(A2b + ((size_t)(m0 + row) * 4096 + k0 + ((sl ^ (row & 7)) << 3)),
                        As + r * 2048 + woff);
        }
#pragma unroll
        for (int r = 0; r < 4; ++r) {
            int o = r * 4096 + tid * 16;
            int row = o >> 7;
            int sl = (o >> 4) & 7;
            gload_lds16(XsT + ((size_t)row * 4096 + k0 + ((sl ^ (row & 7)) << 3)),
                        Bs + r * 2048 + woff);
        }
        __syncthreads();
#pragma unroll
        for (int kk = 0; kk < 2; ++kk) {
            const int h = kk * 4 + (lane >> 4);
            bf16x8 a[2], bh[2], bl[2];
#pragma unroll
            for (int i = 0; i < 2; ++i) {
                int r = wr + i * 16 + (lane & 15);
                a[i] = *(const bf16x8*)(As + r * 64 + ((h ^ (r & 7)) << 3));
            }
#pragma unroll
            for (int j = 0; j < 2; ++j) {
                int r = wc + j * 16 + (lane & 15);
                bh[j] = *(const bf16x8*)(Bs + r * 64 + ((h ^ (r & 7)) << 3));
                int r2 = r + 64;
                bl[j] = *(const bf16x8*)(Bs + r2 * 64 + ((h ^ (r2 & 7)) << 3));
            }
#pragma unroll
            for (int i = 0; i < 2; ++i)
#pragma unroll
                for (int j = 0; j < 2; ++j) {
                    acc[i][j] = __builtin_amdgcn_mfma_f32_16x16x32_bf16(a[i], bh[j], acc[i][j], 0, 0, 0);
                    acc[i][j] = __builtin_amdgcn_mfma_f32_16x16x32_bf16(a[i], bl[j], acc[i][j], 0, 0, 0);
                }
        }
        __syncthreads();
    }

    const int cr = (lane >> 4) * 4;
    const int cc = lane & 15;
#pragma unroll
    for (int i = 0; i < 2; ++i)
#pragma unroll
        for (int j = 0; j < 2; ++j)
#pragma unroll
            for (int q = 0; q < 4; ++q)
                part[((size_t)kc * NNODES + m0 + wr + i * 16 + cr + q) * 64 + wc + j * 16 + cc]
                    = acc[i][j][q];
}

// X [4096][64] f32 -> XsT [128][4096] bf16 (hi rows 0-63, lo 64-127), dn folded
__global__ void xsT_k(const float* __restrict__ X, const int* __restrict__ degA,
                      short* __restrict__ XsT)
{
    const int n = blockIdx.y;
    const int k = blockIdx.x * 256 + threadIdx.x;
    float v = X[(size_t)k * 64 + n] * (1.0f / sqrtf((float)degA[k]));
    short hi = f2bf(v);
    float hif = __builtin_bit_cast(float, ((unsigned)(unsigned short)hi) << 16);
    short lo = f2bf(v - hif);
    XsT[(size_t)n * 4096 + k] = hi;
    XsT[(size_t)(64 + n) * 4096 + k] = lo;
}

// A8 u8 -> bf16 (exact 0/1)
__global__ void a2b_k(const unsigned* __restrict__ A8w, short* __restrict__ A2b, int words)
{
    int t = blockIdx.x * 256 + threadIdx.x;
    if (t < words) {
        unsigned w = A8w[t];
        short4v o;
#pragma unroll
        for (int j = 0; j < 4; ++j) o[j] = ((w >> (8 * j)) & 1u) ? (short)0x3F80 : (short)0;
        *(short4v*)(A2b + (size_t)t * 4) = o;
    }
}

// f32 [R][C] -> bf16 transposed [C][R]
__global__ void f32_to_bf16T_k(const float* __restrict__ src, short* __restrict__ dstT,
                               int R, int C)
{
    __shared__ float t[64][65];
    const int br = blockIdx.y * 64, bc = blockIdx.x * 64;
    for (int idx = threadIdx.x; idx < 64 * 64; idx += 256) {
        int r = idx >> 6, c = idx & 63;
        t[r][c] = src[(size_t)(br + r) * C + bc + c];
    }
    __syncthreads();
    for (int idx = threadIdx.x; idx < 64 * 64; idx += 256) {
        int c = idx >> 6, r = idx & 63;
        dstT[(size_t)(bc + c) * R + br + r] = f2bf(t[r][c]);
    }
}

__global__ void mask_to_bf16_k(const unsigned* __restrict__ mask, short* __restrict__ adj,
                               int words)
{
    int t = blockIdx.x * 256 + threadIdx.x;
    if (t < words) {
        unsigned w = mask[t];
        short4v o;
        o.x = f2bf((float)__popc(w & 0x7u));
        o.y = f2bf((float)__popc(w & 0x700u));
        o.z = f2bf((float)__popc(w & 0x70000u));
        o.w = f2bf((float)__popc(w & 0x7000000u));
        *(short4v*)(adj + (size_t)t * 4) = o;
    }
}

// x [N,512] f32 * doi -> split-bf16 xe [N][1536] = [hi | hi | lo]
__global__ void xsplit_k(Ptr3 xv, const float* __restrict__ isq, short* __restrict__ xe)
{
    const int z = blockIdx.y;
    int t = blockIdx.x * 256 + threadIdx.x;
    int n = t >> 9, k = t & 511;
    float a = xv.p[z][(size_t)n * 512 + k] * isq[2 * z * NNODES + n];
    short hi = f2bf(a);
    float hif = __builtin_bit_cast(float, ((unsigned)(unsigned short)hi) << 16);
    short lo = f2bf(a - hif);
    short* row = xe + (size_t)z * NNODES * 1536 + (size_t)n * 1536;
    row[k] = hi; row[512 + k] = hi; row[1024 + k] = lo;
}

// W [K][Nn] f32 -> split-bf16 transposed Bt [Nn][3K] = [hi | lo | hi]
__global__ void wsplitT_k(Ptr3 Wv, short* __restrict__ out, int K, int Nn)
{
    const int z = blockIdx.y;
    int t = blockIdx.x * 256 + threadIdx.x;
    if (t >= K * Nn) return;
    int k = t / Nn, n = t % Nn;
    float w = Wv.p[z][(size_t)k * Nn + n];
    short hi = f2bf(w);
    float hif = __builtin_bit_cast(float, ((unsigned)(unsigned short)hi) << 16);
    short lo = f2bf(w - hif);
    short* row = out + (size_t)z * Nn * 3 * K + (size_t)n * 3 * K;
    row[k] = hi; row[K + k] = lo; row[2 * K + k] = hi;
}

// fused: s = (sum_p part[p][row,:]) * deg[row]^-1/2 ; out = act(s @ Wm + b)
// optional split-bf16 emit for h@h^T operands (Ae=[hi|hi|lo], Be=[hi|lo|hi])
template<int RELU>
__global__ __launch_bounds__(256)
void redgemm_k(const float* __restrict__ part, const int* __restrict__ degA,
               const float* __restrict__ Wm, const float* __restrict__ bias,
               float* __restrict__ out, short* __restrict__ Ae, short* __restrict__ Be)
{
    __shared__ float Ws[64 * 64];
    const int tid = threadIdx.x;
    for (int i = tid; i < 4096; i += 256) Ws[i] = Wm[i];
    __syncthreads();
    const int lane = tid & 63, wave = tid >> 6;
    const float bv = bias[lane];
    for (int rr = 0; rr < 16; ++rr) {
        int row = blockIdx.x * 64 + wave * 16 + rr;
        float s = 0.f;
#pragma unroll
        for (int p = 0; p < 8; ++p) s += part[((size_t)p * NNODES + row) * 64 + lane];
        s *= 1.0f / sqrtf((float)degA[row]);
        float acc = bv;
#pragma unroll
        for (int k = 0; k < 64; ++k)
            acc = fmaf(__shfl(s, k), Ws[k * 64 + lane], acc);
        if (RELU) acc = fmaxf(acc, 0.f);
        out[(size_t)row * 64 + lane] = acc;
        if (Ae) {
            short hi = f2bf(acc);
            float hif = __builtin_bit_cast(float, ((unsigned)(unsigned short)hi) << 16);
            short lo = f2bf(acc - hif);
            size_t ro = (size_t)row * 192;
            Ae[ro + lane] = hi; Ae[ro + 64 + lane] = hi; Ae[ro + 128 + lane] = lo;
            Be[ro + lane] = hi; Be[ro + 64 + lane] = lo; Be[ro + 128 + lane] = hi;
        }
    }
}

// ---------------- graph construction ----------------
__global__ void edge_k(Ptr3i src, Ptr3i dst, unsigned* __restrict__ mask, int* __restrict__ degs)
{
    int e = blockIdx.x * 256 + threadIdx.x;
    int z = blockIdx.y;
    if (e < NEDGES) {
        int s = src.p[z][e], d = dst.p[z][e];
        unsigned c = (unsigned)s * (unsigned)NNODES + (unsigned)d;
        atomicOr(&mask[c >> 2], 1u << ((c & 3u) * 8u + (unsigned)z));
        atomicAdd(&degs[2 * z * NNODES + s], 1);
        atomicAdd(&degs[(2 * z + 1) * NNODES + d], 1);
    }
}

__global__ void deg_norm_k(const int* __restrict__ degs, float* __restrict__ isq, int n)
{
    int t = blockIdx.x * 256 + threadIdx.x;
    if (t < n) isq[t] = 1.0f / sqrtf(fmaxf((float)degs[t], 1.0f));
}

__global__ __launch_bounds__(1024)
void scan_k(const int* __restrict__ degs, int* __restrict__ rowptr, int* __restrict__ cursor)
{
    const int z = blockIdx.x;
    const int* din = degs + (2 * z + 1) * NNODES;
    __shared__ int sm[1024];
    const int t = threadIdx.x;
    int v0 = din[t * 4], v1 = din[t * 4 + 1], v2 = din[t * 4 + 2], v3 = din[t * 4 + 3];
    int c1 = v0 + v1, c2 = c1 + v2, s = c2 + v3;
    sm[t] = s;
    __syncthreads();
    for (int off = 1; off < 1024; off <<= 1) {
        int add = (t >= off) ? sm[t - off] : 0;
        __syncthreads();
        sm[t] += add;
        __syncthreads();
    }
    int base = sm[t] - s;
    int* rp = rowptr + z * NNODES;
    int* cu = cursor + z * NNODES;
    rp[t * 4] = base;          cu[t * 4] = base;
    rp[t * 4 + 1] = base + v0; cu[t * 4 + 1] = base + v0;
    rp[t * 4 + 2] = base + c1; cu[t * 4 + 2] = base + c1;
    rp[t * 4 + 3] = base + c2; cu[t * 4 + 3] = base + c2;
}

__global__ void fill_k(Ptr3i src, Ptr3i dst, int* __restrict__ cursor, int* __restrict__ eidx)
{
    int e = blockIdx.x * 256 + threadIdx.x;
    int z = blockIdx.y;
    if (e < NEDGES) {
        int d = dst.p[z][e];
        int pos = atomicAdd(&cursor[z * NNODES + d], 1);
        eidx[(size_t)z * NEDGES + pos] = src.p[z][e];
    }
}

// fused CSR-gather + norm + bias + act -> split-bf16 A rows [node][3F]
template<int F, int ACT, int MODE>
__global__ void gather_k(const float* __restrict__ Hpre, const int* __restrict__ eidx,
                         const int* __restrict__ rowptr, const int* __restrict__ degs,
                         const float* __restrict__ isq, Ptr3 bias, short* __restrict__ Sout)
{
    const int z = blockIdx.y;
    const int tid = threadIdx.x;
    const int node = blockIdx.x * (256 / F) + tid / F;
    const int f = tid % F;
    const float* H = Hpre + (size_t)z * NNODES * F;
    const int base = rowptr[z * NNODES + node];
    const int cnt = degs[(2 * z + 1) * NNODES + node];
    const int* ei = eidx + (size_t)z * NEDGES + base;
    float s = 0.f;
    for (int i = 0; i < cnt; ++i) s += H[(size_t)ei[i] * F + f];
    float v = s * isq[(2 * z + 1) * NNODES + node] + bias.p[z][f];
    if (ACT) v = fmaxf(v, 0.f);
    if (MODE == 1) v *= isq[2 * z * NNODES + node];
    short hi = f2bf(v);
    float hif = __builtin_bit_cast(float, ((unsigned)(unsigned short)hi) << 16);
    short lo = f2bf(v - hif);
    short* row = Sout + (size_t)z * NNODES * 3 * F + (size_t)node * 3 * F;
    row[f] = hi; row[F + f] = hi; row[2 * F + f] = lo;
}

// z = softmax_row(zp0+zp1+zp2)
__global__ void softsum_k(const float* __restrict__ zp, float* __restrict__ z)
{
    int row = blockIdx.x * 4 + (threadIdx.x >> 6);
    int f = threadIdx.x & 63;
    size_t i = (size_t)row * 64 + f;
    float v = zp[i] + zp[i + (size_t)NNODES * 64] + zp[i + (size_t)2 * NNODES * 64];
    float m = v;
#pragma unroll
    for (int off = 32; off >= 1; off >>= 1) m = fmaxf(m, __shfl_xor(m, off));
    float e = expf(v - m);
    float s = e;
#pragma unroll
    for (int off = 32; off >= 1; off >>= 1) s += __shfl_xor(s, off);
    z[i] = e / s;
}

// A8[i,j] = P[i,j] | P[j,i] | (i==j), deg row-sums.
__global__ __launch_bounds__(256)
void build_A2_k(const unsigned char* __restrict__ P, unsigned char* __restrict__ A8,
                int* __restrict__ degA)
{
    __shared__ unsigned Ts[64][20];
    const int bi = blockIdx.y * 64, bj = blockIdx.x * 64;
    const int tid = threadIdx.x;
    const int r = tid >> 2, seg = tid & 3;
    uint4 tv = *(const uint4*)(P + (size_t)(bj + r) * NNODES + bi + seg * 16);
    Ts[r][seg * 4 + 0] = tv.x; Ts[r][seg * 4 + 1] = tv.y;
    Ts[r][seg * 4 + 2] = tv.z; Ts[r][seg * 4 + 3] = tv.w;
    __syncthreads();
    uint4 dv = *(const uint4*)(P + (size_t)(bi + r) * NNODES + bj + seg * 16);
    unsigned dw[4] = {dv.x, dv.y, dv.z, dv.w};
    const unsigned char* Tb = (const unsigned char*)Ts;
    unsigned ow[4];
    int psum = 0;
#pragma unroll
    for (int w = 0; w < 4; ++w) {
        unsigned o = 0;
#pragma unroll
        for (int b = 0; b < 4; ++b) {
            int j = seg * 16 + w * 4 + b;
            unsigned a = (dw[w] >> (8 * b)) & 1u;
            unsigned tr = Tb[j * 80 + r] & 1u;
            unsigned on = a | tr | (unsigned)((bi + r) == (bj + j));
            o |= on << (8 * b);
            psum += (int)on;
        }
        ow[w] = o;
    }
    uint4 o4; o4.x = ow[0]; o4.y = ow[1]; o4.z = ow[2]; o4.w = ow[3];
    *(uint4*)(A8 + (size_t)(bi + r) * NNODES + bj + seg * 16) = o4;
    psum += __shfl_xor(psum, 1);
    psum += __shfl_xor(psum, 2);
    if (seg == 0) atomicAdd(&degA[bi + r], psum);
}

extern "C" void kernel_launch(void* const* d_in, const int* in_sizes, int n_in,
                              void* d_out, int out_size, void* d_ws, size_t ws_size,
                              hipStream_t stream)
{
    const int N = NNODES, E = NEDGES;
    const size_t MB = 1024 * 1024;

    const float* x[3]; const int* src[3]; const int* dst[3];
    const float *Wv0[3], *bv0[3], *Wv1[3], *bv1[3], *Wf[3];
    for (int v = 0; v < 3; ++v) {
        const int b = v * 8;
        x[v]   = (const float*)d_in[b + 0];
        src[v] = (const int*)  d_in[b + 1];
        dst[v] = (const int*)  d_in[b + 2];
        Wv0[v] = (const float*)d_in[b + 3];
        bv0[v] = (const float*)d_in[b + 4];
        Wv1[v] = (const float*)d_in[b + 5];
        bv1[v] = (const float*)d_in[b + 6];
        Wf[v]  = (const float*)d_in[b + 7];
    }
    const float* Wg1 = (const float*)d_in[24];
    const float* bg1 = (const float*)d_in[25];
    const float* Wg2 = (const float*)d_in[26];
    const float* bg2 = (const float*)d_in[27];
    const float* Wm0 = (const float*)d_in[28];
    const float* bm0 = (const float*)d_in[29];
    const float* Wm1 = (const float*)d_in[30];
    const float* bm1 = (const float*)d_in[31];

    float* out_adjr = (float*)d_out;                    // [N,N] f32 (final)
    float* out_rec  = out_adjr + (size_t)N * N;         // [N,N] f32 (final; scratch until then)
    float* out_h    = out_rec + (size_t)N * N;          // [N,64]

    // --- scratch carved from dead regions of outputs ---
    char* oa = (char*)out_adjr;                         // 64 MB, final write = GEMM2
    short* AdjB = (short*)oa;                           // bf16 [N][N]  [0,32M)
    float* hv1  = (float*)(oa + 32 * MB);               // f32 [3][N][128]
    short* Ae2  = (short*)(oa + 38 * MB);
    short* Ae3  = (short*)(oa + 47 * MB);
    float* hv2  = (float*)(oa + 52 * MB);
    float* zp   = (float*)(oa + 56 * MB);

    char* orc = (char*)out_rec;                         // 64 MB, final write = h@hT
    short* xe   = (short*)orc;                          // bf16 [3][N][1536] (dead after L1)
    short* H1b  = (short*)orc;                          // bf16 [N][2048]  [0,16M)
    unsigned char* P = (unsigned char*)(orc + 16 * MB); // u8 [N][N]       [16,32M)
    short* Wg1T = (short*)(orc + 16 * MB);              // dead when P written (after GEMM1)
    short* Wg2T = (short*)(orc + 32 * MB);              // [32,48M)
    short* A2b  = (short*)orc;                          // bf16 [N][N] [0,32M) after build_A2
    float* part = (float*)(orc + 48 * MB);              // 8 MB K-split partials (spmm)

    // ---- workspace carve ----
    char* p = (char*)d_ws;
    unsigned* mask = (unsigned*)p;
    unsigned char* A8 = (unsigned char*)p;              // reuses mask region
    short* AeF = (short*)p;                             // h@hT operands (after A8 dead)
    short* BeF = AeF + (size_t)N * 192;
    p += (size_t)N * N;                                 // 16MB
    int* degs = (int*)p;     p += (size_t)6 * N * 4;
    float* isq = (float*)p;  p += (size_t)6 * N * 4;
    int* rowptr = (int*)p;   p += (size_t)3 * N * 4;
    int* cursor = (int*)p;   p += (size_t)3 * N * 4;
    int* eidx = (int*)p;     p += (size_t)3 * E * 4;
    int* degA = (int*)p;     p += (size_t)N * 4;
    float* zbuf = (float*)p; p += (size_t)N * 64 * 4;
    float* h1m = (float*)p;  p += (size_t)N * 64 * 4;
    short* XsT = (short*)p;  p += (size_t)128 * N * 2;
    short* Wv0T = (short*)p; p += (size_t)3 * 128 * 1536 * 2;
    short* Wv1T = (short*)p; p += (size_t)3 * 64 * 384 * 2;
    short* WfT  = (short*)p; p += (size_t)3 * 64 * 192 * 2;

    Ptr3i srcP, dstP;
    for (int v = 0; v < 3; ++v) { srcP.p[v] = src[v]; dstP.p[v] = dst[v]; }

    hipMemsetAsync(mask, 0, (size_t)N * N, stream);
    hipMemsetAsync(degs, 0, (size_t)6 * N * 4, stream);

    edge_k<<<dim3((E + 255) / 256, 3), 256, 0, stream>>>(srcP, dstP, mask, degs);
    deg_norm_k<<<(6 * N + 255) / 256, 256, 0, stream>>>(degs, isq, 6 * N);
    scan_k<<<3, 1024, 0, stream>>>(degs, rowptr, cursor);
    fill_k<<<dim3((E + 255) / 256, 3), 256, 0, stream>>>(srcP, dstP, cursor, eidx);

    // ---- split-bf16 operand builders for per-view GEMMs ----
    Ptr3 xP; for (int v = 0; v < 3; ++v) xP.p[v] = x[v];
    xsplit_k<<<dim3(N * 512 / 256, 3), 256, 0, stream>>>(xP, isq, xe);
    Ptr3 wP;
    for (int v = 0; v < 3; ++v) wP.p[v] = Wv0[v];
    wsplitT_k<<<dim3(512 * 128 / 256, 3), 256, 0, stream>>>(wP, Wv0T, 512, 128);
    for (int v = 0; v < 3; ++v) wP.p[v] = Wv1[v];
    wsplitT_k<<<dim3(128 * 64 / 256, 3), 256, 0, stream>>>(wP, Wv1T, 128, 64);
    for (int v = 0; v < 3; ++v) wP.p[v] = Wf[v];
    wsplitT_k<<<dim3(64 * 64 / 256, 3), 256, 0, stream>>>(wP, WfT, 64, 64);

    // ---- per-view GCN stacks on MFMA (lossless split-bf16) ----
    Ptr3h BtP; Ptr3 biasP;
    for (int v = 0; v < 3; ++v) BtP.p[v] = Wv0T + (size_t)v * 128 * 1536;
    mfma_gemm_b_k<<<dim3(2, N / 64, 3), 256, 0, stream>>>(xe, BtP, hv1, N, 128, 1536);
    for (int v = 0; v < 3; ++v) biasP.p[v] = bv0[v];
    gather_k<128, 1, 1><<<dim3(N / 2, 3), 256, 0, stream>>>(hv1, eidx, rowptr, degs, isq, biasP, Ae2);
    for (int v = 0; v < 3; ++v) BtP.p[v] = Wv1T + (size_t)v * 64 * 384;
    mfma_gemm_b_k<<<dim3(1, N / 64, 3), 256, 0, stream>>>(Ae2, BtP, hv2, N, 64, 384);
    for (int v = 0; v < 3; ++v) biasP.p[v] = bv1[v];
    gather_k<64, 0, 2><<<dim3(N / 4, 3), 256, 0, stream>>>(hv2, eidx, rowptr, degs, isq, biasP, Ae3);
    for (int v = 0; v < 3; ++v) BtP.p[v] = WfT + (size_t)v * 64 * 192;
    mfma_gemm_b_k<<<dim3(1, N / 64, 3), 256, 0, stream>>>(Ae3, BtP, zp, N, 64, 192);
    softsum_k<<<N / 4, 256, 0, stream>>>(zp, zbuf);

    // ---- GFN conversions (xe dead; per-view scratch in oa dead) ----
    mask_to_bf16_k<<<(N * N / 4 + 255) / 256, 256, 0, stream>>>(mask, AdjB, N * N / 4);
    f32_to_bf16T_k<<<dim3(2048 / 64, 4096 / 64), 256, 0, stream>>>(Wg1, Wg1T, 4096, 2048);

    // ---- GEMM1: 8-phase BN=128, direct relu->bf16, no K-split ----
    g8_k<128, 1><<<dim3(2048 / 128, 4096 / 256), 512, 0, stream>>>(
        AdjB, Wg1T, bg1, H1b, nullptr, 4096, 2048, 4096, 4096, 4096);

    f32_to_bf16T_k<<<dim3(4096 / 64, 2048 / 64), 256, 0, stream>>>(Wg2, Wg2T, 2048, 4096);

    // ---- GEMM2: 8-phase BN=256, writes adj_r (f32) + P (u8) ----
    g8_k<256, 2><<<dim3(4096 / 256, 4096 / 256), 512, 0, stream>>>(
        H1b, Wg2T, bg2, out_adjr, P, 4096, 4096, 2048, 2048, 2048);

    // ---- consensus graph ----
    hipMemsetAsync(degA, 0, (size_t)N * 4, stream);
    build_A2_k<<<dim3(N / 64, N / 64), 256, 0, stream>>>(P, A8, degA);

    // ---- fused-graph GCN on MFMA ----
    a2b_k<<<(N * N / 4 + 255) / 256, 256, 0, stream>>>((const unsigned*)A8, A2b, N * N / 4);
    xsT_k<<<dim3(16, 64), 256, 0, stream>>>(zbuf, degA, XsT);
    spmm_mfma_k<<<dim3(8, N / 64), 256, 0, stream>>>(A2b, XsT, part);
    redgemm_k<1><<<64, 256, 0, stream>>>(part, degA, Wm0, bm0, h1m, nullptr, nullptr);
    xsT_k<<<dim3(16, 64), 256, 0, stream>>>(h1m, degA, XsT);
    spmm_mfma_k<<<dim3(8, N / 64), 256, 0, stream>>>(A2b, XsT, part);
    redgemm_k<0><<<64, 256, 0, stream>>>(part, degA, Wm1, bm1, out_h, AeF, BeF);

    // ---- adj_rec = h @ h^T via split-bf16 pipelined MFMA (K=192) ----
    gemm256_k<0><<<dim3(4096 / 128, 4096 / 256), 512, 0, stream>>>(
        AeF, BeF, nullptr, out_rec, nullptr, 4096, 4096, 192);
}

// Round 9
// 455.094 us; speedup vs baseline: 10.6192x; 1.1610x over previous
//
#include <hip/hip_runtime.h>
#include <math.h>

#define NNODES 4096
#define NEDGES 65536

typedef short bf16x8 __attribute__((ext_vector_type(8)));
typedef short short4v __attribute__((ext_vector_type(4)));
typedef float f32x4 __attribute__((ext_vector_type(4)));

struct Ptr3  { const float* p[3]; };
struct Ptr3i { const int*   p[3]; };
struct Ptr3h { const short* p[3]; };

__device__ __forceinline__ short f2bf(float f) {
    unsigned u = __builtin_bit_cast(unsigned, f);
    unsigned r = (u + 0x7FFFu + ((u >> 16) & 1u)) >> 16;
    return (short)r;
}

__device__ __forceinline__ void gload_lds16(const void* g, void* l) {
    __builtin_amdgcn_global_load_lds(
        (const __attribute__((address_space(1))) unsigned*)g,
        (__attribute__((address_space(3))) unsigned*)l, 16, 0, 0);
}

// ========== depth-3 pipelined bf16 MFMA GEMM: C = act(A @ B^T + bias) ==========
// BM=256, BN=128, BK=64, 512 thr (8 waves 4M x 2N), wave tile 64x64.
// LDS: 3-slot ring x 48KB (A 32KB + B 16KB) = 144KB -> 1 block/CU.
// Per tile t: 2 phases; each phase {ds_read frags, stage 3 gloads of t+2,
// barrier, setprio 16 MFMA, barrier}; vmcnt(6) once per tile (counted, m201
// formula: 6 loads/tile x 1 tile in flight beyond t+1). Steady state: end of
// tile t leaves exactly t+2's 6 loads outstanding. Tail drains vmcnt(0).
// ACT==1: relu->bf16 ; ACT==2: round(clip+0.1)->f32 + u8 P ; else raw f32
template<int ACT>
__global__ __launch_bounds__(512, 1)
void g8_k(const short* __restrict__ A, const short* __restrict__ Bt,
          const float* __restrict__ bias, void* __restrict__ Cout,
          unsigned char* __restrict__ Pout, int M, int Nn, int K, int lda, int ldb)
{
    constexpr int SLOT = 24576;                 // shorts per slot (48 KB)
    __shared__ short lds[3 * SLOT];
    const int tid = threadIdx.x;
    const int lane = tid & 63;
    const int wave = tid >> 6;
    const int wm = wave >> 1, wn = wave & 1;    // 4 M-waves x 2 N-waves
    // XCD-bijective swizzle (nwg % 8 == 0 for all grids used)
    const int gx = gridDim.x, nwg = gx * gridDim.y;
    int w = blockIdx.y * gx + blockIdx.x;
    const int q8 = nwg >> 3;
    w = (w & 7) * q8 + (w >> 3);
    const int bm0 = (w / gx) * 256, bn0 = (w % gx) * 128;
    const int NT = K >> 6;

    // stage half the loads of tile t into slot t%3.
    // part 0: A rounds 0,1 (rows 0-127) + B round 0 (rows 0-63)
    // part 1: A rounds 2,3 (rows 128-255) + B round 1 (rows 64-127)
    // each round = 8KB/block = 1 gload/wave. 3 gloads/wave per part.
    auto stageR = [&](int t, int part) {
        if (t >= NT) return;
        const int k0 = t << 6;
        char* base = (char*)(lds + (t % 3) * SLOT);
#pragma unroll
        for (int r = 0; r < 2; ++r) {
            int ra = part * 2 + r;
            int o = ra * 8192 + tid * 16;
            int row = o >> 7;                    // 128B per row (BK=64 bf16)
            int sl = (o >> 4) & 7;
            gload_lds16(A + ((size_t)(bm0 + row) * lda + k0 + ((sl ^ (row & 7)) << 3)),
                        base + ra * 8192 + wave * 1024);
        }
        {
            int o = part * 8192 + tid * 16;
            int row = o >> 7;
            int sl = (o >> 4) & 7;
            gload_lds16(Bt + ((size_t)(bn0 + row) * ldb + k0 + ((sl ^ (row & 7)) << 3)),
                        base + 32768 + part * 8192 + wave * 1024);
        }
    };

    f32x4 acc[4][4] = {};
    bf16x8 bF[4][2];     // B frags held across both phases of a tile

    // prologue: stage tiles 0 and 1 fully (12 gloads/wave), wait tile 0 done
    stageR(0, 0); stageR(0, 1);
    stageR(1, 0); stageR(1, 1);
    asm volatile("s_waitcnt vmcnt(6)" ::: "memory");
    __builtin_amdgcn_sched_barrier(0);
    __builtin_amdgcn_s_barrier();

    for (int t = 0; t < NT; ++t) {
        const short* As_ = lds + (t % 3) * SLOT;
        const short* Bs_ = As_ + 16384;
        bf16x8 aF[2][2];
        // ---- phase 0: read B(all, hold) + A rows wm*64+0..31 ----
#pragma unroll
        for (int kk = 0; kk < 2; ++kk) {
            const int h = kk * 4 + (lane >> 4);
#pragma unroll
            for (int j = 0; j < 4; ++j) {
                int r = wn * 64 + j * 16 + (lane & 15);
                bF[j][kk] = *(const bf16x8*)(Bs_ + r * 64 + ((h ^ (r & 7)) << 3));
            }
#pragma unroll
            for (int i = 0; i < 2; ++i) {
                int r = wm * 64 + i * 16 + (lane & 15);
                aF[i][kk] = *(const bf16x8*)(As_ + r * 64 + ((h ^ (r & 7)) << 3));
            }
        }
        stageR(t + 2, 0);
        __builtin_amdgcn_s_barrier();
        __builtin_amdgcn_s_setprio(1);
#pragma unroll
        for (int kk = 0; kk < 2; ++kk)
#pragma unroll
            for (int i = 0; i < 2; ++i)
#pragma unroll
                for (int j = 0; j < 4; ++j)
                    acc[i][j] = __builtin_amdgcn_mfma_f32_16x16x32_bf16(
                        aF[i][kk], bF[j][kk], acc[i][j], 0, 0, 0);
        __builtin_amdgcn_s_setprio(0);
        __builtin_amdgcn_s_barrier();
        // ---- phase 1: read A rows wm*64+32..63; vmcnt once per tile ----
#pragma unroll
        for (int kk = 0; kk < 2; ++kk) {
            const int h = kk * 4 + (lane >> 4);
#pragma unroll
            for (int i = 0; i < 2; ++i) {
                int r = wm * 64 + 32 + i * 16 + (lane & 15);
                aF[i][kk] = *(const bf16x8*)(As_ + r * 64 + ((h ^ (r & 7)) << 3));
            }
        }
        stageR(t + 2, 1);
        __builtin_amdgcn_s_barrier();
        __builtin_amdgcn_s_setprio(1);
#pragma unroll
        for (int kk = 0; kk < 2; ++kk)
#pragma unroll
            for (int i = 0; i < 2; ++i)
#pragma unroll
                for (int j = 0; j < 4; ++j)
                    acc[2 + i][j] = __builtin_amdgcn_mfma_f32_16x16x32_bf16(
                        aF[i][kk], bF[j][kk], acc[2 + i][j], 0, 0, 0);
        __builtin_amdgcn_s_setprio(0);
        if (t + 2 < NT) { asm volatile("s_waitcnt vmcnt(6)" ::: "memory"); }
        else            { asm volatile("s_waitcnt vmcnt(0)" ::: "memory"); }
        __builtin_amdgcn_sched_barrier(0);
        __builtin_amdgcn_s_barrier();
    }

    const int cr = (lane >> 4) * 4;   // C/D: col=lane&15, row=(lane>>4)*4+reg
    const int cc = lane & 15;
#pragma unroll
    for (int im = 0; im < 4; ++im) {
#pragma unroll
        for (int j = 0; j < 4; ++j) {
            int col = bn0 + wn * 64 + j * 16 + cc;
            float bv = bias ? bias[col] : 0.f;
#pragma unroll
            for (int q2 = 0; q2 < 4; ++q2) {
                int row = bm0 + wm * 64 + (im >> 1) * 32 + (im & 1) * 16 + cr + q2;
                float v = acc[im][j][q2] + bv;
                if constexpr (ACT == 1) {
                    v = fmaxf(v, 0.f);
                    ((short*)Cout)[(size_t)row * Nn + col] = f2bf(v);
                } else if constexpr (ACT == 2) {
                    v = rintf(fminf(fmaxf(v, 0.f), 1.f) + 0.1f);
                    ((float*)Cout)[(size_t)row * Nn + col] = v;
                    Pout[(size_t)row * Nn + col] = (unsigned char)(v > 0.5f);
                } else {
                    ((float*)Cout)[(size_t)row * Nn + col] = v;
                }
            }
        }
    }
}

// ---------------- batched bf16 MFMA GEMM, 64x64 tile (per-view stacks) ----------------
__global__ __launch_bounds__(256)
void mfma_gemm_b_k(const short* __restrict__ Aall, Ptr3h Btv, float* __restrict__ Call,
                   int M, int Nn, int K)
{
    __shared__ short As[64 * 64];
    __shared__ short Bs[64 * 64];
    const int z = blockIdx.z;
    const short* A = Aall + (size_t)z * M * K;
    const short* Bt = Btv.p[z];
    float* C = Call + (size_t)z * M * Nn;
    const int tid = threadIdx.x;
    const int lane = tid & 63, wave = tid >> 6;
    const int bm0 = blockIdx.y * 64, bn0 = blockIdx.x * 64;
    const int wr = (wave >> 1) * 32, wc = (wave & 1) * 32;

    f32x4 acc[2][2] = {};

    for (int k0 = 0; k0 < K; k0 += 64) {
        for (int c = wave; c < 8; c += 4) {
            int o = c * 1024 + lane * 16;
            int row = o >> 7;
            int sl = (o >> 4) & 7;
            int ss = sl ^ (row & 7);
            gload_lds16(A + ((size_t)(bm0 + row) * K + k0 + ss * 8), As + c * 512);
            gload_lds16(Bt + ((size_t)(bn0 + row) * K + k0 + ss * 8), Bs + c * 512);
        }
        __syncthreads();
#pragma unroll
        for (int kk = 0; kk < 2; ++kk) {
            bf16x8 a[2], b[2];
            const int khalf = kk * 4 + (lane >> 4);
#pragma unroll
            for (int i = 0; i < 2; ++i) {
                int r = wr + i * 16 + (lane & 15);
                a[i] = *(const bf16x8*)(As + r * 64 + ((khalf ^ (r & 7)) << 3));
            }
#pragma unroll
            for (int j = 0; j < 2; ++j) {
                int r = wc + j * 16 + (lane & 15);
                b[j] = *(const bf16x8*)(Bs + r * 64 + ((khalf ^ (r & 7)) << 3));
            }
#pragma unroll
            for (int i = 0; i < 2; ++i)
#pragma unroll
                for (int j = 0; j < 2; ++j)
                    acc[i][j] = __builtin_amdgcn_mfma_f32_16x16x32_bf16(a[i], b[j], acc[i][j], 0, 0, 0);
        }
        __syncthreads();
    }

    const int cr = (lane >> 4) * 4;
    const int cc = lane & 15;
#pragma unroll
    for (int i = 0; i < 2; ++i)
#pragma unroll
        for (int j = 0; j < 2; ++j)
#pragma unroll
            for (int q = 0; q < 4; ++q) {
                int row = bm0 + wr + i * 16 + cr + q;
                int col = bn0 + wc + j * 16 + cc;
                C[(size_t)row * Nn + col] = acc[i][j][q];
            }
}

// ---------------- MFMA SpMM: part[kc] = A2b[:,kc-chunk] @ (hi+lo)^T ----------------
__global__ __launch_bounds__(256)
void spmm_mfma_k(const short* __restrict__ A2b, const short* __restrict__ XsT,
                 float* __restrict__ part)
{
    __shared__ short As[64 * 64];
    __shared__ short Bs[128 * 64];
    const int tid = threadIdx.x;
    const int lane = tid & 63, wave = tid >> 6;
    const int kc = blockIdx.x, m0 = blockIdx.y * 64;
    const int wr = (wave >> 1) * 32, wc = (wave & 1) * 32;
    const int woff = wave * 512;

    f32x4 acc[2][2] = {};

    for (int k0 = kc * 512; k0 < kc * 512 + 512; k0 += 64) {
#pragma unroll
        for (int r = 0; r < 2; ++r) {
            int o = r * 4096 + tid * 16;
            int row = o >> 7;
            int sl = (o >> 4) & 7;
            gload_lds16(A2b + ((size_t)(m0 + row) * 4096 + k0 + ((sl ^ (row & 7)) << 3)),
                        As + r * 2048 + woff);
        }
#pragma unroll
        for (int r = 0; r < 4; ++r) {
            int o = r * 4096 + tid * 16;
            int row = o >> 7;
            int sl = (o >> 4) & 7;
            gload_lds16(XsT + ((size_t)row * 4096 + k0 + ((sl ^ (row & 7)) << 3)),
                        Bs + r * 2048 + woff);
        }
        __syncthreads();
#pragma unroll
        for (int kk = 0; kk < 2; ++kk) {
            const int h = kk * 4 + (lane >> 4);
            bf16x8 a[2], bh[2], bl[2];
#pragma unroll
            for (int i = 0; i < 2; ++i) {
                int r = wr + i * 16 + (lane & 15);
                a[i] = *(const bf16x8*)(As + r * 64 + ((h ^ (r & 7)) << 3));
            }
#pragma unroll
            for (int j = 0; j < 2; ++j) {
                int r = wc + j * 16 + (lane & 15);
                bh[j] = *(const bf16x8*)(Bs + r * 64 + ((h ^ (r & 7)) << 3));
                int r2 = r + 64;
                bl[j] = *(const bf16x8*)(Bs + r2 * 64 + ((h ^ (r2 & 7)) << 3));
            }
#pragma unroll
            for (int i = 0; i < 2; ++i)
#pragma unroll
                for (int j = 0; j < 2; ++j) {
                    acc[i][j] = __builtin_amdgcn_mfma_f32_16x16x32_bf16(a[i], bh[j], acc[i][j], 0, 0, 0);
                    acc[i][j] = __builtin_amdgcn_mfma_f32_16x16x32_bf16(a[i], bl[j], acc[i][j], 0, 0, 0);
                }
        }
        __syncthreads();
    }

    const int cr = (lane >> 4) * 4;
    const int cc = lane & 15;
#pragma unroll
    for (int i = 0; i < 2; ++i)
#pragma unroll
        for (int j = 0; j < 2; ++j)
#pragma unroll
            for (int q = 0; q < 4; ++q)
                part[((size_t)kc * NNODES + m0 + wr + i * 16 + cr + q) * 64 + wc + j * 16 + cc]
                    = acc[i][j][q];
}

// X [4096][64] f32 -> XsT [128][4096] bf16 (hi rows 0-63, lo 64-127), dn folded
__global__ void xsT_k(const float* __restrict__ X, const int* __restrict__ degA,
                      short* __restrict__ XsT)
{
    const int n = blockIdx.y;
    const int k = blockIdx.x * 256 + threadIdx.x;
    float v = X[(size_t)k * 64 + n] * (1.0f / sqrtf((float)degA[k]));
    short hi = f2bf(v);
    float hif = __builtin_bit_cast(float, ((unsigned)(unsigned short)hi) << 16);
    short lo = f2bf(v - hif);
    XsT[(size_t)n * 4096 + k] = hi;
    XsT[(size_t)(64 + n) * 4096 + k] = lo;
}

// A8 u8 -> bf16 (exact 0/1)
__global__ void a2b_k(const unsigned* __restrict__ A8w, short* __restrict__ A2b, int words)
{
    int t = blockIdx.x * 256 + threadIdx.x;
    if (t < words) {
        unsigned w = A8w[t];
        short4v o;
#pragma unroll
        for (int j = 0; j < 4; ++j) o[j] = ((w >> (8 * j)) & 1u) ? (short)0x3F80 : (short)0;
        *(short4v*)(A2b + (size_t)t * 4) = o;
    }
}

// f32 [R][C] -> bf16 transposed [C][R]
__global__ void f32_to_bf16T_k(const float* __restrict__ src, short* __restrict__ dstT,
                               int R, int C)
{
    __shared__ float t[64][65];
    const int br = blockIdx.y * 64, bc = blockIdx.x * 64;
    for (int idx = threadIdx.x; idx < 64 * 64; idx += 256) {
        int r = idx >> 6, c = idx & 63;
        t[r][c] = src[(size_t)(br + r) * C + bc + c];
    }
    __syncthreads();
    for (int idx = threadIdx.x; idx < 64 * 64; idx += 256) {
        int c = idx >> 6, r = idx & 63;
        dstT[(size_t)(bc + c) * R + br + r] = f2bf(t[r][c]);
    }
}

__global__ void mask_to_bf16_k(const unsigned* __restrict__ mask, short* __restrict__ adj,
                               int words)
{
    int t = blockIdx.x * 256 + threadIdx.x;
    if (t < words) {
        unsigned w = mask[t];
        short4v o;
        o.x = f2bf((float)__popc(w & 0x7u));
        o.y = f2bf((float)__popc(w & 0x700u));
        o.z = f2bf((float)__popc(w & 0x70000u));
        o.w = f2bf((float)__popc(w & 0x7000000u));
        *(short4v*)(adj + (size_t)t * 4) = o;
    }
}

// x [N,512] f32 * doi -> split-bf16 xe [N][1536] = [hi | hi | lo]
__global__ void xsplit_k(Ptr3 xv, const float* __restrict__ isq, short* __restrict__ xe)
{
    const int z = blockIdx.y;
    int t = blockIdx.x * 256 + threadIdx.x;
    int n = t >> 9, k = t & 511;
    float a = xv.p[z][(size_t)n * 512 + k] * isq[2 * z * NNODES + n];
    short hi = f2bf(a);
    float hif = __builtin_bit_cast(float, ((unsigned)(unsigned short)hi) << 16);
    short lo = f2bf(a - hif);
    short* row = xe + (size_t)z * NNODES * 1536 + (size_t)n * 1536;
    row[k] = hi; row[512 + k] = hi; row[1024 + k] = lo;
}

// W [K][Nn] f32 -> split-bf16 transposed Bt [Nn][3K] = [hi | lo | hi]
__global__ void wsplitT_k(Ptr3 Wv, short* __restrict__ out, int K, int Nn)
{
    const int z = blockIdx.y;
    int t = blockIdx.x * 256 + threadIdx.x;
    if (t >= K * Nn) return;
    int k = t / Nn, n = t % Nn;
    float w = Wv.p[z][(size_t)k * Nn + n];
    short hi = f2bf(w);
    float hif = __builtin_bit_cast(float, ((unsigned)(unsigned short)hi) << 16);
    short lo = f2bf(w - hif);
    short* row = out + (size_t)z * Nn * 3 * K + (size_t)n * 3 * K;
    row[k] = hi; row[K + k] = lo; row[2 * K + k] = hi;
}

// fused: s = (sum_p part[p][row,:]) * deg[row]^-1/2 ; out = act(s @ Wm + b)
// optional split-bf16 emit for h@h^T operands (Ae=[hi|hi|lo], Be=[hi|lo|hi])
template<int RELU>
__global__ __launch_bounds__(256)
void redgemm_k(const float* __restrict__ part, const int* __restrict__ degA,
               const float* __restrict__ Wm, const float* __restrict__ bias,
               float* __restrict__ out, short* __restrict__ Ae, short* __restrict__ Be)
{
    __shared__ float Ws[64 * 64];
    const int tid = threadIdx.x;
    for (int i = tid; i < 4096; i += 256) Ws[i] = Wm[i];
    __syncthreads();
    const int lane = tid & 63, wave = tid >> 6;
    const float bv = bias[lane];
    for (int rr = 0; rr < 4; ++rr) {
        int row = blockIdx.x * 16 + wave * 4 + rr;
        float s = 0.f;
#pragma unroll
        for (int p = 0; p < 8; ++p) s += part[((size_t)p * NNODES + row) * 64 + lane];
        s *= 1.0f / sqrtf((float)degA[row]);
        float acc = bv;
#pragma unroll
        for (int k = 0; k < 64; ++k)
            acc = fmaf(__shfl(s, k), Ws[k * 64 + lane], acc);
        if (RELU) acc = fmaxf(acc, 0.f);
        out[(size_t)row * 64 + lane] = acc;
        if (Ae) {
            short hi = f2bf(acc);
            float hif = __builtin_bit_cast(float, ((unsigned)(unsigned short)hi) << 16);
            short lo = f2bf(acc - hif);
            size_t ro = (size_t)row * 192;
            Ae[ro + lane] = hi; Ae[ro + 64 + lane] = hi; Ae[ro + 128 + lane] = lo;
            Be[ro + lane] = hi; Be[ro + 64 + lane] = lo; Be[ro + 128 + lane] = hi;
        }
    }
}

// ---------------- graph construction ----------------
__global__ void edge_k(Ptr3i src, Ptr3i dst, unsigned* __restrict__ mask, int* __restrict__ degs)
{
    int e = blockIdx.x * 256 + threadIdx.x;
    int z = blockIdx.y;
    if (e < NEDGES) {
        int s = src.p[z][e], d = dst.p[z][e];
        unsigned c = (unsigned)s * (unsigned)NNODES + (unsigned)d;
        atomicOr(&mask[c >> 2], 1u << ((c & 3u) * 8u + (unsigned)z));
        atomicAdd(&degs[2 * z * NNODES + s], 1);
        atomicAdd(&degs[(2 * z + 1) * NNODES + d], 1);
    }
}

__global__ void deg_norm_k(const int* __restrict__ degs, float* __restrict__ isq, int n)
{
    int t = blockIdx.x * 256 + threadIdx.x;
    if (t < n) isq[t] = 1.0f / sqrtf(fmaxf((float)degs[t], 1.0f));
}

__global__ __launch_bounds__(1024)
void scan_k(const int* __restrict__ degs, int* __restrict__ rowptr, int* __restrict__ cursor)
{
    const int z = blockIdx.x;
    const int* din = degs + (2 * z + 1) * NNODES;
    __shared__ int sm[1024];
    const int t = threadIdx.x;
    int v0 = din[t * 4], v1 = din[t * 4 + 1], v2 = din[t * 4 + 2], v3 = din[t * 4 + 3];
    int c1 = v0 + v1, c2 = c1 + v2, s = c2 + v3;
    sm[t] = s;
    __syncthreads();
    for (int off = 1; off < 1024; off <<= 1) {
        int add = (t >= off) ? sm[t - off] : 0;
        __syncthreads();
        sm[t] += add;
        __syncthreads();
    }
    int base = sm[t] - s;
    int* rp = rowptr + z * NNODES;
    int* cu = cursor + z * NNODES;
    rp[t * 4] = base;          cu[t * 4] = base;
    rp[t * 4 + 1] = base + v0; cu[t * 4 + 1] = base + v0;
    rp[t * 4 + 2] = base + c1; cu[t * 4 + 2] = base + c1;
    rp[t * 4 + 3] = base + c2; cu[t * 4 + 3] = base + c2;
}

__global__ void fill_k(Ptr3i src, Ptr3i dst, int* __restrict__ cursor, int* __restrict__ eidx)
{
    int e = blockIdx.x * 256 + threadIdx.x;
    int z = blockIdx.y;
    if (e < NEDGES) {
        int d = dst.p[z][e];
        int pos = atomicAdd(&cursor[z * NNODES + d], 1);
        eidx[(size_t)z * NEDGES + pos] = src.p[z][e];
    }
}

// fused CSR-gather + norm + bias + act -> split-bf16 A rows [node][3F]
template<int F, int ACT, int MODE>
__global__ void gather_k(const float* __restrict__ Hpre, const int* __restrict__ eidx,
                         const int* __restrict__ rowptr, const int* __restrict__ degs,
                         const float* __restrict__ isq, Ptr3 bias, short* __restrict__ Sout)
{
    const int z = blockIdx.y;
    const int tid = threadIdx.x;
    const int node = blockIdx.x * (256 / F) + tid / F;
    const int f = tid % F;
    const float* H = Hpre + (size_t)z * NNODES * F;
    const int base = rowptr[z * NNODES + node];
    const int cnt = degs[(2 * z + 1) * NNODES + node];
    const int* ei = eidx + (size_t)z * NEDGES + base;
    float s = 0.f;
    for (int i = 0; i < cnt; ++i) s += H[(size_t)ei[i] * F + f];
    float v = s * isq[(2 * z + 1) * NNODES + node] + bias.p[z][f];
    if (ACT) v = fmaxf(v, 0.f);
    if (MODE == 1) v *= isq[2 * z * NNODES + node];
    short hi = f2bf(v);
    float hif = __builtin_bit_cast(float, ((unsigned)(unsigned short)hi) << 16);
    short lo = f2bf(v - hif);
    short* row = Sout + (size_t)z * NNODES * 3 * F + (size_t)node * 3 * F;
    row[f] = hi; row[F + f] = hi; row[2 * F + f] = lo;
}

// z = softmax_row(zp0+zp1+zp2)
__global__ void softsum_k(const float* __restrict__ zp, float* __restrict__ z)
{
    int row = blockIdx.x * 4 + (threadIdx.x >> 6);
    int f = threadIdx.x & 63;
    size_t i = (size_t)row * 64 + f;
    float v = zp[i] + zp[i + (size_t)NNODES * 64] + zp[i + (size_t)2 * NNODES * 64];
    float m = v;
#pragma unroll
    for (int off = 32; off >= 1; off >>= 1) m = fmaxf(m, __shfl_xor(m, off));
    float e = expf(v - m);
    float s = e;
#pragma unroll
    for (int off = 32; off >= 1; off >>= 1) s += __shfl_xor(s, off);
    z[i] = e / s;
}

// A8[i,j] = P[i,j] | P[j,i] | (i==j), deg row-sums.
__global__ __launch_bounds__(256)
void build_A2_k(const unsigned char* __restrict__ P, unsigned char* __restrict__ A8,
                int* __restrict__ degA)
{
    __shared__ unsigned Ts[64][20];
    const int bi = blockIdx.y * 64, bj = blockIdx.x * 64;
    const int tid = threadIdx.x;
    const int r = tid >> 2, seg = tid & 3;
    uint4 tv = *(const uint4*)(P + (size_t)(bj + r) * NNODES + bi + seg * 16);
    Ts[r][seg * 4 + 0] = tv.x; Ts[r][seg * 4 + 1] = tv.y;
    Ts[r][seg * 4 + 2] = tv.z; Ts[r][seg * 4 + 3] = tv.w;
    __syncthreads();
    uint4 dv = *(const uint4*)(P + (size_t)(bi + r) * NNODES + bj + seg * 16);
    unsigned dw[4] = {dv.x, dv.y, dv.z, dv.w};
    const unsigned char* Tb = (const unsigned char*)Ts;
    unsigned ow[4];
    int psum = 0;
#pragma unroll
    for (int w = 0; w < 4; ++w) {
        unsigned o = 0;
#pragma unroll
        for (int b = 0; b < 4; ++b) {
            int j = seg * 16 + w * 4 + b;
            unsigned a = (dw[w] >> (8 * b)) & 1u;
            unsigned tr = Tb[j * 80 + r] & 1u;
            unsigned on = a | tr | (unsigned)((bi + r) == (bj + j));
            o |= on << (8 * b);
            psum += (int)on;
        }
        ow[w] = o;
    }
    uint4 o4; o4.x = ow[0]; o4.y = ow[1]; o4.z = ow[2]; o4.w = ow[3];
    *(uint4*)(A8 + (size_t)(bi + r) * NNODES + bj + seg * 16) = o4;
    psum += __shfl_xor(psum, 1);
    psum += __shfl_xor(psum, 2);
    if (seg == 0) atomicAdd(&degA[bi + r], psum);
}

extern "C" void kernel_launch(void* const* d_in, const int* in_sizes, int n_in,
                              void* d_out, int out_size, void* d_ws, size_t ws_size,
                              hipStream_t stream)
{
    const int N = NNODES, E = NEDGES;
    const size_t MB = 1024 * 1024;

    const float* x[3]; const int* src[3]; const int* dst[3];
    const float *Wv0[3], *bv0[3], *Wv1[3], *bv1[3], *Wf[3];
    for (int v = 0; v < 3; ++v) {
        const int b = v * 8;
        x[v]   = (const float*)d_in[b + 0];
        src[v] = (const int*)  d_in[b + 1];
        dst[v] = (const int*)  d_in[b + 2];
        Wv0[v] = (const float*)d_in[b + 3];
        bv0[v] = (const float*)d_in[b + 4];
        Wv1[v] = (const float*)d_in[b + 5];
        bv1[v] = (const float*)d_in[b + 6];
        Wf[v]  = (const float*)d_in[b + 7];
    }
    const float* Wg1 = (const float*)d_in[24];
    const float* bg1 = (const float*)d_in[25];
    const float* Wg2 = (const float*)d_in[26];
    const float* bg2 = (const float*)d_in[27];
    const float* Wm0 = (const float*)d_in[28];
    const float* bm0 = (const float*)d_in[29];
    const float* Wm1 = (const float*)d_in[30];
    const float* bm1 = (const float*)d_in[31];

    float* out_adjr = (float*)d_out;                    // [N,N] f32 (final)
    float* out_rec  = out_adjr + (size_t)N * N;         // [N,N] f32 (final; scratch until then)
    float* out_h    = out_rec + (size_t)N * N;          // [N,64]

    // --- scratch carved from dead regions of outputs ---
    char* oa = (char*)out_adjr;                         // 64 MB, final write = GEMM2
    short* AdjB = (short*)oa;                           // bf16 [N][N]  [0,32M)
    float* hv1  = (float*)(oa + 32 * MB);               // f32 [3][N][128]
    short* Ae2  = (short*)(oa + 38 * MB);
    short* Ae3  = (short*)(oa + 47 * MB);
    float* hv2  = (float*)(oa + 52 * MB);
    float* zp   = (float*)(oa + 56 * MB);

    char* orc = (char*)out_rec;                         // 64 MB, final write = h@hT
    short* xe   = (short*)orc;                          // bf16 [3][N][1536] (dead after L1)
    short* H1b  = (short*)orc;                          // bf16 [N][2048]  [0,16M)
    unsigned char* P = (unsigned char*)(orc + 16 * MB); // u8 [N][N]       [16,32M)
    short* Wg1T = (short*)(orc + 16 * MB);              // dead when P written (after GEMM1)
    short* Wg2T = (short*)(orc + 32 * MB);              // [32,48M)
    short* A2b  = (short*)orc;                          // bf16 [N][N] [0,32M) after build_A2
    float* part = (float*)(orc + 48 * MB);              // 8 MB K-split partials (spmm)

    // ---- workspace carve ----
    char* p = (char*)d_ws;
    unsigned* mask = (unsigned*)p;
    unsigned char* A8 = (unsigned char*)p;              // reuses mask region
    short* AeF = (short*)p;                             // h@hT operands (after A8 dead)
    short* BeF = AeF + (size_t)N * 192;
    p += (size_t)N * N;                                 // 16MB
    int* degs = (int*)p;     p += (size_t)6 * N * 4;
    float* isq = (float*)p;  p += (size_t)6 * N * 4;
    int* rowptr = (int*)p;   p += (size_t)3 * N * 4;
    int* cursor = (int*)p;   p += (size_t)3 * N * 4;
    int* eidx = (int*)p;     p += (size_t)3 * E * 4;
    int* degA = (int*)p;     p += (size_t)N * 4;
    float* zbuf = (float*)p; p += (size_t)N * 64 * 4;
    float* h1m = (float*)p;  p += (size_t)N * 64 * 4;
    short* XsT = (short*)p;  p += (size_t)128 * N * 2;
    short* Wv0T = (short*)p; p += (size_t)3 * 128 * 1536 * 2;
    short* Wv1T = (short*)p; p += (size_t)3 * 64 * 384 * 2;
    short* WfT  = (short*)p; p += (size_t)3 * 64 * 192 * 2;

    Ptr3i srcP, dstP;
    for (int v = 0; v < 3; ++v) { srcP.p[v] = src[v]; dstP.p[v] = dst[v]; }

    hipMemsetAsync(mask, 0, (size_t)N * N, stream);
    hipMemsetAsync(degs, 0, (size_t)6 * N * 4, stream);

    edge_k<<<dim3((E + 255) / 256, 3), 256, 0, stream>>>(srcP, dstP, mask, degs);
    deg_norm_k<<<(6 * N + 255) / 256, 256, 0, stream>>>(degs, isq, 6 * N);
    scan_k<<<3, 1024, 0, stream>>>(degs, rowptr, cursor);
    fill_k<<<dim3((E + 255) / 256, 3), 256, 0, stream>>>(srcP, dstP, cursor, eidx);

    // ---- split-bf16 operand builders for per-view GEMMs ----
    Ptr3 xP; for (int v = 0; v < 3; ++v) xP.p[v] = x[v];
    xsplit_k<<<dim3(N * 512 / 256, 3), 256, 0, stream>>>(xP, isq, xe);
    Ptr3 wP;
    for (int v = 0; v < 3; ++v) wP.p[v] = Wv0[v];
    wsplitT_k<<<dim3(512 * 128 / 256, 3), 256, 0, stream>>>(wP, Wv0T, 512, 128);
    for (int v = 0; v < 3; ++v) wP.p[v] = Wv1[v];
    wsplitT_k<<<dim3(128 * 64 / 256, 3), 256, 0, stream>>>(wP, Wv1T, 128, 64);
    for (int v = 0; v < 3; ++v) wP.p[v] = Wf[v];
    wsplitT_k<<<dim3(64 * 64 / 256, 3), 256, 0, stream>>>(wP, WfT, 64, 64);

    // ---- per-view GCN stacks on MFMA (lossless split-bf16) ----
    Ptr3h BtP; Ptr3 biasP;
    for (int v = 0; v < 3; ++v) BtP.p[v] = Wv0T + (size_t)v * 128 * 1536;
    mfma_gemm_b_k<<<dim3(2, N / 64, 3), 256, 0, stream>>>(xe, BtP, hv1, N, 128, 1536);
    for (int v = 0; v < 3; ++v) biasP.p[v] = bv0[v];
    gather_k<128, 1, 1><<<dim3(N / 2, 3), 256, 0, stream>>>(hv1, eidx, rowptr, degs, isq, biasP, Ae2);
    for (int v = 0; v < 3; ++v) BtP.p[v] = Wv1T + (size_t)v * 64 * 384;
    mfma_gemm_b_k<<<dim3(1, N / 64, 3), 256, 0, stream>>>(Ae2, BtP, hv2, N, 64, 384);
    for (int v = 0; v < 3; ++v) biasP.p[v] = bv1[v];
    gather_k<64, 0, 2><<<dim3(N / 4, 3), 256, 0, stream>>>(hv2, eidx, rowptr, degs, isq, biasP, Ae3);
    for (int v = 0; v < 3; ++v) BtP.p[v] = WfT + (size_t)v * 64 * 192;
    mfma_gemm_b_k<<<dim3(1, N / 64, 3), 256, 0, stream>>>(Ae3, BtP, zp, N, 64, 192);
    softsum_k<<<N / 4, 256, 0, stream>>>(zp, zbuf);

    // ---- GFN conversions (xe dead; per-view scratch in oa dead) ----
    mask_to_bf16_k<<<(N * N / 4 + 255) / 256, 256, 0, stream>>>(mask, AdjB, N * N / 4);
    f32_to_bf16T_k<<<dim3(2048 / 64, 4096 / 64), 256, 0, stream>>>(Wg1, Wg1T, 4096, 2048);

    // ---- GEMM1: depth-3 pipelined, relu->bf16 ----
    g8_k<1><<<dim3(2048 / 128, 4096 / 256), 512, 0, stream>>>(
        AdjB, Wg1T, bg1, H1b, nullptr, 4096, 2048, 4096, 4096, 4096);

    f32_to_bf16T_k<<<dim3(4096 / 64, 2048 / 64), 256, 0, stream>>>(Wg2, Wg2T, 2048, 4096);

    // ---- GEMM2: depth-3 pipelined, writes adj_r (f32) + P (u8) ----
    g8_k<2><<<dim3(4096 / 128, 4096 / 256), 512, 0, stream>>>(
        H1b, Wg2T, bg2, out_adjr, P, 4096, 4096, 2048, 2048, 2048);

    // ---- consensus graph ----
    hipMemsetAsync(degA, 0, (size_t)N * 4, stream);
    build_A2_k<<<dim3(N / 64, N / 64), 256, 0, stream>>>(P, A8, degA);

    // ---- fused-graph GCN on MFMA ----
    a2b_k<<<(N * N / 4 + 255) / 256, 256, 0, stream>>>((const unsigned*)A8, A2b, N * N / 4);
    xsT_k<<<dim3(16, 64), 256, 0, stream>>>(zbuf, degA, XsT);
    spmm_mfma_k<<<dim3(8, N / 64), 256, 0, stream>>>(A2b, XsT, part);
    redgemm_k<1><<<256, 256, 0, stream>>>(part, degA, Wm0, bm0, h1m, nullptr, nullptr);
    xsT_k<<<dim3(16, 64), 256, 0, stream>>>(h1m, degA, XsT);
    spmm_mfma_k<<<dim3(8, N / 64), 256, 0, stream>>>(A2b, XsT, part);
    redgemm_k<0><<<256, 256, 0, stream>>>(part, degA, Wm1, bm1, out_h, AeF, BeF);

    // ---- adj_rec = h @ h^T via split-bf16 depth-3 MFMA (K=192) ----
    g8_k<0><<<dim3(4096 / 128, 4096 / 256), 512, 0, stream>>>(
        AeF, BeF, nullptr, out_rec, nullptr, 4096, 4096, 192, 192, 192);
}

// Round 10
// 452.846 us; speedup vs baseline: 10.6719x; 1.0050x over previous
//
#include <hip/hip_runtime.h>
#include <math.h>

#define NNODES 4096
#define NEDGES 65536

typedef short bf16x8 __attribute__((ext_vector_type(8)));
typedef short short4v __attribute__((ext_vector_type(4)));
typedef float f32x4 __attribute__((ext_vector_type(4)));
typedef float f32x4v __attribute__((ext_vector_type(4)));

struct Ptr3  { const float* p[3]; };
struct Ptr3i { const int*   p[3]; };
struct Ptr3h { const short* p[3]; };

__device__ __forceinline__ short f2bf(float f) {
    unsigned u = __builtin_bit_cast(unsigned, f);
    unsigned r = (u + 0x7FFFu + ((u >> 16) & 1u)) >> 16;
    return (short)r;
}

__device__ __forceinline__ void gload_lds16(const void* g, void* l) {
    __builtin_amdgcn_global_load_lds(
        (const __attribute__((address_space(1))) unsigned*)g,
        (__attribute__((address_space(3))) unsigned*)l, 16, 0, 0);
}

// ============ m201-style 256x256 bf16 MFMA GEMM (T1+T2+T3+T4+T5) ============
// 512 thr, 8 waves (2M x 4N), wave tile 128x64, BK=64, LDS 2 x 64KB dbuf.
// 4 quadrant-phases per K-tile (16 MFMA each), read-once frags (A re-read per
// qm half, B held all 4 phases). Half-tile (16KB, 2 gloads/wave) staging, one
// per phase in hazard-verified order; vmcnt(6) once per K-tile = 2 loads x 3
// half-tiles in flight (m201 formula). Odd-NT epilogue (no stage, drained).
// ACT==2: round(clip+0.1)->f32 + u8 P ; ACT==3: raw f32 to (z?C1:C0) ; else f32
template<int ACT>
__global__ __launch_bounds__(512, 1)
void gm_k(const short* __restrict__ A, const short* __restrict__ Bt,
          const float* __restrict__ bias, void* __restrict__ Cout, float* __restrict__ Cout1,
          unsigned char* __restrict__ Pout, int M, int Nn, int K, int lda, int ldb)
{
    constexpr int SLOT = 32768;              // shorts per slot (64KB: A 32KB + B 32KB)
    __shared__ short lds[2 * SLOT];
    const int tid = threadIdx.x;
    const int lane = tid & 63;
    const int wave = tid >> 6;
    const int wm = wave >> 2, wn = wave & 3; // 2 M-waves x 4 N-waves
    const int z = blockIdx.z;
    A  += (size_t)z * K;                     // K-split slice offset
    Bt += (size_t)z * K;
    float* Cf = (ACT == 3 && z == 1) ? Cout1 : (float*)Cout;
    // XCD-bijective swizzle within z-slice (nwg % 8 == 0 for all grids used)
    const int gx = gridDim.x, nwg = gx * gridDim.y;
    int w = blockIdx.y * gx + blockIdx.x;
    const int q8 = nwg >> 3;
    w = (w & 7) * q8 + (w >> 3);
    const int bm0 = (w / gx) * 256, bn0 = (w % gx) * 256;
    const int NT = K >> 6;

    // stage one half-tile of tile t. part: 0=B rows0-127, 1=B rows128-255,
    // 2=A rows0-127, 3=A rows128-255. 16KB = 2 rounds of 512thr x 16B = 2 gloads/wave.
    auto stageH = [&](int t, int part) {
        if (t >= NT) return;
        const int k0 = t << 6;
        char* base = (char*)(lds + (t & 1) * SLOT);
        const int isB = (part < 2);
        const int h = part & 1;
#pragma unroll
        for (int r = 0; r < 2; ++r) {
            int o = r * 8192 + tid * 16;                 // byte offset within half
            int row = o >> 7;                            // 0..127
            int grow = h * 128 + row;                    // 0..255
            int scol = (((o >> 4) & 7) ^ (grow & 7)) << 3;
            const short* gsrc = isB ? (Bt + (size_t)(bn0 + grow) * ldb + k0 + scol)
                                    : (A  + (size_t)(bm0 + grow) * lda + k0 + scol);
            gload_lds16(gsrc, base + (isB ? 32768 : 0) + h * 16384 + r * 8192 + wave * 1024);
        }
    };

    f32x4 acc[8][4] = {};
    bf16x8 aF[4][2];     // current qm half's A frags (rows wm*128 + qm*64 ..+63)
    bf16x8 bF[4][2];     // wave's 64 B cols, held across all 4 phases of a tile

// one quadrant-phase: reads (QN==0: A qm-half; QM==0: B qn-half), up to 2 stages,
// barrier, 16 MFMA (setprio), optional counted vmcnt, barrier.
#define PH(QM, QN, TCUR, T1, P1, T2, P2, VM)                                          \
    {                                                                                 \
        const short* As_ = lds + ((TCUR) & 1) * SLOT;                                 \
        const short* Bs_ = As_ + 16384;                                               \
        if constexpr ((QN) == 0) {                                                    \
            _Pragma("unroll") for (int kk = 0; kk < 2; ++kk) {                        \
                const int h_ = kk * 4 + (lane >> 4);                                  \
                _Pragma("unroll") for (int i = 0; i < 4; ++i) {                       \
                    int r_ = wm * 128 + (QM) * 64 + i * 16 + (lane & 15);             \
                    aF[i][kk] = *(const bf16x8*)(As_ + r_ * 64 + ((h_ ^ (r_ & 7)) << 3)); \
                }                                                                     \
            }                                                                         \
        }                                                                             \
        if constexpr ((QM) == 0) {                                                    \
            _Pragma("unroll") for (int kk = 0; kk < 2; ++kk) {                        \
                const int h_ = kk * 4 + (lane >> 4);                                  \
                _Pragma("unroll") for (int j = 0; j < 2; ++j) {                       \
                    int r_ = wn * 64 + ((QN) * 2 + j) * 16 + (lane & 15);             \
                    bF[(QN) * 2 + j][kk] = *(const bf16x8*)(Bs_ + r_ * 64 + ((h_ ^ (r_ & 7)) << 3)); \
                }                                                                     \
            }                                                                         \
        }                                                                             \
        if ((P1) >= 0) stageH(T1, P1);                                                \
        if ((P2) >= 0) stageH(T2, P2);                                                \
        __builtin_amdgcn_s_barrier();                                                 \
        __builtin_amdgcn_s_setprio(1);                                                \
        _Pragma("unroll") for (int kk = 0; kk < 2; ++kk)                              \
            _Pragma("unroll") for (int i = 0; i < 4; ++i)                             \
                _Pragma("unroll") for (int j = 0; j < 2; ++j)                         \
                    acc[(QM) * 4 + i][(QN) * 2 + j] =                                 \
                        __builtin_amdgcn_mfma_f32_16x16x32_bf16(                      \
                            aF[i][kk], bF[(QN) * 2 + j][kk],                          \
                            acc[(QM) * 4 + i][(QN) * 2 + j], 0, 0, 0);                \
        __builtin_amdgcn_s_setprio(0);                                                \
        if ((VM) == 6)      { asm volatile("s_waitcnt vmcnt(6)" ::: "memory");        \
                              __builtin_amdgcn_sched_barrier(0); }                    \
        else if ((VM) == 0) { asm volatile("s_waitcnt vmcnt(0)" ::: "memory");        \
                              __builtin_amdgcn_sched_barrier(0); }                    \
        __builtin_amdgcn_s_barrier();                                                 \
    }

    // prologue: tile 0 fully + tile 1 parts B0,B1,A0 (A1 comes at first ph1).
    // vmcnt(6) -> tile 0's 8 loads done, t1's 6 newest outstanding.
    stageH(0, 0); stageH(0, 1); stageH(0, 2); stageH(0, 3);
    if (NT > 1) { stageH(1, 0); stageH(1, 1); stageH(1, 2); }
    if (NT > 1) { asm volatile("s_waitcnt vmcnt(6)" ::: "memory"); }
    else        { asm volatile("s_waitcnt vmcnt(0)" ::: "memory"); }
    __builtin_amdgcn_sched_barrier(0);
    __builtin_amdgcn_s_barrier();

    for (int it = 0; it < NT / 2; ++it) {
        const int t0 = 2 * it, t1 = t0 + 1, t2 = t0 + 2, t3 = t0 + 3;
        const int vm4 = (t2 < NT) ? 6 : 0;
        const int vm8 = (t3 < NT) ? 6 : 0;
        // hazard map: t2 slot == t0 slot (B free after ph(0,1), A after ph(1,0));
        // t3 slot == t1 slot. vmcnt(6) at ph(1,1) -> ALL older loads (= next tile)
        // complete; newest 6 = the 3 half-tiles just issued.
        PH(0, 0, t0, t1, 3,  0, -1, -1)
        PH(0, 1, t0,  0, -1, 0, -1, -1)
        PH(1, 0, t0, t2, 0, t2,  1, -1)
        PH(1, 1, t0, t2, 2,  0, -1, vm4)
        PH(0, 0, t1, t2, 3,  0, -1, -1)
        PH(0, 1, t1,  0, -1, 0, -1, -1)
        PH(1, 0, t1, t3, 0, t3,  1, -1)
        PH(1, 1, t1, t3, 2,  0, -1, vm8)
    }
    if (NT & 1) {   // odd-NT epilogue: last tile, fully staged + drained already
        const int tl = NT - 1;
        PH(0, 0, tl, 0, -1, 0, -1, -1)
        PH(0, 1, tl, 0, -1, 0, -1, -1)
        PH(1, 0, tl, 0, -1, 0, -1, -1)
        PH(1, 1, tl, 0, -1, 0, -1, -1)
    }
#undef PH

    const int cr = (lane >> 4) * 4;   // C/D: col=lane&15, row=(lane>>4)*4+reg
    const int cc = lane & 15;
#pragma unroll
    for (int im = 0; im < 8; ++im) {
#pragma unroll
        for (int jn = 0; jn < 4; ++jn) {
            int col = bn0 + wn * 64 + jn * 16 + cc;
            float bv = bias ? bias[col] : 0.f;
#pragma unroll
            for (int q2 = 0; q2 < 4; ++q2) {
                int row = bm0 + wm * 128 + (im >> 2) * 64 + (im & 3) * 16 + cr + q2;
                float v = acc[im][jn][q2] + bv;
                if constexpr (ACT == 2) {
                    v = rintf(fminf(fmaxf(v, 0.f), 1.f) + 0.1f);
                    Cf[(size_t)row * Nn + col] = v;
                    Pout[(size_t)row * Nn + col] = (unsigned char)(v > 0.5f);
                } else {
                    Cf[(size_t)row * Nn + col] = v;
                }
            }
        }
    }
}

// H1b = bf16(relu(part0 + part1 + bias[col])), [4096][2048]
__global__ void reduce_h1_k(const float* __restrict__ p0, const float* __restrict__ p1,
                            const float* __restrict__ bias, short* __restrict__ H1b)
{
    int i = (blockIdx.x * 256 + threadIdx.x) * 4;
    f32x4v a = *(const f32x4v*)(p0 + i);
    f32x4v b = *(const f32x4v*)(p1 + i);
    int col = i & 2047;
    short4v o;
#pragma unroll
    for (int j = 0; j < 4; ++j) {
        float v = a[j] + b[j] + bias[col + j];
        o[j] = f2bf(fmaxf(v, 0.f));
    }
    *(short4v*)(H1b + i) = o;
}

// ---------------- batched bf16 MFMA GEMM, 64x64 tile (per-view stacks) ----------------
__global__ __launch_bounds__(256)
void mfma_gemm_b_k(const short* __restrict__ Aall, Ptr3h Btv, float* __restrict__ Call,
                   int M, int Nn, int K)
{
    __shared__ short As[64 * 64];
    __shared__ short Bs[64 * 64];
    const int z = blockIdx.z;
    const short* A = Aall + (size_t)z * M * K;
    const short* Bt = Btv.p[z];
    float* C = Call + (size_t)z * M * Nn;
    const int tid = threadIdx.x;
    const int lane = tid & 63, wave = tid >> 6;
    const int bm0 = blockIdx.y * 64, bn0 = blockIdx.x * 64;
    const int wr = (wave >> 1) * 32, wc = (wave & 1) * 32;

    f32x4 acc[2][2] = {};

    for (int k0 = 0; k0 < K; k0 += 64) {
        for (int c = wave; c < 8; c += 4) {
            int o = c * 1024 + lane * 16;
            int row = o >> 7;
            int sl = (o >> 4) & 7;
            int ss = sl ^ (row & 7);
            gload_lds16(A + ((size_t)(bm0 + row) * K + k0 + ss * 8), As + c * 512);
            gload_lds16(Bt + ((size_t)(bn0 + row) * K + k0 + ss * 8), Bs + c * 512);
        }
        __syncthreads();
#pragma unroll
        for (int kk = 0; kk < 2; ++kk) {
            bf16x8 a[2], b[2];
            const int khalf = kk * 4 + (lane >> 4);
#pragma unroll
            for (int i = 0; i < 2; ++i) {
                int r = wr + i * 16 + (lane & 15);
                a[i] = *(const bf16x8*)(As + r * 64 + ((khalf ^ (r & 7)) << 3));
            }
#pragma unroll
            for (int j = 0; j < 2; ++j) {
                int r = wc + j * 16 + (lane & 15);
                b[j] = *(const bf16x8*)(Bs + r * 64 + ((khalf ^ (r & 7)) << 3));
            }
#pragma unroll
            for (int i = 0; i < 2; ++i)
#pragma unroll
                for (int j = 0; j < 2; ++j)
                    acc[i][j] = __builtin_amdgcn_mfma_f32_16x16x32_bf16(a[i], b[j], acc[i][j], 0, 0, 0);
        }
        __syncthreads();
    }

    const int cr = (lane >> 4) * 4;
    const int cc = lane & 15;
#pragma unroll
    for (int i = 0; i < 2; ++i)
#pragma unroll
        for (int j = 0; j < 2; ++j)
#pragma unroll
            for (int q = 0; q < 4; ++q) {
                int row = bm0 + wr + i * 16 + cr + q;
                int col = bn0 + wc + j * 16 + cc;
                C[(size_t)row * Nn + col] = acc[i][j][q];
            }
}

// ---------------- MFMA SpMM: part[kc] = A2b[:,kc-chunk] @ (hi+lo)^T ----------------
__global__ __launch_bounds__(256)
void spmm_mfma_k(const short* __restrict__ A2b, const short* __restrict__ XsT,
                 float* __restrict__ part)
{
    __shared__ short As[64 * 64];
    __shared__ short Bs[128 * 64];
    const int tid = threadIdx.x;
    const int lane = tid & 63, wave = tid >> 6;
    const int kc = blockIdx.x, m0 = blockIdx.y * 64;
    const int wr = (wave >> 1) * 32, wc = (wave & 1) * 32;
    const int woff = wave * 512;

    f32x4 acc[2][2] = {};

    for (int k0 = kc * 512; k0 < kc * 512 + 512; k0 += 64) {
#pragma unroll
        for (int r = 0; r < 2; ++r) {
            int o = r * 4096 + tid * 16;
            int row = o >> 7;
            int sl = (o >> 4) & 7;
            gload_lds16(A2b + ((size_t)(m0 + row) * 4096 + k0 + ((sl ^ (row & 7)) << 3)),
                        As + r * 2048 + woff);
        }
#pragma unroll
        for (int r = 0; r < 4; ++r) {
            int o = r * 4096 + tid * 16;
            int row = o >> 7;
            int sl = (o >> 4) & 7;
            gload_lds16(XsT + ((size_t)row * 4096 + k0 + ((sl ^ (row & 7)) << 3)),
                        Bs + r * 2048 + woff);
        }
        __syncthreads();
#pragma unroll
        for (int kk = 0; kk < 2; ++kk) {
            const int h = kk * 4 + (lane >> 4);
            bf16x8 a[2], bh[2], bl[2];
#pragma unroll
            for (int i = 0; i < 2; ++i) {
                int r = wr + i * 16 + (lane & 15);
                a[i] = *(const bf16x8*)(As + r * 64 + ((h ^ (r & 7)) << 3));
            }
#pragma unroll
            for (int j = 0; j < 2; ++j) {
                int r = wc + j * 16 + (lane & 15);
                bh[j] = *(const bf16x8*)(Bs + r * 64 + ((h ^ (r & 7)) << 3));
                int r2 = r + 64;
                bl[j] = *(const bf16x8*)(Bs + r2 * 64 + ((h ^ (r2 & 7)) << 3));
            }
#pragma unroll
            for (int i = 0; i < 2; ++i)
#pragma unroll
                for (int j = 0; j < 2; ++j) {
                    acc[i][j] = __builtin_amdgcn_mfma_f32_16x16x32_bf16(a[i], bh[j], acc[i][j], 0, 0, 0);
                    acc[i][j] = __builtin_amdgcn_mfma_f32_16x16x32_bf16(a[i], bl[j], acc[i][j], 0, 0, 0);
                }
        }
        __syncthreads();
    }

    const int cr = (lane >> 4) * 4;
    const int cc = lane & 15;
#pragma unroll
    for (int i = 0; i < 2; ++i)
#pragma unroll
        for (int j = 0; j < 2; ++j)
#pragma unroll
            for (int q = 0; q < 4; ++q)
                part[((size_t)kc * NNODES + m0 + wr + i * 16 + cr + q) * 64 + wc + j * 16 + cc]
                    = acc[i][j][q];
}

// X [4096][64] f32 -> XsT [128][4096] bf16 (hi rows 0-63, lo 64-127), dn folded
__global__ void xsT_k(const float* __restrict__ X, const int* __restrict__ degA,
                      short* __restrict__ XsT)
{
    const int n = blockIdx.y;
    const int k = blockIdx.x * 256 + threadIdx.x;
    float v = X[(size_t)k * 64 + n] * (1.0f / sqrtf((float)degA[k]));
    short hi = f2bf(v);
    float hif = __builtin_bit_cast(float, ((unsigned)(unsigned short)hi) << 16);
    short lo = f2bf(v - hif);
    XsT[(size_t)n * 4096 + k] = hi;
    XsT[(size_t)(64 + n) * 4096 + k] = lo;
}

// A8 u8 -> bf16 (exact 0/1)
__global__ void a2b_k(const unsigned* __restrict__ A8w, short* __restrict__ A2b, int words)
{
    int t = blockIdx.x * 256 + threadIdx.x;
    if (t < words) {
        unsigned w = A8w[t];
        short4v o;
#pragma unroll
        for (int j = 0; j < 4; ++j) o[j] = ((w >> (8 * j)) & 1u) ? (short)0x3F80 : (short)0;
        *(short4v*)(A2b + (size_t)t * 4) = o;
    }
}

// f32 [R][C] -> bf16 transposed [C][R]
__global__ void f32_to_bf16T_k(const float* __restrict__ src, short* __restrict__ dstT,
                               int R, int C)
{
    __shared__ float t[64][65];
    const int br = blockIdx.y * 64, bc = blockIdx.x * 64;
    for (int idx = threadIdx.x; idx < 64 * 64; idx += 256) {
        int r = idx >> 6, c = idx & 63;
        t[r][c] = src[(size_t)(br + r) * C + bc + c];
    }
    __syncthreads();
    for (int idx = threadIdx.x; idx < 64 * 64; idx += 256) {
        int c = idx >> 6, r = idx & 63;
        dstT[(size_t)(bc + c) * R + br + r] = f2bf(t[r][c]);
    }
}

__global__ void mask_to_bf16_k(const unsigned* __restrict__ mask, short* __restrict__ adj,
                               int words)
{
    int t = blockIdx.x * 256 + threadIdx.x;
    if (t < words) {
        unsigned w = mask[t];
        short4v o;
        o.x = f2bf((float)__popc(w & 0x7u));
        o.y = f2bf((float)__popc(w & 0x700u));
        o.z = f2bf((float)__popc(w & 0x70000u));
        o.w = f2bf((float)__popc(w & 0x7000000u));
        *(short4v*)(adj + (size_t)t * 4) = o;
    }
}

// x [N,512] f32 * doi -> split-bf16 xe [N][1536] = [hi | hi | lo]
__global__ void xsplit_k(Ptr3 xv, const float* __restrict__ isq, short* __restrict__ xe)
{
    const int z = blockIdx.y;
    int t = blockIdx.x * 256 + threadIdx.x;
    int n = t >> 9, k = t & 511;
    float a = xv.p[z][(size_t)n * 512 + k] * isq[2 * z * NNODES + n];
    short hi = f2bf(a);
    float hif = __builtin_bit_cast(float, ((unsigned)(unsigned short)hi) << 16);
    short lo = f2bf(a - hif);
    short* row = xe + (size_t)z * NNODES * 1536 + (size_t)n * 1536;
    row[k] = hi; row[512 + k] = hi; row[1024 + k] = lo;
}

// W [K][Nn] f32 -> split-bf16 transposed Bt [Nn][3K] = [hi | lo | hi]
__global__ void wsplitT_k(Ptr3 Wv, short* __restrict__ out, int K, int Nn)
{
    const int z = blockIdx.y;
    int t = blockIdx.x * 256 + threadIdx.x;
    if (t >= K * Nn) return;
    int k = t / Nn, n = t % Nn;
    float w = Wv.p[z][(size_t)k * Nn + n];
    short hi = f2bf(w);
    float hif = __builtin_bit_cast(float, ((unsigned)(unsigned short)hi) << 16);
    short lo = f2bf(w - hif);
    short* row = out + (size_t)z * Nn * 3 * K + (size_t)n * 3 * K;
    row[k] = hi; row[K + k] = lo; row[2 * K + k] = hi;
}

// fused: s = (sum_p part[p][row,:]) * deg[row]^-1/2 ; out = act(s @ Wm + b)
// optional split-bf16 emit for h@h^T operands (Ae=[hi|hi|lo], Be=[hi|lo|hi])
template<int RELU>
__global__ __launch_bounds__(256)
void redgemm_k(const float* __restrict__ part, const int* __restrict__ degA,
               const float* __restrict__ Wm, const float* __restrict__ bias,
               float* __restrict__ out, short* __restrict__ Ae, short* __restrict__ Be)
{
    __shared__ float Ws[64 * 64];
    const int tid = threadIdx.x;
    for (int i = tid; i < 4096; i += 256) Ws[i] = Wm[i];
    __syncthreads();
    const int lane = tid & 63, wave = tid >> 6;
    const float bv = bias[lane];
    for (int rr = 0; rr < 4; ++rr) {
        int row = blockIdx.x * 16 + wave * 4 + rr;
        float s = 0.f;
#pragma unroll
        for (int p = 0; p < 8; ++p) s += part[((size_t)p * NNODES + row) * 64 + lane];
        s *= 1.0f / sqrtf((float)degA[row]);
        float acc = bv;
#pragma unroll
        for (int k = 0; k < 64; ++k)
            acc = fmaf(__shfl(s, k), Ws[k * 64 + lane], acc);
        if (RELU) acc = fmaxf(acc, 0.f);
        out[(size_t)row * 64 + lane] = acc;
        if (Ae) {
            short hi = f2bf(acc);
            float hif = __builtin_bit_cast(float, ((unsigned)(unsigned short)hi) << 16);
            short lo = f2bf(acc - hif);
            size_t ro = (size_t)row * 192;
            Ae[ro + lane] = hi; Ae[ro + 64 + lane] = hi; Ae[ro + 128 + lane] = lo;
            Be[ro + lane] = hi; Be[ro + 64 + lane] = lo; Be[ro + 128 + lane] = hi;
        }
    }
}

// ---------------- graph construction ----------------
__global__ void edge_k(Ptr3i src, Ptr3i dst, unsigned* __restrict__ mask, int* __restrict__ degs)
{
    int e = blockIdx.x * 256 + threadIdx.x;
    int z = blockIdx.y;
    if (e < NEDGES) {
        int s = src.p[z][e], d = dst.p[z][e];
        unsigned c = (unsigned)s * (unsigned)NNODES + (unsigned)d;
        atomicOr(&mask[c >> 2], 1u << ((c & 3u) * 8u + (unsigned)z));
        atomicAdd(&degs[2 * z * NNODES + s], 1);
        atomicAdd(&degs[(2 * z + 1) * NNODES + d], 1);
    }
}

__global__ void deg_norm_k(const int* __restrict__ degs, float* __restrict__ isq, int n)
{
    int t = blockIdx.x * 256 + threadIdx.x;
    if (t < n) isq[t] = 1.0f / sqrtf(fmaxf((float)degs[t], 1.0f));
}

__global__ __launch_bounds__(1024)
void scan_k(const int* __restrict__ degs, int* __restrict__ rowptr, int* __restrict__ cursor)
{
    const int z = blockIdx.x;
    const int* din = degs + (2 * z + 1) * NNODES;
    __shared__ int sm[1024];
    const int t = threadIdx.x;
    int v0 = din[t * 4], v1 = din[t * 4 + 1], v2 = din[t * 4 + 2], v3 = din[t * 4 + 3];
    int c1 = v0 + v1, c2 = c1 + v2, s = c2 + v3;
    sm[t] = s;
    __syncthreads();
    for (int off = 1; off < 1024; off <<= 1) {
        int add = (t >= off) ? sm[t - off] : 0;
        __syncthreads();
        sm[t] += add;
        __syncthreads();
    }
    int base = sm[t] - s;
    int* rp = rowptr + z * NNODES;
    int* cu = cursor + z * NNODES;
    rp[t * 4] = base;          cu[t * 4] = base;
    rp[t * 4 + 1] = base + v0; cu[t * 4 + 1] = base + v0;
    rp[t * 4 + 2] = base + c1; cu[t * 4 + 2] = base + c1;
    rp[t * 4 + 3] = base + c2; cu[t * 4 + 3] = base + c2;
}

__global__ void fill_k(Ptr3i src, Ptr3i dst, int* __restrict__ cursor, int* __restrict__ eidx)
{
    int e = blockIdx.x * 256 + threadIdx.x;
    int z = blockIdx.y;
    if (e < NEDGES) {
        int d = dst.p[z][e];
        int pos = atomicAdd(&cursor[z * NNODES + d], 1);
        eidx[(size_t)z * NEDGES + pos] = src.p[z][e];
    }
}

// fused CSR-gather + norm + bias + act -> split-bf16 A rows [node][3F]
template<int F, int ACT, int MODE>
__global__ void gather_k(const float* __restrict__ Hpre, const int* __restrict__ eidx,
                         const int* __restrict__ rowptr, const int* __restrict__ degs,
                         const float* __restrict__ isq, Ptr3 bias, short* __restrict__ Sout)
{
    const int z = blockIdx.y;
    const int tid = threadIdx.x;
    const int node = blockIdx.x * (256 / F) + tid / F;
    const int f = tid % F;
    const float* H = Hpre + (size_t)z * NNODES * F;
    const int base = rowptr[z * NNODES + node];
    const int cnt = degs[(2 * z + 1) * NNODES + node];
    const int* ei = eidx + (size_t)z * NEDGES + base;
    float s = 0.f;
    for (int i = 0; i < cnt; ++i) s += H[(size_t)ei[i] * F + f];
    float v = s * isq[(2 * z + 1) * NNODES + node] + bias.p[z][f];
    if (ACT) v = fmaxf(v, 0.f);
    if (MODE == 1) v *= isq[2 * z * NNODES + node];
    short hi = f2bf(v);
    float hif = __builtin_bit_cast(float, ((unsigned)(unsigned short)hi) << 16);
    short lo = f2bf(v - hif);
    short* row = Sout + (size_t)z * NNODES * 3 * F + (size_t)node * 3 * F;
    row[f] = hi; row[F + f] = hi; row[2 * F + f] = lo;
}

// z = softmax_row(zp0+zp1+zp2)
__global__ void softsum_k(const float* __restrict__ zp, float* __restrict__ z)
{
    int row = blockIdx.x * 4 + (threadIdx.x >> 6);
    int f = threadIdx.x & 63;
    size_t i = (size_t)row * 64 + f;
    float v = zp[i] + zp[i + (size_t)NNODES * 64] + zp[i + (size_t)2 * NNODES * 64];
    float m = v;
#pragma unroll
    for (int off = 32; off >= 1; off >>= 1) m = fmaxf(m, __shfl_xor(m, off));
    float e = expf(v - m);
    float s = e;
#pragma unroll
    for (int off = 32; off >= 1; off >>= 1) s += __shfl_xor(s, off);
    z[i] = e / s;
}

// A8[i,j] = P[i,j] | P[j,i] | (i==j), deg row-sums.
__global__ __launch_bounds__(256)
void build_A2_k(const unsigned char* __restrict__ P, unsigned char* __restrict__ A8,
                int* __restrict__ degA)
{
    __shared__ unsigned Ts[64][20];
    const int bi = blockIdx.y * 64, bj = blockIdx.x * 64;
    const int tid = threadIdx.x;
    const int r = tid >> 2, seg = tid & 3;
    uint4 tv = *(const uint4*)(P + (size_t)(bj + r) * NNODES + bi + seg * 16);
    Ts[r][seg * 4 + 0] = tv.x; Ts[r][seg * 4 + 1] = tv.y;
    Ts[r][seg * 4 + 2] = tv.z; Ts[r][seg * 4 + 3] = tv.w;
    __syncthreads();
    uint4 dv = *(const uint4*)(P + (size_t)(bi + r) * NNODES + bj + seg * 16);
    unsigned dw[4] = {dv.x, dv.y, dv.z, dv.w};
    const unsigned char* Tb = (const unsigned char*)Ts;
    unsigned ow[4];
    int psum = 0;
#pragma unroll
    for (int w = 0; w < 4; ++w) {
        unsigned o = 0;
#pragma unroll
        for (int b = 0; b < 4; ++b) {
            int j = seg * 16 + w * 4 + b;
            unsigned a = (dw[w] >> (8 * b)) & 1u;
            unsigned tr = Tb[j * 80 + r] & 1u;
            unsigned on = a | tr | (unsigned)((bi + r) == (bj + j));
            o |= on << (8 * b);
            psum += (int)on;
        }
        ow[w] = o;
    }
    uint4 o4; o4.x = ow[0]; o4.y = ow[1]; o4.z = ow[2]; o4.w = ow[3];
    *(uint4*)(A8 + (size_t)(bi + r) * NNODES + bj + seg * 16) = o4;
    psum += __shfl_xor(psum, 1);
    psum += __shfl_xor(psum, 2);
    if (seg == 0) atomicAdd(&degA[bi + r], psum);
}

extern "C" void kernel_launch(void* const* d_in, const int* in_sizes, int n_in,
                              void* d_out, int out_size, void* d_ws, size_t ws_size,
                              hipStream_t stream)
{
    const int N = NNODES, E = NEDGES;
    const size_t MB = 1024 * 1024;

    const float* x[3]; const int* src[3]; const int* dst[3];
    const float *Wv0[3], *bv0[3], *Wv1[3], *bv1[3], *Wf[3];
    for (int v = 0; v < 3; ++v) {
        const int b = v * 8;
        x[v]   = (const float*)d_in[b + 0];
        src[v] = (const int*)  d_in[b + 1];
        dst[v] = (const int*)  d_in[b + 2];
        Wv0[v] = (const float*)d_in[b + 3];
        bv0[v] = (const float*)d_in[b + 4];
        Wv1[v] = (const float*)d_in[b + 5];
        bv1[v] = (const float*)d_in[b + 6];
        Wf[v]  = (const float*)d_in[b + 7];
    }
    const float* Wg1 = (const float*)d_in[24];
    const float* bg1 = (const float*)d_in[25];
    const float* Wg2 = (const float*)d_in[26];
    const float* bg2 = (const float*)d_in[27];
    const float* Wm0 = (const float*)d_in[28];
    const float* bm0 = (const float*)d_in[29];
    const float* Wm1 = (const float*)d_in[30];
    const float* bm1 = (const float*)d_in[31];

    float* out_adjr = (float*)d_out;                    // [N,N] f32 (final)
    float* out_rec  = out_adjr + (size_t)N * N;         // [N,N] f32 (final; scratch until then)
    float* out_h    = out_rec + (size_t)N * N;          // [N,64]

    // --- scratch carved from dead regions of outputs ---
    char* oa = (char*)out_adjr;                         // 64 MB, final write = GEMM2
    short* AdjB = (short*)oa;                           // bf16 [N][N]  [0,32M)
    float* hv1  = (float*)(oa + 32 * MB);               // f32 [3][N][128]
    short* Ae2  = (short*)(oa + 38 * MB);
    short* Ae3  = (short*)(oa + 47 * MB);
    float* hv2  = (float*)(oa + 52 * MB);
    float* zp   = (float*)(oa + 56 * MB);
    float* partg0 = (float*)(oa + 32 * MB);             // GEMM1 K-split partial z=0 (32 MB)

    char* orc = (char*)out_rec;                         // 64 MB, final write = h@hT
    short* xe   = (short*)orc;                          // bf16 [3][N][1536] (dead after L1)
    short* H1b  = (short*)orc;                          // bf16 [N][2048]  [0,16M)
    unsigned char* P = (unsigned char*)(orc + 16 * MB); // u8 [N][N]       [16,32M)
    short* Wg1T = (short*)(orc + 16 * MB);              // dead when P written (after GEMM1)
    float* partg1 = (float*)(orc + 32 * MB);            // GEMM1 K-split partial z=1 (32 MB)
    short* Wg2T = (short*)(orc + 32 * MB);              // built AFTER reduce (over dead partg1)
    short* A2b  = (short*)orc;                          // bf16 [N][N] [0,32M) after build_A2
    float* part = (float*)(orc + 48 * MB);              // 8 MB K-split partials (spmm)

    // ---- workspace carve ----
    char* p = (char*)d_ws;
    unsigned* mask = (unsigned*)p;
    unsigned char* A8 = (unsigned char*)p;              // reuses mask region
    short* AeF = (short*)p;                             // h@hT operands (after A8 dead)
    short* BeF = AeF + (size_t)N * 192;
    p += (size_t)N * N;                                 // 16MB
    int* degs = (int*)p;     p += (size_t)6 * N * 4;
    float* isq = (float*)p;  p += (size_t)6 * N * 4;
    int* rowptr = (int*)p;   p += (size_t)3 * N * 4;
    int* cursor = (int*)p;   p += (size_t)3 * N * 4;
    int* eidx = (int*)p;     p += (size_t)3 * E * 4;
    int* degA = (int*)p;     p += (size_t)N * 4;
    float* zbuf = (float*)p; p += (size_t)N * 64 * 4;
    float* h1m = (float*)p;  p += (size_t)N * 64 * 4;
    short* XsT = (short*)p;  p += (size_t)128 * N * 2;
    short* Wv0T = (short*)p; p += (size_t)3 * 128 * 1536 * 2;
    short* Wv1T = (short*)p; p += (size_t)3 * 64 * 384 * 2;
    short* WfT  = (short*)p; p += (size_t)3 * 64 * 192 * 2;

    Ptr3i srcP, dstP;
    for (int v = 0; v < 3; ++v) { srcP.p[v] = src[v]; dstP.p[v] = dst[v]; }

    hipMemsetAsync(mask, 0, (size_t)N * N, stream);
    hipMemsetAsync(degs, 0, (size_t)6 * N * 4, stream);

    edge_k<<<dim3((E + 255) / 256, 3), 256, 0, stream>>>(srcP, dstP, mask, degs);
    deg_norm_k<<<(6 * N + 255) / 256, 256, 0, stream>>>(degs, isq, 6 * N);
    scan_k<<<3, 1024, 0, stream>>>(degs, rowptr, cursor);
    fill_k<<<dim3((E + 255) / 256, 3), 256, 0, stream>>>(srcP, dstP, cursor, eidx);

    // ---- split-bf16 operand builders for per-view GEMMs ----
    Ptr3 xP; for (int v = 0; v < 3; ++v) xP.p[v] = x[v];
    xsplit_k<<<dim3(N * 512 / 256, 3), 256, 0, stream>>>(xP, isq, xe);
    Ptr3 wP;
    for (int v = 0; v < 3; ++v) wP.p[v] = Wv0[v];
    wsplitT_k<<<dim3(512 * 128 / 256, 3), 256, 0, stream>>>(wP, Wv0T, 512, 128);
    for (int v = 0; v < 3; ++v) wP.p[v] = Wv1[v];
    wsplitT_k<<<dim3(128 * 64 / 256, 3), 256, 0, stream>>>(wP, Wv1T, 128, 64);
    for (int v = 0; v < 3; ++v) wP.p[v] = Wf[v];
    wsplitT_k<<<dim3(64 * 64 / 256, 3), 256, 0, stream>>>(wP, WfT, 64, 64);

    // ---- per-view GCN stacks on MFMA (lossless split-bf16) ----
    Ptr3h BtP; Ptr3 biasP;
    for (int v = 0; v < 3; ++v) BtP.p[v] = Wv0T + (size_t)v * 128 * 1536;
    mfma_gemm_b_k<<<dim3(2, N / 64, 3), 256, 0, stream>>>(xe, BtP, hv1, N, 128, 1536);
    for (int v = 0; v < 3; ++v) biasP.p[v] = bv0[v];
    gather_k<128, 1, 1><<<dim3(N / 2, 3), 256, 0, stream>>>(hv1, eidx, rowptr, degs, isq, biasP, Ae2);
    for (int v = 0; v < 3; ++v) BtP.p[v] = Wv1T + (size_t)v * 64 * 384;
    mfma_gemm_b_k<<<dim3(1, N / 64, 3), 256, 0, stream>>>(Ae2, BtP, hv2, N, 64, 384);
    for (int v = 0; v < 3; ++v) biasP.p[v] = bv1[v];
    gather_k<64, 0, 2><<<dim3(N / 4, 3), 256, 0, stream>>>(hv2, eidx, rowptr, degs, isq, biasP, Ae3);
    for (int v = 0; v < 3; ++v) BtP.p[v] = WfT + (size_t)v * 64 * 192;
    mfma_gemm_b_k<<<dim3(1, N / 64, 3), 256, 0, stream>>>(Ae3, BtP, zp, N, 64, 192);
    softsum_k<<<N / 4, 256, 0, stream>>>(zp, zbuf);

    // ---- GFN conversions (xe dead; per-view scratch in oa dead) ----
    mask_to_bf16_k<<<(N * N / 4 + 255) / 256, 256, 0, stream>>>(mask, AdjB, N * N / 4);
    f32_to_bf16T_k<<<dim3(2048 / 64, 4096 / 64), 256, 0, stream>>>(Wg1, Wg1T, 4096, 2048);

    // ---- GEMM1: m201 engine, K-split-2 (z), f32 partials -> reduce(+bias,relu) ----
    gm_k<3><<<dim3(2048 / 256, 4096 / 256, 2), 512, 0, stream>>>(
        AdjB, Wg1T, nullptr, partg0, partg1, nullptr, 4096, 2048, 2048, 4096, 4096);
    reduce_h1_k<<<4096 * 2048 / 4 / 256, 256, 0, stream>>>(partg0, partg1, bg1, H1b);

    // Wg2T built over dead partg1
    f32_to_bf16T_k<<<dim3(4096 / 64, 2048 / 64), 256, 0, stream>>>(Wg2, Wg2T, 2048, 4096);

    // ---- GEMM2: m201 engine, writes adj_r (f32, over dead AdjB/partg0) + P (u8) ----
    gm_k<2><<<dim3(4096 / 256, 4096 / 256, 1), 512, 0, stream>>>(
        H1b, Wg2T, bg2, out_adjr, nullptr, P, 4096, 4096, 2048, 2048, 2048);

    // ---- consensus graph ----
    hipMemsetAsync(degA, 0, (size_t)N * 4, stream);
    build_A2_k<<<dim3(N / 64, N / 64), 256, 0, stream>>>(P, A8, degA);

    // ---- fused-graph GCN on MFMA ----
    a2b_k<<<(N * N / 4 + 255) / 256, 256, 0, stream>>>((const unsigned*)A8, A2b, N * N / 4);
    xsT_k<<<dim3(16, 64), 256, 0, stream>>>(zbuf, degA, XsT);
    spmm_mfma_k<<<dim3(8, N / 64), 256, 0, stream>>>(A2b, XsT, part);
    redgemm_k<1><<<256, 256, 0, stream>>>(part, degA, Wm0, bm0, h1m, nullptr, nullptr);
    xsT_k<<<dim3(16, 64), 256, 0, stream>>>(h1m, degA, XsT);
    spmm_mfma_k<<<dim3(8, N / 64), 256, 0, stream>>>(A2b, XsT, part);
    redgemm_k<0><<<256, 256, 0, stream>>>(part, degA, Wm1, bm1, out_h, AeF, BeF);

    // ---- adj_rec = h @ h^T via split-bf16 m201 engine (K=192, odd-NT path) ----
    gm_k<0><<<dim3(4096 / 256, 4096 / 256, 1), 512, 0, stream>>>(
        AeF, BeF, nullptr, out_rec, nullptr, nullptr, 4096, 4096, 192, 192, 192);
}

// Round 11
// 450.041 us; speedup vs baseline: 10.7385x; 1.0062x over previous
//
#include <hip/hip_runtime.h>
#include <math.h>

#define NNODES 4096
#define NEDGES 65536

typedef short bf16x8 __attribute__((ext_vector_type(8)));
typedef short short4v __attribute__((ext_vector_type(4)));
typedef float f32x4 __attribute__((ext_vector_type(4)));

struct Ptr3  { const float* p[3]; };
struct Ptr3i { const int*   p[3]; };
struct Ptr3h { const short* p[3]; };

__device__ __forceinline__ short f2bf(float f) {
    unsigned u = __builtin_bit_cast(unsigned, f);
    unsigned r = (u + 0x7FFFu + ((u >> 16) & 1u)) >> 16;
    return (short)r;
}
__device__ __forceinline__ float bf2f(short s) {
    return __builtin_bit_cast(float, ((unsigned)(unsigned short)s) << 16);
}

__device__ __forceinline__ void gload_lds16(const void* g, void* l) {
    __builtin_amdgcn_global_load_lds(
        (const __attribute__((address_space(1))) unsigned*)g,
        (__attribute__((address_space(3))) unsigned*)l, 16, 0, 0);
}

// ============ m201-style 256x256 bf16 MFMA GEMM (T1+T2+T3+T4+T5) ============
// 512 thr, 8 waves (2M x 4N), wave tile 128x64, BK=64, LDS 2 x 64KB dbuf.
// 4 quadrant-phases per K-tile (16 MFMA each), read-once frags. Half-tile
// staging, hazard-verified order; vmcnt(6) once per K-tile. Odd-NT epilogue.
// ACT==2: round(clip+0.1)->f32 + u8 P ; ACT==3: bf16 partial to (z?C1:C0) ; else f32
template<int ACT>
__global__ __launch_bounds__(512, 1)
void gm_k(const short* __restrict__ A, const short* __restrict__ Bt,
          const float* __restrict__ bias, void* __restrict__ Cout, void* __restrict__ Cout1,
          unsigned char* __restrict__ Pout, int M, int Nn, int K, int lda, int ldb)
{
    constexpr int SLOT = 32768;              // shorts per slot (64KB: A 32KB + B 32KB)
    __shared__ short lds[2 * SLOT];
    const int tid = threadIdx.x;
    const int lane = tid & 63;
    const int wave = tid >> 6;
    const int wm = wave >> 2, wn = wave & 3; // 2 M-waves x 4 N-waves
    const int z = blockIdx.z;
    A  += (size_t)z * K;                     // K-split slice offset
    Bt += (size_t)z * K;
    void* Cw = (ACT == 3 && z == 1) ? Cout1 : Cout;
    // XCD-bijective swizzle within z-slice (nwg % 8 == 0 for all grids used)
    const int gx = gridDim.x, nwg = gx * gridDim.y;
    int w = blockIdx.y * gx + blockIdx.x;
    const int q8 = nwg >> 3;
    w = (w & 7) * q8 + (w >> 3);
    const int bm0 = (w / gx) * 256, bn0 = (w % gx) * 256;
    const int NT = K >> 6;

    // stage one half-tile of tile t. part: 0=B rows0-127, 1=B rows128-255,
    // 2=A rows0-127, 3=A rows128-255. 16KB = 2 gloads/wave.
    auto stageH = [&](int t, int part) {
        if (t >= NT) return;
        const int k0 = t << 6;
        char* base = (char*)(lds + (t & 1) * SLOT);
        const int isB = (part < 2);
        const int h = part & 1;
#pragma unroll
        for (int r = 0; r < 2; ++r) {
            int o = r * 8192 + tid * 16;
            int row = o >> 7;
            int grow = h * 128 + row;
            int scol = (((o >> 4) & 7) ^ (grow & 7)) << 3;
            const short* gsrc = isB ? (Bt + (size_t)(bn0 + grow) * ldb + k0 + scol)
                                    : (A  + (size_t)(bm0 + grow) * lda + k0 + scol);
            gload_lds16(gsrc, base + (isB ? 32768 : 0) + h * 16384 + r * 8192 + wave * 1024);
        }
    };

    f32x4 acc[8][4] = {};
    bf16x8 aF[4][2];
    bf16x8 bF[4][2];

#define PH(QM, QN, TCUR, T1, P1, T2, P2, VM)                                          \
    {                                                                                 \
        const short* As_ = lds + ((TCUR) & 1) * SLOT;                                 \
        const short* Bs_ = As_ + 16384;                                               \
        if constexpr ((QN) == 0) {                                                    \
            _Pragma("unroll") for (int kk = 0; kk < 2; ++kk) {                        \
                const int h_ = kk * 4 + (lane >> 4);                                  \
                _Pragma("unroll") for (int i = 0; i < 4; ++i) {                       \
                    int r_ = wm * 128 + (QM) * 64 + i * 16 + (lane & 15);             \
                    aF[i][kk] = *(const bf16x8*)(As_ + r_ * 64 + ((h_ ^ (r_ & 7)) << 3)); \
                }                                                                     \
            }                                                                         \
        }                                                                             \
        if constexpr ((QM) == 0) {                                                    \
            _Pragma("unroll") for (int kk = 0; kk < 2; ++kk) {                        \
                const int h_ = kk * 4 + (lane >> 4);                                  \
                _Pragma("unroll") for (int j = 0; j < 2; ++j) {                       \
                    int r_ = wn * 64 + ((QN) * 2 + j) * 16 + (lane & 15);             \
                    bF[(QN) * 2 + j][kk] = *(const bf16x8*)(Bs_ + r_ * 64 + ((h_ ^ (r_ & 7)) << 3)); \
                }                                                                     \
            }                                                                         \
        }                                                                             \
        if ((P1) >= 0) stageH(T1, P1);                                                \
        if ((P2) >= 0) stageH(T2, P2);                                                \
        if constexpr ((QM) == 0 && (QN) == 0) {                                       \
            asm volatile("s_waitcnt lgkmcnt(8)" ::: "memory");                        \
        }                                                                             \
        __builtin_amdgcn_s_barrier();                                                 \
        __builtin_amdgcn_s_setprio(1);                                                \
        _Pragma("unroll") for (int kk = 0; kk < 2; ++kk)                              \
            _Pragma("unroll") for (int i = 0; i < 4; ++i)                             \
                _Pragma("unroll") for (int j = 0; j < 2; ++j)                         \
                    acc[(QM) * 4 + i][(QN) * 2 + j] =                                 \
                        __builtin_amdgcn_mfma_f32_16x16x32_bf16(                      \
                            aF[i][kk], bF[(QN) * 2 + j][kk],                          \
                            acc[(QM) * 4 + i][(QN) * 2 + j], 0, 0, 0);                \
        __builtin_amdgcn_s_setprio(0);                                                \
        if ((VM) == 6)      { asm volatile("s_waitcnt vmcnt(6)" ::: "memory");        \
                              __builtin_amdgcn_sched_barrier(0); }                    \
        else if ((VM) == 0) { asm volatile("s_waitcnt vmcnt(0)" ::: "memory");        \
                              __builtin_amdgcn_sched_barrier(0); }                    \
        __builtin_amdgcn_s_barrier();                                                 \
    }

    // prologue: tile 0 fully + tile 1 parts B0,B1,A0 (A1 comes at first ph1)
    stageH(0, 0); stageH(0, 1); stageH(0, 2); stageH(0, 3);
    if (NT > 1) { stageH(1, 0); stageH(1, 1); stageH(1, 2); }
    if (NT > 1) { asm volatile("s_waitcnt vmcnt(6)" ::: "memory"); }
    else        { asm volatile("s_waitcnt vmcnt(0)" ::: "memory"); }
    __builtin_amdgcn_sched_barrier(0);
    __builtin_amdgcn_s_barrier();

    for (int it = 0; it < NT / 2; ++it) {
        const int t0 = 2 * it, t1 = t0 + 1, t2 = t0 + 2, t3 = t0 + 3;
        const int vm4 = (t2 < NT) ? 6 : 0;
        const int vm8 = (t3 < NT) ? 6 : 0;
        PH(0, 0, t0, t1, 3,  0, -1, -1)
        PH(0, 1, t0,  0, -1, 0, -1, -1)
        PH(1, 0, t0, t2, 0, t2,  1, -1)
        PH(1, 1, t0, t2, 2,  0, -1, vm4)
        PH(0, 0, t1, t2, 3,  0, -1, -1)
        PH(0, 1, t1,  0, -1, 0, -1, -1)
        PH(1, 0, t1, t3, 0, t3,  1, -1)
        PH(1, 1, t1, t3, 2,  0, -1, vm8)
    }
    if (NT & 1) {
        const int tl = NT - 1;
        PH(0, 0, tl, 0, -1, 0, -1, -1)
        PH(0, 1, tl, 0, -1, 0, -1, -1)
        PH(1, 0, tl, 0, -1, 0, -1, -1)
        PH(1, 1, tl, 0, -1, 0, -1, -1)
    }
#undef PH

    const int cr = (lane >> 4) * 4;   // C/D: col=lane&15, row=(lane>>4)*4+reg
    const int cc = lane & 15;
#pragma unroll
    for (int im = 0; im < 8; ++im) {
#pragma unroll
        for (int jn = 0; jn < 4; ++jn) {
            int col = bn0 + wn * 64 + jn * 16 + cc;
            float bv = bias ? bias[col] : 0.f;
#pragma unroll
            for (int q2 = 0; q2 < 4; ++q2) {
                int row = bm0 + wm * 128 + (im >> 2) * 64 + (im & 3) * 16 + cr + q2;
                float v = acc[im][jn][q2] + bv;
                if constexpr (ACT == 2) {
                    v = rintf(fminf(fmaxf(v, 0.f), 1.f) + 0.1f);
                    ((float*)Cw)[(size_t)row * Nn + col] = v;
                    Pout[(size_t)row * Nn + col] = (unsigned char)(v > 0.5f);
                } else if constexpr (ACT == 3) {
                    ((short*)Cw)[(size_t)row * Nn + col] = f2bf(v);
                } else {
                    ((float*)Cw)[(size_t)row * Nn + col] = v;
                }
            }
        }
    }
}

// H1b = bf16(relu(bf16_part0 + bf16_part1 + bias[col])), [4096][2048]
__global__ void reduce_h1_k(const short* __restrict__ p0, const short* __restrict__ p1,
                            const float* __restrict__ bias, short* __restrict__ H1b)
{
    int i = (blockIdx.x * 256 + threadIdx.x) * 8;
    bf16x8 a = *(const bf16x8*)(p0 + i);
    bf16x8 b = *(const bf16x8*)(p1 + i);
    int col = i & 2047;
    bf16x8 o;
#pragma unroll
    for (int j = 0; j < 8; ++j) {
        float v = bf2f(a[j]) + bf2f(b[j]) + bias[col + j];
        o[j] = f2bf(fmaxf(v, 0.f));
    }
    *(bf16x8*)(H1b + i) = o;
}

// ---------------- batched bf16 MFMA GEMM, 64x64 tile (per-view stacks) ----------------
__global__ __launch_bounds__(256)
void mfma_gemm_b_k(const short* __restrict__ Aall, Ptr3h Btv, float* __restrict__ Call,
                   int M, int Nn, int K)
{
    __shared__ short As[64 * 64];
    __shared__ short Bs[64 * 64];
    const int z = blockIdx.z;
    const short* A = Aall + (size_t)z * M * K;
    const short* Bt = Btv.p[z];
    float* C = Call + (size_t)z * M * Nn;
    const int tid = threadIdx.x;
    const int lane = tid & 63, wave = tid >> 6;
    const int bm0 = blockIdx.y * 64, bn0 = blockIdx.x * 64;
    const int wr = (wave >> 1) * 32, wc = (wave & 1) * 32;

    f32x4 acc[2][2] = {};

    for (int k0 = 0; k0 < K; k0 += 64) {
        for (int c = wave; c < 8; c += 4) {
            int o = c * 1024 + lane * 16;
            int row = o >> 7;
            int sl = (o >> 4) & 7;
            int ss = sl ^ (row & 7);
            gload_lds16(A + ((size_t)(bm0 + row) * K + k0 + ss * 8), As + c * 512);
            gload_lds16(Bt + ((size_t)(bn0 + row) * K + k0 + ss * 8), Bs + c * 512);
        }
        __syncthreads();
#pragma unroll
        for (int kk = 0; kk < 2; ++kk) {
            bf16x8 a[2], b[2];
            const int khalf = kk * 4 + (lane >> 4);
#pragma unroll
            for (int i = 0; i < 2; ++i) {
                int r = wr + i * 16 + (lane & 15);
                a[i] = *(const bf16x8*)(As + r * 64 + ((khalf ^ (r & 7)) << 3));
            }
#pragma unroll
            for (int j = 0; j < 2; ++j) {
                int r = wc + j * 16 + (lane & 15);
                b[j] = *(const bf16x8*)(Bs + r * 64 + ((khalf ^ (r & 7)) << 3));
            }
#pragma unroll
            for (int i = 0; i < 2; ++i)
#pragma unroll
                for (int j = 0; j < 2; ++j)
                    acc[i][j] = __builtin_amdgcn_mfma_f32_16x16x32_bf16(a[i], b[j], acc[i][j], 0, 0, 0);
        }
        __syncthreads();
    }

    const int cr = (lane >> 4) * 4;
    const int cc = lane & 15;
#pragma unroll
    for (int i = 0; i < 2; ++i)
#pragma unroll
        for (int j = 0; j < 2; ++j)
#pragma unroll
            for (int q = 0; q < 4; ++q) {
                int row = bm0 + wr + i * 16 + cr + q;
                int col = bn0 + wc + j * 16 + cc;
                C[(size_t)row * Nn + col] = acc[i][j][q];
            }
}

// ---------------- MFMA SpMM: part[kc] = A2b[:,kc-chunk] @ (hi+lo)^T ----------------
__global__ __launch_bounds__(256)
void spmm_mfma_k(const short* __restrict__ A2b, const short* __restrict__ XsT,
                 float* __restrict__ part)
{
    __shared__ short As[64 * 64];
    __shared__ short Bs[128 * 64];
    const int tid = threadIdx.x;
    const int lane = tid & 63, wave = tid >> 6;
    const int kc = blockIdx.x, m0 = blockIdx.y * 64;
    const int wr = (wave >> 1) * 32, wc = (wave & 1) * 32;
    const int woff = wave * 512;

    f32x4 acc[2][2] = {};

    for (int k0 = kc * 512; k0 < kc * 512 + 512; k0 += 64) {
#pragma unroll
        for (int r = 0; r < 2; ++r) {
            int o = r * 4096 + tid * 16;
            int row = o >> 7;
            int sl = (o >> 4) & 7;
            gload_lds16(A2b + ((size_t)(m0 + row) * 4096 + k0 + ((sl ^ (row & 7)) << 3)),
                        As + r * 2048 + woff);
        }
#pragma unroll
        for (int r = 0; r < 4; ++r) {
            int o = r * 4096 + tid * 16;
            int row = o >> 7;
            int sl = (o >> 4) & 7;
            gload_lds16(XsT + ((size_t)row * 4096 + k0 + ((sl ^ (row & 7)) << 3)),
                        Bs + r * 2048 + woff);
        }
        __syncthreads();
#pragma unroll
        for (int kk = 0; kk < 2; ++kk) {
            const int h = kk * 4 + (lane >> 4);
            bf16x8 a[2], bh[2], bl[2];
#pragma unroll
            for (int i = 0; i < 2; ++i) {
                int r = wr + i * 16 + (lane & 15);
                a[i] = *(const bf16x8*)(As + r * 64 + ((h ^ (r & 7)) << 3));
            }
#pragma unroll
            for (int j = 0; j < 2; ++j) {
                int r = wc + j * 16 + (lane & 15);
                bh[j] = *(const bf16x8*)(Bs + r * 64 + ((h ^ (r & 7)) << 3));
                int r2 = r + 64;
                bl[j] = *(const bf16x8*)(Bs + r2 * 64 + ((h ^ (r2 & 7)) << 3));
            }
#pragma unroll
            for (int i = 0; i < 2; ++i)
#pragma unroll
                for (int j = 0; j < 2; ++j) {
                    acc[i][j] = __builtin_amdgcn_mfma_f32_16x16x32_bf16(a[i], bh[j], acc[i][j], 0, 0, 0);
                    acc[i][j] = __builtin_amdgcn_mfma_f32_16x16x32_bf16(a[i], bl[j], acc[i][j], 0, 0, 0);
                }
        }
        __syncthreads();
    }

    const int cr = (lane >> 4) * 4;
    const int cc = lane & 15;
#pragma unroll
    for (int i = 0; i < 2; ++i)
#pragma unroll
        for (int j = 0; j < 2; ++j)
#pragma unroll
            for (int q = 0; q < 4; ++q)
                part[((size_t)kc * NNODES + m0 + wr + i * 16 + cr + q) * 64 + wc + j * 16 + cc]
                    = acc[i][j][q];
}

// X [4096][64] f32 -> XsT [128][4096] bf16 (hi rows 0-63, lo 64-127), dn folded
__global__ void xsT_k(const float* __restrict__ X, const int* __restrict__ degA,
                      short* __restrict__ XsT)
{
    const int n = blockIdx.y;
    const int k = blockIdx.x * 256 + threadIdx.x;
    float v = X[(size_t)k * 64 + n] * (1.0f / sqrtf((float)degA[k]));
    short hi = f2bf(v);
    short lo = f2bf(v - bf2f(hi));
    XsT[(size_t)n * 4096 + k] = hi;
    XsT[(size_t)(64 + n) * 4096 + k] = lo;
}

// f32 [R][C] -> bf16 transposed [C][R]
__global__ void f32_to_bf16T_k(const float* __restrict__ src, short* __restrict__ dstT,
                               int R, int C)
{
    __shared__ float t[64][65];
    const int br = blockIdx.y * 64, bc = blockIdx.x * 64;
    for (int idx = threadIdx.x; idx < 64 * 64; idx += 256) {
        int r = idx >> 6, c = idx & 63;
        t[r][c] = src[(size_t)(br + r) * C + bc + c];
    }
    __syncthreads();
    for (int idx = threadIdx.x; idx < 64 * 64; idx += 256) {
        int c = idx >> 6, r = idx & 63;
        dstT[(size_t)(bc + c) * R + br + r] = f2bf(t[r][c]);
    }
}

__global__ void mask_to_bf16_k(const unsigned* __restrict__ mask, short* __restrict__ adj,
                               int words)
{
    int t = blockIdx.x * 256 + threadIdx.x;
    if (t < words) {
        unsigned w = mask[t];
        short4v o;
        o.x = f2bf((float)__popc(w & 0x7u));
        o.y = f2bf((float)__popc(w & 0x700u));
        o.z = f2bf((float)__popc(w & 0x70000u));
        o.w = f2bf((float)__popc(w & 0x7000000u));
        *(short4v*)(adj + (size_t)t * 4) = o;
    }
}

// x [N,512] f32 * doi -> split-bf16 xe [N][1536] = [hi | hi | lo]
__global__ void xsplit_k(Ptr3 xv, const float* __restrict__ isq, short* __restrict__ xe)
{
    const int z = blockIdx.y;
    int t = blockIdx.x * 256 + threadIdx.x;
    int n = t >> 9, k = t & 511;
    float a = xv.p[z][(size_t)n * 512 + k] * isq[2 * z * NNODES + n];
    short hi = f2bf(a);
    short lo = f2bf(a - bf2f(hi));
    short* row = xe + (size_t)z * NNODES * 1536 + (size_t)n * 1536;
    row[k] = hi; row[512 + k] = hi; row[1024 + k] = lo;
}

// W [K][Nn] f32 -> split-bf16 transposed Bt [Nn][3K] = [hi | lo | hi]
__global__ void wsplitT_k(Ptr3 Wv, short* __restrict__ out, int K, int Nn)
{
    const int z = blockIdx.y;
    int t = blockIdx.x * 256 + threadIdx.x;
    if (t >= K * Nn) return;
    int k = t / Nn, n = t % Nn;
    float w = Wv.p[z][(size_t)k * Nn + n];
    short hi = f2bf(w);
    short lo = f2bf(w - bf2f(hi));
    short* row = out + (size_t)z * Nn * 3 * K + (size_t)n * 3 * K;
    row[k] = hi; row[K + k] = lo; row[2 * K + k] = hi;
}

// fused: s = (sum_p part[p][row,:]) * deg[row]^-1/2 ; out = act(s @ Wm + b)
// optional emits: split-bf16 Ae/Be (h@hT operands) or dn-folded XsT (next spmm B)
template<int RELU>
__global__ __launch_bounds__(256)
void redgemm_k(const float* __restrict__ part, const int* __restrict__ degA,
               const float* __restrict__ Wm, const float* __restrict__ bias,
               float* __restrict__ out, short* __restrict__ Ae, short* __restrict__ Be,
               short* __restrict__ XsT)
{
    __shared__ float Ws[64 * 64];
    const int tid = threadIdx.x;
    for (int i = tid; i < 4096; i += 256) Ws[i] = Wm[i];
    __syncthreads();
    const int lane = tid & 63, wave = tid >> 6;
    const float bv = bias[lane];
    for (int rr = 0; rr < 4; ++rr) {
        int row = blockIdx.x * 16 + wave * 4 + rr;
        float s = 0.f;
#pragma unroll
        for (int p = 0; p < 8; ++p) s += part[((size_t)p * NNODES + row) * 64 + lane];
        const float dn = 1.0f / sqrtf((float)degA[row]);
        s *= dn;
        float acc = bv;
#pragma unroll
        for (int k = 0; k < 64; ++k)
            acc = fmaf(__shfl(s, k), Ws[k * 64 + lane], acc);
        if (RELU) acc = fmaxf(acc, 0.f);
        out[(size_t)row * 64 + lane] = acc;
        if (Ae) {
            short hi = f2bf(acc);
            short lo = f2bf(acc - bf2f(hi));
            size_t ro = (size_t)row * 192;
            Ae[ro + lane] = hi; Ae[ro + 64 + lane] = hi; Ae[ro + 128 + lane] = lo;
            Be[ro + lane] = hi; Be[ro + 64 + lane] = lo; Be[ro + 128 + lane] = hi;
        }
        if (XsT) {
            float vv = acc * dn;
            short hi = f2bf(vv);
            short lo = f2bf(vv - bf2f(hi));
            XsT[(size_t)lane * 4096 + row] = hi;
            XsT[(size_t)(64 + lane) * 4096 + row] = lo;
        }
    }
}

// ---------------- graph construction ----------------
__global__ void edge_k(Ptr3i src, Ptr3i dst, unsigned* __restrict__ mask, int* __restrict__ degs)
{
    int e = blockIdx.x * 256 + threadIdx.x;
    int z = blockIdx.y;
    if (e < NEDGES) {
        int s = src.p[z][e], d = dst.p[z][e];
        unsigned c = (unsigned)s * (unsigned)NNODES + (unsigned)d;
        atomicOr(&mask[c >> 2], 1u << ((c & 3u) * 8u + (unsigned)z));
        atomicAdd(&degs[2 * z * NNODES + s], 1);
        atomicAdd(&degs[(2 * z + 1) * NNODES + d], 1);
    }
}

__global__ void deg_norm_k(const int* __restrict__ degs, float* __restrict__ isq, int n)
{
    int t = blockIdx.x * 256 + threadIdx.x;
    if (t < n) isq[t] = 1.0f / sqrtf(fmaxf((float)t >= 0 ? (float)degs[t] : 1.0f, 1.0f));
}

__global__ __launch_bounds__(1024)
void scan_k(const int* __restrict__ degs, int* __restrict__ rowptr, int* __restrict__ cursor)
{
    const int z = blockIdx.x;
    const int* din = degs + (2 * z + 1) * NNODES;
    __shared__ int sm[1024];
    const int t = threadIdx.x;
    int v0 = din[t * 4], v1 = din[t * 4 + 1], v2 = din[t * 4 + 2], v3 = din[t * 4 + 3];
    int c1 = v0 + v1, c2 = c1 + v2, s = c2 + v3;
    sm[t] = s;
    __syncthreads();
    for (int off = 1; off < 1024; off <<= 1) {
        int add = (t >= off) ? sm[t - off] : 0;
        __syncthreads();
        sm[t] += add;
        __syncthreads();
    }
    int base = sm[t] - s;
    int* rp = rowptr + z * NNODES;
    int* cu = cursor + z * NNODES;
    rp[t * 4] = base;          cu[t * 4] = base;
    rp[t * 4 + 1] = base + v0; cu[t * 4 + 1] = base + v0;
    rp[t * 4 + 2] = base + c1; cu[t * 4 + 2] = base + c1;
    rp[t * 4 + 3] = base + c2; cu[t * 4 + 3] = base + c2;
}

__global__ void fill_k(Ptr3i src, Ptr3i dst, int* __restrict__ cursor, int* __restrict__ eidx)
{
    int e = blockIdx.x * 256 + threadIdx.x;
    int z = blockIdx.y;
    if (e < NEDGES) {
        int d = dst.p[z][e];
        int pos = atomicAdd(&cursor[z * NNODES + d], 1);
        eidx[(size_t)z * NEDGES + pos] = src.p[z][e];
    }
}

// fused CSR-gather + norm + bias + act -> split-bf16 A rows [node][3F]
template<int F, int ACT, int MODE>
__global__ void gather_k(const float* __restrict__ Hpre, const int* __restrict__ eidx,
                         const int* __restrict__ rowptr, const int* __restrict__ degs,
                         const float* __restrict__ isq, Ptr3 bias, short* __restrict__ Sout)
{
    const int z = blockIdx.y;
    const int tid = threadIdx.x;
    const int node = blockIdx.x * (256 / F) + tid / F;
    const int f = tid % F;
    const float* H = Hpre + (size_t)z * NNODES * F;
    const int base = rowptr[z * NNODES + node];
    const int cnt = degs[(2 * z + 1) * NNODES + node];
    const int* ei = eidx + (size_t)z * NEDGES + base;
    float s = 0.f;
    for (int i = 0; i < cnt; ++i) s += H[(size_t)ei[i] * F + f];
    float v = s * isq[(2 * z + 1) * NNODES + node] + bias.p[z][f];
    if (ACT) v = fmaxf(v, 0.f);
    if (MODE == 1) v *= isq[2 * z * NNODES + node];
    short hi = f2bf(v);
    short lo = f2bf(v - bf2f(hi));
    short* row = Sout + (size_t)z * NNODES * 3 * F + (size_t)node * 3 * F;
    row[f] = hi; row[F + f] = hi; row[2 * F + f] = lo;
}

// z = softmax_row(zp0+zp1+zp2)
__global__ void softsum_k(const float* __restrict__ zp, float* __restrict__ z)
{
    int row = blockIdx.x * 4 + (threadIdx.x >> 6);
    int f = threadIdx.x & 63;
    size_t i = (size_t)row * 64 + f;
    float v = zp[i] + zp[i + (size_t)NNODES * 64] + zp[i + (size_t)2 * NNODES * 64];
    float m = v;
#pragma unroll
    for (int off = 32; off >= 1; off >>= 1) m = fmaxf(m, __shfl_xor(m, off));
    float e = expf(v - m);
    float s = e;
#pragma unroll
    for (int off = 32; off >= 1; off >>= 1) s += __shfl_xor(s, off);
    z[i] = e / s;
}

// A2b[i,j] = bf16( P[i,j] | P[j,i] | (i==j) ), deg row-sums. (direct bf16 emit)
__global__ __launch_bounds__(256)
void build_A2_k(const unsigned char* __restrict__ P, short* __restrict__ A2b,
                int* __restrict__ degA)
{
    __shared__ unsigned Ts[64][20];
    const int bi = blockIdx.y * 64, bj = blockIdx.x * 64;
    const int tid = threadIdx.x;
    const int r = tid >> 2, seg = tid & 3;
    uint4 tv = *(const uint4*)(P + (size_t)(bj + r) * NNODES + bi + seg * 16);
    Ts[r][seg * 4 + 0] = tv.x; Ts[r][seg * 4 + 1] = tv.y;
    Ts[r][seg * 4 + 2] = tv.z; Ts[r][seg * 4 + 3] = tv.w;
    __syncthreads();
    uint4 dv = *(const uint4*)(P + (size_t)(bi + r) * NNODES + bj + seg * 16);
    unsigned dw[4] = {dv.x, dv.y, dv.z, dv.w};
    const unsigned char* Tb = (const unsigned char*)Ts;
    bf16x8 o0, o1;
    int psum = 0;
#pragma unroll
    for (int w = 0; w < 4; ++w) {
#pragma unroll
        for (int b = 0; b < 4; ++b) {
            int idx = w * 4 + b;
            int j = seg * 16 + idx;
            unsigned a = (dw[w] >> (8 * b)) & 1u;
            unsigned tr = Tb[j * 80 + r] & 1u;
            unsigned on = a | tr | (unsigned)((bi + r) == (bj + j));
            short val = on ? (short)0x3F80 : (short)0;
            if (idx < 8) o0[idx] = val; else o1[idx - 8] = val;
            psum += (int)on;
        }
    }
    short* dst = A2b + (size_t)(bi + r) * NNODES + bj + seg * 16;
    *(bf16x8*)dst = o0;
    *(bf16x8*)(dst + 8) = o1;
    psum += __shfl_xor(psum, 1);
    psum += __shfl_xor(psum, 2);
    if (seg == 0) atomicAdd(&degA[bi + r], psum);
}

extern "C" void kernel_launch(void* const* d_in, const int* in_sizes, int n_in,
                              void* d_out, int out_size, void* d_ws, size_t ws_size,
                              hipStream_t stream)
{
    const int N = NNODES, E = NEDGES;
    const size_t MB = 1024 * 1024;

    const float* x[3]; const int* src[3]; const int* dst[3];
    const float *Wv0[3], *bv0[3], *Wv1[3], *bv1[3], *Wf[3];
    for (int v = 0; v < 3; ++v) {
        const int b = v * 8;
        x[v]   = (const float*)d_in[b + 0];
        src[v] = (const int*)  d_in[b + 1];
        dst[v] = (const int*)  d_in[b + 2];
        Wv0[v] = (const float*)d_in[b + 3];
        bv0[v] = (const float*)d_in[b + 4];
        Wv1[v] = (const float*)d_in[b + 5];
        bv1[v] = (const float*)d_in[b + 6];
        Wf[v]  = (const float*)d_in[b + 7];
    }
    const float* Wg1 = (const float*)d_in[24];
    const float* bg1 = (const float*)d_in[25];
    const float* Wg2 = (const float*)d_in[26];
    const float* bg2 = (const float*)d_in[27];
    const float* Wm0 = (const float*)d_in[28];
    const float* bm0 = (const float*)d_in[29];
    const float* Wm1 = (const float*)d_in[30];
    const float* bm1 = (const float*)d_in[31];

    float* out_adjr = (float*)d_out;                    // [N,N] f32 (final)
    float* out_rec  = out_adjr + (size_t)N * N;         // [N,N] f32 (final; scratch until then)
    float* out_h    = out_rec + (size_t)N * N;          // [N,64]

    // --- scratch carved from dead regions of outputs ---
    char* oa = (char*)out_adjr;                         // 64 MB, final write = GEMM2
    short* AdjB = (short*)oa;                           // bf16 [N][N]  [0,32M)
    float* hv1  = (float*)(oa + 32 * MB);               // f32 [3][N][128]
    short* Ae2  = (short*)(oa + 38 * MB);
    short* Ae3  = (short*)(oa + 47 * MB);
    float* hv2  = (float*)(oa + 52 * MB);
    float* zp   = (float*)(oa + 56 * MB);
    short* partg0 = (short*)(oa + 32 * MB);             // GEMM1 bf16 partial z=0 (16 MB)
    short* partg1 = (short*)(oa + 48 * MB);             // GEMM1 bf16 partial z=1 (16 MB)

    char* orc = (char*)out_rec;                         // 64 MB, final write = h@hT
    short* xe   = (short*)orc;                          // bf16 [3][N][1536] (dead after L1)
    short* H1b  = (short*)orc;                          // bf16 [N][2048]  [0,16M)
    unsigned char* P = (unsigned char*)(orc + 16 * MB); // u8 [N][N]       [16,32M)
    short* Wg1T = (short*)(orc + 16 * MB);              // dead when P written (after GEMM1)
    short* Wg2T = (short*)(orc + 32 * MB);              // [32,48M)
    float* part = (float*)(orc + 48 * MB);              // 8 MB K-split partials (spmm)

    // ---- workspace carve ----
    char* p = (char*)d_ws;
    unsigned* mask = (unsigned*)p;                      // [0,16M); dead after mask_to_bf16
    short* AeF = (short*)p;                             // h@hT operands (over dead mask)
    short* BeF = AeF + (size_t)N * 192;
    p += (size_t)N * N;                                 // 16MB
    int* degs = (int*)p;     p += (size_t)6 * N * 4;
    float* isq = (float*)p;  p += (size_t)6 * N * 4;
    int* rowptr = (int*)p;   p += (size_t)3 * N * 4;
    int* cursor = (int*)p;   p += (size_t)3 * N * 4;
    int* eidx = (int*)p;     p += (size_t)3 * E * 4;
    int* degA = (int*)p;     p += (size_t)N * 4;
    float* zbuf = (float*)p; p += (size_t)N * 64 * 4;
    float* h1m = (float*)p;  p += (size_t)N * 64 * 4;
    short* XsT = (short*)p;  p += (size_t)128 * N * 2;
    short* Wv0T = (short*)p; p += (size_t)3 * 128 * 1536 * 2;
    short* Wv1T = (short*)p; p += (size_t)3 * 64 * 384 * 2;
    short* WfT  = (short*)p; p += (size_t)3 * 64 * 192 * 2;
    // align to 64MB boundary region for A2b (plenty of ws: poison fill shows ~380+ MB)
    short* A2b = (short*)((char*)d_ws + 64 * MB);       // bf16 [N][N] (32 MB)

    Ptr3i srcP, dstP;
    for (int v = 0; v < 3; ++v) { srcP.p[v] = src[v]; dstP.p[v] = dst[v]; }

    hipMemsetAsync(mask, 0, (size_t)N * N, stream);
    hipMemsetAsync(degs, 0, (size_t)6 * N * 4, stream);

    edge_k<<<dim3((E + 255) / 256, 3), 256, 0, stream>>>(srcP, dstP, mask, degs);
    deg_norm_k<<<(6 * N + 255) / 256, 256, 0, stream>>>(degs, isq, 6 * N);
    scan_k<<<3, 1024, 0, stream>>>(degs, rowptr, cursor);
    fill_k<<<dim3((E + 255) / 256, 3), 256, 0, stream>>>(srcP, dstP, cursor, eidx);

    // ---- split-bf16 operand builders for per-view GEMMs ----
    Ptr3 xP; for (int v = 0; v < 3; ++v) xP.p[v] = x[v];
    xsplit_k<<<dim3(N * 512 / 256, 3), 256, 0, stream>>>(xP, isq, xe);
    Ptr3 wP;
    for (int v = 0; v < 3; ++v) wP.p[v] = Wv0[v];
    wsplitT_k<<<dim3(512 * 128 / 256, 3), 256, 0, stream>>>(wP, Wv0T, 512, 128);
    for (int v = 0; v < 3; ++v) wP.p[v] = Wv1[v];
    wsplitT_k<<<dim3(128 * 64 / 256, 3), 256, 0, stream>>>(wP, Wv1T, 128, 64);
    for (int v = 0; v < 3; ++v) wP.p[v] = Wf[v];
    wsplitT_k<<<dim3(64 * 64 / 256, 3), 256, 0, stream>>>(wP, WfT, 64, 64);

    // ---- per-view GCN stacks on MFMA (lossless split-bf16) ----
    Ptr3h BtP; Ptr3 biasP;
    for (int v = 0; v < 3; ++v) BtP.p[v] = Wv0T + (size_t)v * 128 * 1536;
    mfma_gemm_b_k<<<dim3(2, N / 64, 3), 256, 0, stream>>>(xe, BtP, hv1, N, 128, 1536);
    for (int v = 0; v < 3; ++v) biasP.p[v] = bv0[v];
    gather_k<128, 1, 1><<<dim3(N / 2, 3), 256, 0, stream>>>(hv1, eidx, rowptr, degs, isq, biasP, Ae2);
    for (int v = 0; v < 3; ++v) BtP.p[v] = Wv1T + (size_t)v * 64 * 384;
    mfma_gemm_b_k<<<dim3(1, N / 64, 3), 256, 0, stream>>>(Ae2, BtP, hv2, N, 64, 384);
    for (int v = 0; v < 3; ++v) biasP.p[v] = bv1[v];
    gather_k<64, 0, 2><<<dim3(N / 4, 3), 256, 0, stream>>>(hv2, eidx, rowptr, degs, isq, biasP, Ae3);
    for (int v = 0; v < 3; ++v) BtP.p[v] = WfT + (size_t)v * 64 * 192;
    mfma_gemm_b_k<<<dim3(1, N / 64, 3), 256, 0, stream>>>(Ae3, BtP, zp, N, 64, 192);
    softsum_k<<<N / 4, 256, 0, stream>>>(zp, zbuf);

    // ---- GFN conversions (xe dead; per-view scratch in oa dead) ----
    mask_to_bf16_k<<<(N * N / 4 + 255) / 256, 256, 0, stream>>>(mask, AdjB, N * N / 4);
    f32_to_bf16T_k<<<dim3(2048 / 64, 4096 / 64), 256, 0, stream>>>(Wg1, Wg1T, 4096, 2048);
    f32_to_bf16T_k<<<dim3(4096 / 64, 2048 / 64), 256, 0, stream>>>(Wg2, Wg2T, 2048, 4096);

    // ---- GEMM1: K-split-2 (z), bf16 partials -> reduce(+bias,relu) -> H1b ----
    gm_k<3><<<dim3(2048 / 256, 4096 / 256, 2), 512, 0, stream>>>(
        AdjB, Wg1T, nullptr, partg0, partg1, nullptr, 4096, 2048, 2048, 4096, 4096);
    reduce_h1_k<<<4096 * 2048 / 8 / 256, 256, 0, stream>>>(partg0, partg1, bg1, H1b);

    // ---- GEMM2: writes adj_r (f32, full oa) + P (u8) ----
    gm_k<2><<<dim3(4096 / 256, 4096 / 256, 1), 512, 0, stream>>>(
        H1b, Wg2T, bg2, out_adjr, nullptr, P, 4096, 4096, 2048, 2048, 2048);

    // ---- consensus graph: direct bf16 A2b + degrees ----
    hipMemsetAsync(degA, 0, (size_t)N * 4, stream);
    build_A2_k<<<dim3(N / 64, N / 64), 256, 0, stream>>>(P, A2b, degA);

    // ---- fused-graph GCN on MFMA ----
    xsT_k<<<dim3(16, 64), 256, 0, stream>>>(zbuf, degA, XsT);
    spmm_mfma_k<<<dim3(8, N / 64), 256, 0, stream>>>(A2b, XsT, part);
    redgemm_k<1><<<256, 256, 0, stream>>>(part, degA, Wm0, bm0, h1m, nullptr, nullptr, XsT);
    spmm_mfma_k<<<dim3(8, N / 64), 256, 0, stream>>>(A2b, XsT, part);
    redgemm_k<0><<<256, 256, 0, stream>>>(part, degA, Wm1, bm1, out_h, AeF, BeF, nullptr);

    // ---- adj_rec = h @ h^T via split-bf16 engine (K=192, odd-NT path) ----
    gm_k<0><<<dim3(4096 / 256, 4096 / 256, 1), 512, 0, stream>>>(
        AeF, BeF, nullptr, out_rec, nullptr, nullptr, 4096, 4096, 192, 192, 192);
}